// Round 9
// baseline (1894.218 us; speedup 1.0000x reference)
//
#include <hip/hip_runtime.h>
#include <hip/hip_fp16.h>

#define NN 50000
#define NE 150000
#define HD 512
#define HIDN 64
#define BN_EPS 1e-5f
#define SLOPE 0.01f

typedef _Float16 half8 __attribute__((ext_vector_type(8)));
typedef float floatx4 __attribute__((ext_vector_type(4)));

__device__ __forceinline__ float leaky(float v){ return v > 0.f ? v : SLOPE*v; }
__device__ __forceinline__ float h2fu(unsigned short u){ return __half2float(__ushort_as_half(u)); }
__device__ __forceinline__ unsigned short f2hu(float f){ return __half_as_ushort(__float2half(f)); }
__device__ __forceinline__ unsigned packh2(float a, float b){
  return (unsigned)f2hu(a) | ((unsigned)f2hu(b) << 16);
}

// ---------------- setup ----------------
// batch is sorted -> per-graph counts via binary search (no atomics)
__global__ void k_counts_bs(const int* __restrict__ batch, int* __restrict__ counts){
  int g = threadIdx.x;   // 0..63
  int lo = 0, hi = NN;
  while (lo < hi){ int mid = (lo+hi)>>1; if (batch[mid] <  g) lo = mid+1; else hi = mid; }
  int start = lo;
  lo = 0; hi = NN;
  while (lo < hi){ int mid = (lo+hi)>>1; if (batch[mid] <= g) lo = mid+1; else hi = mid; }
  counts[g] = lo - start;
}
__global__ void k_invs_mask0(const int* __restrict__ batch, const int* __restrict__ counts,
                             const float* __restrict__ x, float* __restrict__ invs, int* __restrict__ m0){
  int i = blockIdx.x*blockDim.x + threadIdx.x;
  if (i < NN){
    invs[i] = rsqrtf((float)counts[batch[i]]);
    m0[i] = (fabsf(x[i]) > 0.f) ? 1 : 0;
  }
}
__global__ void k_mask_copy(const int* __restrict__ a, int* __restrict__ b){
  int i = blockIdx.x*blockDim.x + threadIdx.x;
  if (i < NN) b[i] = a[i];
}
__global__ void k_mask_prop(const int* __restrict__ mi, int* __restrict__ mo,
                            const int* __restrict__ src, const int* __restrict__ dst){
  int e = blockIdx.x*blockDim.x + threadIdx.x;
  if (e < NE){ if (mi[src[e]]) atomicOr(&mo[dst[e]], 1); }
}

// ---------------- CSR build (by dst) ----------------
__global__ void k_deg(const int* __restrict__ dst, int* __restrict__ deg){
  int e = blockIdx.x*blockDim.x + threadIdx.x;
  if (e < NE) atomicAdd(&deg[dst[e]], 1);
}
#define SCAN_CHUNK 49  // 1024*49 = 50176 >= NN
__global__ void k_scan(const int* __restrict__ deg, int* __restrict__ off, int* __restrict__ cur){
  __shared__ int part[1024];
  int t = threadIdx.x;
  int base = t * SCAN_CHUNK;
  int s = 0;
  for (int j = 0; j < SCAN_CHUNK; j++){ int i = base + j; if (i < NN) s += deg[i]; }
  part[t] = s;
  __syncthreads();
  for (int d = 1; d < 1024; d <<= 1){
    int add = (t >= d) ? part[t - d] : 0;
    __syncthreads();
    part[t] += add;
    __syncthreads();
  }
  int run = part[t] - s;
  for (int j = 0; j < SCAN_CHUNK; j++){
    int i = base + j;
    if (i < NN){ off[i] = run; cur[i] = run; run += deg[i]; }
  }
}
__global__ void k_scatter(const int* __restrict__ src, const int* __restrict__ dst,
                          int* __restrict__ cur, int* __restrict__ srcs){
  int e = blockIdx.x*blockDim.x + threadIdx.x;
  if (e < NE){
    int pos = atomicAdd(&cur[dst[e]], 1);
    srcs[pos] = src[e];
  }
}

// ---------------- weight prep: Wt[n][k] fp16 = W[k][n] fp32 ----------------
__global__ void k_w2ht(const float* __restrict__ W, unsigned short* __restrict__ Wt, int K, int N){
  __shared__ float t[32][33];
  int kb = blockIdx.x*32, nb = blockIdx.y*32;
  int tx = threadIdx.x & 31, ty = threadIdx.x >> 5;   // 32 x 8
  for (int r = 0; r < 32; r += 8)
    t[ty+r][tx] = W[(size_t)(kb+ty+r)*N + nb+tx];
  __syncthreads();
  for (int r = 0; r < 32; r += 8)
    Wt[(size_t)(nb+ty+r)*K + kb+tx] = f2hu(t[tx][ty+r]);
}

// ---------------- conv1 front ----------------
__global__ void k_sagg_csr(const float* __restrict__ x, const int* __restrict__ off,
                           const int* __restrict__ deg, const int* __restrict__ srcs,
                           const float* __restrict__ epsp, float* __restrict__ h0){
  int i = blockIdx.x*blockDim.x + threadIdx.x;
  if (i < NN){
    float s = (1.f + epsp[0]) * x[i];
    int o = off[i], d = deg[i];
    for (int j = 0; j < d; j++) s += x[srcs[o + j]];
    h0[i] = s;
  }
}
__global__ void k_conv1_h1(const float* __restrict__ h0, const float* __restrict__ w1,
                           const float* __restrict__ b1, unsigned short* __restrict__ C){
  long idx = (long)blockIdx.x*blockDim.x + threadIdx.x;
  if (idx >= (long)NN*HD) return;
  int i = (int)(idx >> 9), c = (int)(idx & (HD-1));
  float v = fmaf(h0[i], w1[c], b1[c]);
  C[idx] = f2hu(v > 0.f ? v : 0.f);
}

// ---------------- gather+combine with on-the-fly BN affine ----------------
__global__ void k_agg_csr(const _Float16* __restrict__ T, const int* __restrict__ off,
                          const int* __restrict__ deg, const int* __restrict__ srcs,
                          const float* __restrict__ epsp,
                          const float* __restrict__ st, const float* __restrict__ g,
                          const float* __restrict__ bb, _Float16* __restrict__ G){
  int i = blockIdx.x;
  int t = threadIdx.x;          // 64 threads, 8 channels each
  int c0 = t << 3;
  const float inv_n = 1.f/(float)NN;
  float sc[8], sh[8];
  #pragma unroll
  for (int k = 0; k < 8; k++){
    int c = c0 + k;
    float mu = st[c]*inv_n;
    float var = st[HD+c]*inv_n - mu*mu;
    float s = g[c]*rsqrtf(var+BN_EPS);
    sc[k] = s; sh[k] = bb[c] - mu*s;
  }
  const half8* Tv = (const half8*)T;
  half8 p = Tv[(size_t)i*64 + t];
  float ep = 1.f + epsp[0];
  float acc[8];
  #pragma unroll
  for (int k = 0; k < 8; k++) acc[k] = (float)p[k] * ep;
  int o = off[i], d = deg[i];
  for (int j = 0; j < d; j++){
    int s = srcs[o + j];
    half8 q = Tv[(size_t)s*64 + t];
    #pragma unroll
    for (int k = 0; k < 8; k++) acc[k] += (float)q[k];
  }
  float cnt = ep + (float)d;
  half8 r;
  #pragma unroll
  for (int k = 0; k < 8; k++) r[k] = (_Float16)fmaf(sc[k], acc[k], cnt*sh[k]);
  ((half8*)G)[(size_t)i*64 + t] = r;
}

// ---------------- MFMA GEMM: C[Mx512](fp16) = relu(A[Mx512] @ W + b), optional fused BN stats ----------------
// Block tile 128x256, 4 waves x (64x128 = 4x8 MFMA 16x16x32), BK=64.
template<bool STATS>
__global__ __launch_bounds__(256) void k_gemm_mfma(const _Float16* __restrict__ A,
    const _Float16* __restrict__ Wt, const float* __restrict__ bias,
    _Float16* __restrict__ C, float* __restrict__ st, int M)
{
  constexpr int PK = 72;
  __shared__ __attribute__((aligned(16))) _Float16 As[128*PK];
  __shared__ __attribute__((aligned(16))) _Float16 Bs[256*PK];
  const int tid = threadIdx.x;
  const int m0 = blockIdx.x * 128;
  const int n0 = blockIdx.y * 256;
  const int w = tid >> 6, lane = tid & 63;
  const int wm = (w >> 1) << 6;       // 0 or 64
  const int wn = (w & 1) << 7;        // 0 or 128
  const int quad = lane >> 4, l16 = lane & 15;

  floatx4 acc[4][8] = {};

  // A staging: 2 threads/row (rows 0..127), 32 halves each
  const int srow = tid >> 1;
  const int skoff = (tid & 1) << 5;
  const int arow = m0 + srow;
  const bool aok = arow < M;
  const _Float16* Ag = A + (size_t)arow*HD + skoff;
  _Float16* Asw = As + srow*PK + skoff;
  // B staging: 1 thread/row (rows 0..255), 64 halves each (full BK)
  const _Float16* Bg = Wt + (size_t)(n0 + tid)*HD;
  _Float16* Bsw = Bs + tid*PK;

  for (int kt = 0; kt < HD; kt += 64){
    half8 a0={},a1={},a2={},a3={};
    if (aok){
      a0 = *(const half8*)(Ag + kt);      a1 = *(const half8*)(Ag + kt + 8);
      a2 = *(const half8*)(Ag + kt + 16); a3 = *(const half8*)(Ag + kt + 24);
    }
    half8 b0 = *(const half8*)(Bg + kt);      half8 b1 = *(const half8*)(Bg + kt + 8);
    half8 b2 = *(const half8*)(Bg + kt + 16); half8 b3 = *(const half8*)(Bg + kt + 24);
    half8 b4 = *(const half8*)(Bg + kt + 32); half8 b5 = *(const half8*)(Bg + kt + 40);
    half8 b6 = *(const half8*)(Bg + kt + 48); half8 b7 = *(const half8*)(Bg + kt + 56);
    __syncthreads();
    *(half8*)(Asw)      = a0; *(half8*)(Asw + 8)  = a1;
    *(half8*)(Asw + 16) = a2; *(half8*)(Asw + 24) = a3;
    *(half8*)(Bsw)      = b0; *(half8*)(Bsw + 8)  = b1;
    *(half8*)(Bsw + 16) = b2; *(half8*)(Bsw + 24) = b3;
    *(half8*)(Bsw + 32) = b4; *(half8*)(Bsw + 40) = b5;
    *(half8*)(Bsw + 48) = b6; *(half8*)(Bsw + 56) = b7;
    __syncthreads();
    #pragma unroll
    for (int k0 = 0; k0 < 64; k0 += 32){
      half8 bf[8];
      #pragma unroll
      for (int ni = 0; ni < 8; ni++)
        bf[ni] = *(const half8*)&Bs[(wn + ni*16 + l16)*PK + k0 + quad*8];
      #pragma unroll
      for (int mi = 0; mi < 4; mi++){
        half8 af = *(const half8*)&As[(wm + mi*16 + l16)*PK + k0 + quad*8];
        #pragma unroll
        for (int ni = 0; ni < 8; ni++){
          acc[mi][ni] = __builtin_amdgcn_mfma_f32_16x16x32_f16(af, bf[ni], acc[mi][ni], 0, 0, 0);
        }
      }
    }
  }

  float sv[8] = {}, qv[8] = {};
  #pragma unroll
  for (int ni = 0; ni < 8; ni++){
    int ccol = n0 + wn + ni*16 + l16;
    float bs = bias[ccol];
    #pragma unroll
    for (int mi = 0; mi < 4; mi++){
      #pragma unroll
      for (int reg = 0; reg < 4; reg++){
        int r = m0 + wm + mi*16 + quad*4 + reg;
        float v = acc[mi][ni][reg] + bs;
        v = v > 0.f ? v : 0.f;
        if (r < M){
          C[(size_t)r*HD + ccol] = (_Float16)v;
          if (STATS){ sv[ni] += v; qv[ni] += v*v; }
        }
      }
    }
  }
  if (STATS){
    #pragma unroll
    for (int ni = 0; ni < 8; ni++){
      float s = sv[ni], q = qv[ni];
      s += __shfl_xor(s, 16); s += __shfl_xor(s, 32);
      q += __shfl_xor(q, 16); q += __shfl_xor(q, 32);
      if (quad == 0){
        int ccol = n0 + wn + ni*16 + l16;
        unsafeAtomicAdd(&st[ccol], s);
        unsafeAtomicAdd(&st[HD+ccol], q);
      }
    }
  }
}

// ---------------- fused head with per-block LDS min/max reduction ----------------
__global__ __launch_bounds__(256) void k_head(const _Float16* __restrict__ Xh,
    const _Float16* __restrict__ W1t, const float* __restrict__ b1,
    const float* __restrict__ w2, const float* __restrict__ b2p,
    const int* __restrict__ mask, const int* __restrict__ batch,
    float* __restrict__ z2, unsigned* __restrict__ mx, unsigned* __restrict__ mn, int M)
{
  constexpr int PK = 72;
  __shared__ __attribute__((aligned(16))) _Float16 As[128*PK];
  __shared__ __attribute__((aligned(16))) _Float16 Bs[64*PK];
  __shared__ unsigned smx[64], smn[64];
  const int tid = threadIdx.x;
  const int m0 = blockIdx.x * 128;
  const int w = tid >> 6, lane = tid & 63;
  const int wm = w << 5;
  const int quad = lane >> 4, l16 = lane & 15;

  if (tid < 64){ smx[tid] = 0u; smn[tid] = 0xFFFFFFFFu; }

  floatx4 acc[2][4] = {};

  const int srow = tid >> 1;
  const int skoff = (tid & 1) << 5;
  const int arow = m0 + srow;
  const bool aok = arow < M;
  const _Float16* Ag = Xh + (size_t)arow*HD + skoff;
  _Float16* Asw = As + srow*PK + skoff;
  const int brow = tid >> 2;
  const int bkoff = (tid & 3) << 4;
  const _Float16* Bg = W1t + (size_t)brow*HD + bkoff;
  _Float16* Bsw = Bs + brow*PK + bkoff;

  for (int kt = 0; kt < HD; kt += 64){
    half8 a0={},a1={},a2={},a3={};
    if (aok){
      a0 = *(const half8*)(Ag + kt);      a1 = *(const half8*)(Ag + kt + 8);
      a2 = *(const half8*)(Ag + kt + 16); a3 = *(const half8*)(Ag + kt + 24);
    }
    half8 b0 = *(const half8*)(Bg + kt);  half8 b1h = *(const half8*)(Bg + kt + 8);
    __syncthreads();
    *(half8*)(Asw)      = a0; *(half8*)(Asw + 8)  = a1;
    *(half8*)(Asw + 16) = a2; *(half8*)(Asw + 24) = a3;
    *(half8*)(Bsw)      = b0; *(half8*)(Bsw + 8)  = b1h;
    __syncthreads();
    #pragma unroll
    for (int k0 = 0; k0 < 64; k0 += 32){
      half8 af[2], bf[4];
      #pragma unroll
      for (int mi = 0; mi < 2; mi++) af[mi] = *(const half8*)&As[(wm + mi*16 + l16)*PK + k0 + quad*8];
      #pragma unroll
      for (int ni = 0; ni < 4; ni++) bf[ni] = *(const half8*)&Bs[(ni*16 + l16)*PK + k0 + quad*8];
      #pragma unroll
      for (int mi = 0; mi < 2; mi++){
        #pragma unroll
        for (int ni = 0; ni < 4; ni++){
          acc[mi][ni] = __builtin_amdgcn_mfma_f32_16x16x32_f16(af[mi], bf[ni], acc[mi][ni], 0, 0, 0);
        }
      }
    }
  }

  float b1v[4], w2v[4];
  #pragma unroll
  for (int ni = 0; ni < 4; ni++){ b1v[ni] = b1[ni*16 + l16]; w2v[ni] = w2[ni*16 + l16]; }
  const float b2 = b2p[0];
  #pragma unroll
  for (int mi = 0; mi < 2; mi++){
    #pragma unroll
    for (int reg = 0; reg < 4; reg++){
      int r = m0 + wm + mi*16 + quad*4 + reg;
      bool ok = r < M;
      float mk = (ok && mask[r]) ? 1.f : 0.f;
      float t = 0.f;
      #pragma unroll
      for (int ni = 0; ni < 4; ni++){
        float v = leaky(acc[mi][ni][reg] + b1v[ni]) * mk;
        t += v * w2v[ni];
      }
      t += __shfl_xor(t, 1); t += __shfl_xor(t, 2);
      t += __shfl_xor(t, 4); t += __shfl_xor(t, 8);
      if (l16 == 0 && ok){
        float zv = leaky(t + b2) * mk;
        z2[r] = zv;
        unsigned u = __float_as_uint(zv);
        unsigned key = (u & 0x80000000u) ? ~u : (u | 0x80000000u);
        int gg = batch[r];
        atomicMax(&smx[gg], key); atomicMin(&smn[gg], key);
      }
    }
  }
  __syncthreads();
  if (tid < 64){
    unsigned vx = smx[tid], vn = smn[tid];
    if (vx != 0u)          atomicMax(&mx[tid], vx);
    if (vn != 0xFFFFFFFFu) atomicMin(&mn[tid], vn);
  }
}

// ---------------- BN apply: T = (affineP(T_prev) + leaky(bn(Hin)))*mask*invs ; stats of T -> st2 ----------------
template<bool RESID>
__global__ void k_bn_apply_stats(const unsigned* __restrict__ Hu, const float* __restrict__ g,
    const float* __restrict__ bb, const float* __restrict__ st,
    const unsigned* __restrict__ Pu, const float* __restrict__ stP,
    const float* __restrict__ gP, const float* __restrict__ bP,
    const int* __restrict__ mask, const float* __restrict__ invs,
    unsigned* __restrict__ Tu, float* __restrict__ st2)
{
  int tid = threadIdx.x; int c = tid<<1;
  const float inv_n = 1.f/(float)NN;
  float mu0 = st[c]*inv_n, mu1 = st[c+1]*inv_n;
  float var0 = st[HD+c]*inv_n - mu0*mu0;
  float var1 = st[HD+c+1]*inv_n - mu1*mu1;
  float sc0 = g[c]*rsqrtf(var0+BN_EPS), sc1 = g[c+1]*rsqrtf(var1+BN_EPS);
  float sh0 = bb[c] - mu0*sc0, sh1 = bb[c+1] - mu1*sc1;
  float pc0=0.f, pc1=0.f, ps0=0.f, ps1=0.f;
  if (RESID){
    float muP0 = stP[c]*inv_n, muP1 = stP[c+1]*inv_n;
    float varP0 = stP[HD+c]*inv_n - muP0*muP0;
    float varP1 = stP[HD+c+1]*inv_n - muP1*muP1;
    pc0 = gP[c]*rsqrtf(varP0+BN_EPS); pc1 = gP[c+1]*rsqrtf(varP1+BN_EPS);
    ps0 = bP[c] - muP0*pc0; ps1 = bP[c+1] - muP1*pc1;
  }
  float s0=0,s1=0,q0=0,q1=0;
  for (int r = blockIdx.x; r < NN; r += gridDim.x){
    unsigned u = Hu[(size_t)r*256 + tid];
    float v0 = leaky(fmaf(h2fu(u&0xFFFF), sc0, sh0));
    float v1 = leaky(fmaf(h2fu(u>>16),   sc1, sh1));
    if (RESID){
      unsigned pu = Pu[(size_t)r*256 + tid];
      v0 += fmaf(h2fu(pu&0xFFFF), pc0, ps0);
      v1 += fmaf(h2fu(pu>>16),    pc1, ps1);
    }
    float ww = mask[r] ? invs[r] : 0.f;
    v0 *= ww; v1 *= ww;
    Tu[(size_t)r*256 + tid] = packh2(v0, v1);
    s0+=v0; s1+=v1; q0+=v0*v0; q1+=v1*v1;
  }
  unsafeAtomicAdd(&st2[c],s0);      unsafeAtomicAdd(&st2[c+1],s1);
  unsafeAtomicAdd(&st2[HD+c],q0);   unsafeAtomicAdd(&st2[HD+c+1],q1);
}
// Xh(fp16) = affine(T) with stats st, params g,bb  (used once, before head)
__global__ void k_bn_final(const unsigned* __restrict__ Tu, const float* __restrict__ g,
    const float* __restrict__ bb, const float* __restrict__ st, unsigned* __restrict__ Xhu)
{
  long i = (long)blockIdx.x*blockDim.x + threadIdx.x;
  if (i >= (long)NN*256) return;
  int c = ((int)(i & 255)) << 1;
  const float inv_n = 1.f/(float)NN;
  float mu0 = st[c]*inv_n, mu1 = st[c+1]*inv_n;
  float var0 = st[HD+c]*inv_n - mu0*mu0;
  float var1 = st[HD+c+1]*inv_n - mu1*mu1;
  float sc0 = g[c]*rsqrtf(var0+BN_EPS), sc1 = g[c+1]*rsqrtf(var1+BN_EPS);
  float sh0 = bb[c] - mu0*sc0, sh1 = bb[c+1] - mu1*sc1;
  unsigned u = Tu[i];
  Xhu[i] = packh2(fmaf(h2fu(u&0xFFFF), sc0, sh0), fmaf(h2fu(u>>16), sc1, sh1));
}

// ---------------- final normalize ----------------
__device__ __forceinline__ float funkey(unsigned k){
  unsigned u = (k & 0x80000000u) ? (k & 0x7fffffffu) : ~k;
  return __uint_as_float(u);
}
__global__ void k_final(const float* __restrict__ z2, const int* __restrict__ batch,
                        const unsigned* __restrict__ mx, const unsigned* __restrict__ mn,
                        float* __restrict__ out){
  int i = blockIdx.x*blockDim.x + threadIdx.x;
  if (i < NN){
    int g = batch[i];
    float bmax = funkey(mx[g]), bmin = funkey(mn[g]);
    out[i] = (z2[i] - bmin) / ((bmax + 1e-6f) - bmin);
  }
}

extern "C" void kernel_launch(void* const* d_in, const int* in_sizes, int n_in,
                              void* d_out, int out_size, void* d_ws, size_t ws_size,
                              hipStream_t stream)
{
  const float* x      = (const float*)d_in[0];
  const int*   ei     = (const int*)d_in[1];
  const int*   src    = ei;
  const int*   dst    = ei + NE;
  const int*   batch  = (const int*)d_in[2];
  const float* c1_w1  = (const float*)d_in[3];
  const float* c1_b1  = (const float*)d_in[4];
  const float* c1_w2  = (const float*)d_in[5];
  const float* c1_b2  = (const float*)d_in[6];
  const float* c1_bng = (const float*)d_in[7];
  const float* c1_bnb = (const float*)d_in[8];
  const float* eps1   = (const float*)d_in[9];
  const float* bn1_g  = (const float*)d_in[10];
  const float* bn1_b  = (const float*)d_in[11];
  const float* cw1    = (const float*)d_in[12];
  const float* cb1    = (const float*)d_in[13];
  const float* cw2    = (const float*)d_in[14];
  const float* cb2    = (const float*)d_in[15];
  const float* cbn_g  = (const float*)d_in[16];
  const float* cbn_b  = (const float*)d_in[17];
  const float* ceps   = (const float*)d_in[18];
  const float* bns_g  = (const float*)d_in[19];
  const float* bns_b  = (const float*)d_in[20];
  const float* l1_w   = (const float*)d_in[21];
  const float* l1_b   = (const float*)d_in[22];
  const float* l2_w   = (const float*)d_in[23];
  const float* l2_b   = (const float*)d_in[24];
  float* out = (float*)d_out;

  const size_t NH = (size_t)NN*HD;
  unsigned short* buf0 = (unsigned short*)d_ws;   // fp16 NH
  unsigned short* buf1 = buf0 + NH;               // fp16 NH
  unsigned short* buf2 = buf1 + NH;               // fp16 NH
  float* h0   = (float*)(buf2 + NH);              // NN
  float* invs = h0 + NN;                          // NN
  float* z2   = invs + NN;                        // NN
  float* stG  = z2 + NN;                          // 1024
  float* stT  = stG + 1024;                       // 4 x 1024
  int* counts = (int*)(stT + 4*1024);             // 64
  unsigned* mx = (unsigned*)(counts + 64);        // 64
  unsigned* mn = mx + 64;                         // 64
  int* deg  = (int*)(mn + 64);                    // NN
  int* off  = deg + NN;                           // NN
  int* cur  = off + NN;                           // NN
  int* srcs = cur + NN;                           // NE
  int* m[5];
  m[0] = srcs + NE;
  for (int k=1;k<5;k++) m[k] = m[k-1] + NN;
  unsigned short* wt[7];
  wt[0] = (unsigned short*)(m[4] + NN);
  for (int k=1;k<7;k++) wt[k] = wt[k-1] + HD*HD;
  unsigned short* w1t = wt[6] + HD*HD;            // 64*512 fp16

  const int TPB = 256;
  dim3 gN((NN+TPB-1)/TPB);
  dim3 gE((NE+TPB-1)/TPB);
  dim3 gNH((unsigned)((NH + TPB-1)/TPB));
  dim3 gNH2((unsigned)((NH/2 + TPB-1)/TPB));
  dim3 gmfma((NN+127)/128, HD/256);
  dim3 gtr(HD/32, HD/32);
  dim3 ghead((NN+127)/128);

  // setup
  k_counts_bs<<<1, 64, 0, stream>>>(batch, counts);
  k_invs_mask0<<<gN, TPB, 0, stream>>>(batch, counts, x, invs, m[0]);
  for (int k=1;k<5;k++){
    k_mask_copy<<<gN,TPB,0,stream>>>(m[k-1], m[k]);
    k_mask_prop<<<gE,TPB,0,stream>>>(m[k-1], m[k], src, dst);
  }
  // CSR by dst
  hipMemsetAsync(deg, 0, NN*sizeof(int), stream);
  k_deg<<<gE,TPB,0,stream>>>(dst, deg);
  k_scan<<<1,1024,0,stream>>>(deg, off, cur);
  k_scatter<<<gE,TPB,0,stream>>>(src, dst, cur, srcs);
  // weight prep (fp16 transposed)
  k_w2ht<<<gtr,256,0,stream>>>(c1_w2, wt[0], HD, HD);
  for (int i=0;i<3;i++){
    k_w2ht<<<gtr,256,0,stream>>>(cw1 + (size_t)i*HD*HD, wt[1+i], HD, HD);
    k_w2ht<<<gtr,256,0,stream>>>(cw2 + (size_t)i*HD*HD, wt[4+i], HD, HD);
  }
  k_w2ht<<<dim3(HD/32, HIDN/32),256,0,stream>>>(l1_w, w1t, HD, HIDN);

  // conv1: h1->buf1, gemm(+stats)->buf2, apply<false>->buf0 (= T0, stats stT[0])
  k_sagg_csr<<<gN,TPB,0,stream>>>(x, off, deg, srcs, eps1, h0);
  k_conv1_h1<<<gNH,TPB,0,stream>>>(h0, c1_w1, c1_b1, buf1);
  hipMemsetAsync(stG, 0, 1024*sizeof(float), stream);
  k_gemm_mfma<true><<<gmfma,256,0,stream>>>((const _Float16*)buf1, (const _Float16*)wt[0], c1_b2, (_Float16*)buf2, stG, NN);
  hipMemsetAsync(stT, 0, 1024*sizeof(float), stream);
  k_bn_apply_stats<false><<<512,256,0,stream>>>((unsigned*)buf2, c1_bng, c1_bnb, stG,
      nullptr, nullptr, nullptr, nullptr, m[1], invs, (unsigned*)buf0, stT);

  // rotation state
  unsigned short *P = buf0, *Q = buf1, *R = buf2;
  const float* stPrev = stT;
  const float* gPrev = bn1_g;
  const float* bPrev = bn1_b;

  for (int i=0;i<3;i++){
    k_agg_csr<<<NN,64,0,stream>>>((const _Float16*)P, off, deg, srcs, ceps+i,
                                  stPrev, gPrev, bPrev, (_Float16*)Q);
    k_gemm_mfma<false><<<gmfma,256,0,stream>>>((const _Float16*)Q, (const _Float16*)wt[1+i], cb1 + (size_t)i*HD, (_Float16*)R, nullptr, NN);
    hipMemsetAsync(stG, 0, 1024*sizeof(float), stream);
    k_gemm_mfma<true><<<gmfma,256,0,stream>>>((const _Float16*)R, (const _Float16*)wt[4+i], cb2 + (size_t)i*HD, (_Float16*)Q, stG, NN);
    float* stCur = stT + (i+1)*1024;
    hipMemsetAsync(stCur, 0, 1024*sizeof(float), stream);
    k_bn_apply_stats<true><<<512,256,0,stream>>>((unsigned*)Q, cbn_g + (size_t)i*HD, cbn_b + (size_t)i*HD, stG,
        (unsigned*)P, stPrev, gPrev, bPrev, m[i+2], invs, (unsigned*)R, stCur);
    unsigned short* tmp = P; P = R; R = tmp;
    stPrev = stCur;
    gPrev = bns_g + (size_t)i*HD;
    bPrev = bns_b + (size_t)i*HD;
  }

  // materialize Xh once: Q = affinePrev(P)
  k_bn_final<<<gNH2,TPB,0,stream>>>((const unsigned*)P, gPrev, bPrev, stPrev, (unsigned*)Q);

  // head: fused lin1+lin2 + per-block LDS minmax, then normalize
  hipMemsetAsync(mx, 0x00, 64*sizeof(unsigned), stream);
  hipMemsetAsync(mn, 0xFF, 64*sizeof(unsigned), stream);
  k_head<<<ghead,256,0,stream>>>((const _Float16*)Q, (const _Float16*)w1t, l1_b, l2_w, l2_b,
                                 m[4], batch, z2, mx, mn, NN);
  k_final<<<gN,TPB,0,stream>>>(z2, batch, mx, mn, out);
}

// Round 10
// 1436.196 us; speedup vs baseline: 1.3189x; 1.3189x over previous
//
#include <hip/hip_runtime.h>
#include <hip/hip_fp16.h>

#define NN 50000
#define NE 150000
#define HD 512
#define HIDN 64
#define BN_EPS 1e-5f
#define SLOPE 0.01f

typedef _Float16 half8 __attribute__((ext_vector_type(8)));
typedef float floatx4 __attribute__((ext_vector_type(4)));

__device__ __forceinline__ float leaky(float v){ return v > 0.f ? v : SLOPE*v; }
__device__ __forceinline__ float h2fu(unsigned short u){ return __half2float(__ushort_as_half(u)); }
__device__ __forceinline__ unsigned short f2hu(float f){ return __half_as_ushort(__float2half(f)); }
__device__ __forceinline__ unsigned packh2(float a, float b){
  return (unsigned)f2hu(a) | ((unsigned)f2hu(b) << 16);
}

// ---------------- setup ----------------
// batch is sorted -> per-graph counts via binary search (no atomics)
__global__ void k_counts_bs(const int* __restrict__ batch, int* __restrict__ counts){
  int g = threadIdx.x;   // 0..63
  int lo = 0, hi = NN;
  while (lo < hi){ int mid = (lo+hi)>>1; if (batch[mid] <  g) lo = mid+1; else hi = mid; }
  int start = lo;
  lo = 0; hi = NN;
  while (lo < hi){ int mid = (lo+hi)>>1; if (batch[mid] <= g) lo = mid+1; else hi = mid; }
  counts[g] = lo - start;
}
__global__ void k_invs_mask0(const int* __restrict__ batch, const int* __restrict__ counts,
                             const float* __restrict__ x, float* __restrict__ invs, int* __restrict__ m0){
  int i = blockIdx.x*blockDim.x + threadIdx.x;
  if (i < NN){
    invs[i] = rsqrtf((float)counts[batch[i]]);
    m0[i] = (fabsf(x[i]) > 0.f) ? 1 : 0;
  }
}
__global__ void k_mask_copy(const int* __restrict__ a, int* __restrict__ b){
  int i = blockIdx.x*blockDim.x + threadIdx.x;
  if (i < NN) b[i] = a[i];
}
__global__ void k_mask_prop(const int* __restrict__ mi, int* __restrict__ mo,
                            const int* __restrict__ src, const int* __restrict__ dst){
  int e = blockIdx.x*blockDim.x + threadIdx.x;
  if (e < NE){ if (mi[src[e]]) atomicOr(&mo[dst[e]], 1); }
}

// ---------------- CSR build (by dst) ----------------
__global__ void k_deg(const int* __restrict__ dst, int* __restrict__ deg){
  int e = blockIdx.x*blockDim.x + threadIdx.x;
  if (e < NE) atomicAdd(&deg[dst[e]], 1);
}
#define SCAN_CHUNK 49  // 1024*49 = 50176 >= NN
__global__ void k_scan(const int* __restrict__ deg, int* __restrict__ off, int* __restrict__ cur){
  __shared__ int part[1024];
  int t = threadIdx.x;
  int base = t * SCAN_CHUNK;
  int s = 0;
  for (int j = 0; j < SCAN_CHUNK; j++){ int i = base + j; if (i < NN) s += deg[i]; }
  part[t] = s;
  __syncthreads();
  for (int d = 1; d < 1024; d <<= 1){
    int add = (t >= d) ? part[t - d] : 0;
    __syncthreads();
    part[t] += add;
    __syncthreads();
  }
  int run = part[t] - s;
  for (int j = 0; j < SCAN_CHUNK; j++){
    int i = base + j;
    if (i < NN){ off[i] = run; cur[i] = run; run += deg[i]; }
  }
}
__global__ void k_scatter(const int* __restrict__ src, const int* __restrict__ dst,
                          int* __restrict__ cur, int* __restrict__ srcs){
  int e = blockIdx.x*blockDim.x + threadIdx.x;
  if (e < NE){
    int pos = atomicAdd(&cur[dst[e]], 1);
    srcs[pos] = src[e];
  }
}

// ---------------- weight prep: Wt[n][k] fp16 = W[k][n] fp32 ----------------
__global__ void k_w2ht(const float* __restrict__ W, unsigned short* __restrict__ Wt, int K, int N){
  __shared__ float t[32][33];
  int kb = blockIdx.x*32, nb = blockIdx.y*32;
  int tx = threadIdx.x & 31, ty = threadIdx.x >> 5;   // 32 x 8
  for (int r = 0; r < 32; r += 8)
    t[ty+r][tx] = W[(size_t)(kb+ty+r)*N + nb+tx];
  __syncthreads();
  for (int r = 0; r < 32; r += 8)
    Wt[(size_t)(nb+ty+r)*K + kb+tx] = f2hu(t[tx][ty+r]);
}

// ---------------- conv1 front ----------------
__global__ void k_sagg_csr(const float* __restrict__ x, const int* __restrict__ off,
                           const int* __restrict__ deg, const int* __restrict__ srcs,
                           const float* __restrict__ epsp, float* __restrict__ h0){
  int i = blockIdx.x*blockDim.x + threadIdx.x;
  if (i < NN){
    float s = (1.f + epsp[0]) * x[i];
    int o = off[i], d = deg[i];
    for (int j = 0; j < d; j++) s += x[srcs[o + j]];
    h0[i] = s;
  }
}
__global__ void k_conv1_h1(const float* __restrict__ h0, const float* __restrict__ w1,
                           const float* __restrict__ b1, unsigned short* __restrict__ C){
  long idx = (long)blockIdx.x*blockDim.x + threadIdx.x;
  if (idx >= (long)NN*HD) return;
  int i = (int)(idx >> 9), c = (int)(idx & (HD-1));
  float v = fmaf(h0[i], w1[c], b1[c]);
  C[idx] = f2hu(v > 0.f ? v : 0.f);
}

// ---------------- gather+combine with on-the-fly BN affine ----------------
__global__ void k_agg_csr(const _Float16* __restrict__ T, const int* __restrict__ off,
                          const int* __restrict__ deg, const int* __restrict__ srcs,
                          const float* __restrict__ epsp,
                          const float* __restrict__ st, const float* __restrict__ g,
                          const float* __restrict__ bb, _Float16* __restrict__ G){
  int i = blockIdx.x;
  int t = threadIdx.x;          // 64 threads, 8 channels each
  int c0 = t << 3;
  const float inv_n = 1.f/(float)NN;
  float sc[8], sh[8];
  #pragma unroll
  for (int k = 0; k < 8; k++){
    int c = c0 + k;
    float mu = st[c]*inv_n;
    float var = st[HD+c]*inv_n - mu*mu;
    float s = g[c]*rsqrtf(var+BN_EPS);
    sc[k] = s; sh[k] = bb[c] - mu*s;
  }
  const half8* Tv = (const half8*)T;
  half8 p = Tv[(size_t)i*64 + t];
  float ep = 1.f + epsp[0];
  float acc[8];
  #pragma unroll
  for (int k = 0; k < 8; k++) acc[k] = (float)p[k] * ep;
  int o = off[i], d = deg[i];
  for (int j = 0; j < d; j++){
    int s = srcs[o + j];
    half8 q = Tv[(size_t)s*64 + t];
    #pragma unroll
    for (int k = 0; k < 8; k++) acc[k] += (float)q[k];
  }
  float cnt = ep + (float)d;
  half8 r;
  #pragma unroll
  for (int k = 0; k < 8; k++) r[k] = (_Float16)fmaf(sc[k], acc[k], cnt*sh[k]);
  ((half8*)G)[(size_t)i*64 + t] = r;
}

// ---------------- MFMA GEMM: C[Mx512](fp16) = relu(A[Mx512] @ W + b), optional fused BN stats ----------------
// 128x128 tile, 4 waves x (64x64 = 4x4 MFMA 16x16x32), BK=64, register staging, padded LDS.
// NOTE (r9): 128x256 retile regressed 98->170us: LDS 55KB -> 2 blocks/CU killed the
// cross-block barrier-drain overlap. blocks/CU > per-wave MFMA density in this structure.
template<bool STATS>
__global__ __launch_bounds__(256) void k_gemm_mfma(const _Float16* __restrict__ A,
    const _Float16* __restrict__ Wt, const float* __restrict__ bias,
    _Float16* __restrict__ C, float* __restrict__ st, int M)
{
  constexpr int PK = 72;
  __shared__ __attribute__((aligned(16))) _Float16 As[128*PK];
  __shared__ __attribute__((aligned(16))) _Float16 Bs[128*PK];
  const int tid = threadIdx.x;
  const int m0 = blockIdx.x * 128;
  const int n0 = blockIdx.y * 128;
  const int w = tid >> 6, lane = tid & 63;
  const int wm = (w >> 1) << 6, wn = (w & 1) << 6;
  const int quad = lane >> 4, l16 = lane & 15;

  floatx4 acc[4][4] = {};

  const int srow = tid >> 1;                 // 0..127
  const int skoff = (tid & 1) << 5;          // 0 or 32 halves
  const int arow = m0 + srow;
  const bool aok = arow < M;
  const _Float16* Ag = A  + (size_t)arow*HD + skoff;
  const _Float16* Bg = Wt + (size_t)(n0 + srow)*HD + skoff;
  _Float16* Asw = As + srow*PK + skoff;
  _Float16* Bsw = Bs + srow*PK + skoff;

  for (int kt = 0; kt < HD; kt += 64){
    half8 a0={},a1={},a2={},a3={};
    if (aok){
      a0 = *(const half8*)(Ag + kt);      a1 = *(const half8*)(Ag + kt + 8);
      a2 = *(const half8*)(Ag + kt + 16); a3 = *(const half8*)(Ag + kt + 24);
    }
    half8 b0 = *(const half8*)(Bg + kt);      half8 b1 = *(const half8*)(Bg + kt + 8);
    half8 b2 = *(const half8*)(Bg + kt + 16); half8 b3 = *(const half8*)(Bg + kt + 24);
    __syncthreads();
    *(half8*)(Asw)      = a0; *(half8*)(Asw + 8)  = a1;
    *(half8*)(Asw + 16) = a2; *(half8*)(Asw + 24) = a3;
    *(half8*)(Bsw)      = b0; *(half8*)(Bsw + 8)  = b1;
    *(half8*)(Bsw + 16) = b2; *(half8*)(Bsw + 24) = b3;
    __syncthreads();
    #pragma unroll
    for (int k0 = 0; k0 < 64; k0 += 32){
      half8 af[4], bf[4];
      #pragma unroll
      for (int t4 = 0; t4 < 4; t4++){
        af[t4] = *(const half8*)(As + (wm + t4*16 + l16)*PK + k0 + quad*8);
        bf[t4] = *(const half8*)(Bs + (wn + t4*16 + l16)*PK + k0 + quad*8);
      }
      #pragma unroll
      for (int mi = 0; mi < 4; mi++){
        #pragma unroll
        for (int ni = 0; ni < 4; ni++){
          acc[mi][ni] = __builtin_amdgcn_mfma_f32_16x16x32_f16(af[mi], bf[ni], acc[mi][ni], 0, 0, 0);
        }
      }
    }
  }

  // epilogue: D row = quad*4+reg, col = l16 ; bias+relu+store (+stats)
  float sv[4] = {0,0,0,0}, qv[4] = {0,0,0,0};
  #pragma unroll
  for (int ni = 0; ni < 4; ni++){
    int ccol = n0 + wn + ni*16 + l16;
    float bs = bias[ccol];
    #pragma unroll
    for (int mi = 0; mi < 4; mi++){
      #pragma unroll
      for (int reg = 0; reg < 4; reg++){
        int r = m0 + wm + mi*16 + quad*4 + reg;
        float v = acc[mi][ni][reg] + bs;
        v = v > 0.f ? v : 0.f;
        if (r < M){
          C[(size_t)r*HD + ccol] = (_Float16)v;
          if (STATS){ sv[ni] += v; qv[ni] += v*v; }
        }
      }
    }
  }
  if (STATS){
    #pragma unroll
    for (int ni = 0; ni < 4; ni++){
      float s = sv[ni], q = qv[ni];
      s += __shfl_xor(s, 16); s += __shfl_xor(s, 32);
      q += __shfl_xor(q, 16); q += __shfl_xor(q, 32);
      if (quad == 0){
        int ccol = n0 + wn + ni*16 + l16;
        unsafeAtomicAdd(&st[ccol], s);
        unsafeAtomicAdd(&st[HD+ccol], q);
      }
    }
  }
}

// ---------------- fused head with per-block LDS min/max reduction ----------------
__global__ __launch_bounds__(256) void k_head(const _Float16* __restrict__ Xh,
    const _Float16* __restrict__ W1t, const float* __restrict__ b1,
    const float* __restrict__ w2, const float* __restrict__ b2p,
    const int* __restrict__ mask, const int* __restrict__ batch,
    float* __restrict__ z2, unsigned* __restrict__ mx, unsigned* __restrict__ mn, int M)
{
  constexpr int PK = 72;
  __shared__ __attribute__((aligned(16))) _Float16 As[128*PK];
  __shared__ __attribute__((aligned(16))) _Float16 Bs[64*PK];
  __shared__ unsigned smx[64], smn[64];
  const int tid = threadIdx.x;
  const int m0 = blockIdx.x * 128;
  const int w = tid >> 6, lane = tid & 63;
  const int wm = w << 5;
  const int quad = lane >> 4, l16 = lane & 15;

  if (tid < 64){ smx[tid] = 0u; smn[tid] = 0xFFFFFFFFu; }

  floatx4 acc[2][4] = {};

  const int srow = tid >> 1;
  const int skoff = (tid & 1) << 5;
  const int arow = m0 + srow;
  const bool aok = arow < M;
  const _Float16* Ag = Xh + (size_t)arow*HD + skoff;
  _Float16* Asw = As + srow*PK + skoff;
  const int brow = tid >> 2;
  const int bkoff = (tid & 3) << 4;
  const _Float16* Bg = W1t + (size_t)brow*HD + bkoff;
  _Float16* Bsw = Bs + brow*PK + bkoff;

  for (int kt = 0; kt < HD; kt += 64){
    half8 a0={},a1={},a2={},a3={};
    if (aok){
      a0 = *(const half8*)(Ag + kt);      a1 = *(const half8*)(Ag + kt + 8);
      a2 = *(const half8*)(Ag + kt + 16); a3 = *(const half8*)(Ag + kt + 24);
    }
    half8 b0 = *(const half8*)(Bg + kt);  half8 b1h = *(const half8*)(Bg + kt + 8);
    __syncthreads();
    *(half8*)(Asw)      = a0; *(half8*)(Asw + 8)  = a1;
    *(half8*)(Asw + 16) = a2; *(half8*)(Asw + 24) = a3;
    *(half8*)(Bsw)      = b0; *(half8*)(Bsw + 8)  = b1h;
    __syncthreads();
    #pragma unroll
    for (int k0 = 0; k0 < 64; k0 += 32){
      half8 af[2], bf[4];
      #pragma unroll
      for (int mi = 0; mi < 2; mi++) af[mi] = *(const half8*)&As[(wm + mi*16 + l16)*PK + k0 + quad*8];
      #pragma unroll
      for (int ni = 0; ni < 4; ni++) bf[ni] = *(const half8*)&Bs[(ni*16 + l16)*PK + k0 + quad*8];
      #pragma unroll
      for (int mi = 0; mi < 2; mi++){
        #pragma unroll
        for (int ni = 0; ni < 4; ni++){
          acc[mi][ni] = __builtin_amdgcn_mfma_f32_16x16x32_f16(af[mi], bf[ni], acc[mi][ni], 0, 0, 0);
        }
      }
    }
  }

  float b1v[4], w2v[4];
  #pragma unroll
  for (int ni = 0; ni < 4; ni++){ b1v[ni] = b1[ni*16 + l16]; w2v[ni] = w2[ni*16 + l16]; }
  const float b2 = b2p[0];
  #pragma unroll
  for (int mi = 0; mi < 2; mi++){
    #pragma unroll
    for (int reg = 0; reg < 4; reg++){
      int r = m0 + wm + mi*16 + quad*4 + reg;
      bool ok = r < M;
      float mk = (ok && mask[r]) ? 1.f : 0.f;
      float t = 0.f;
      #pragma unroll
      for (int ni = 0; ni < 4; ni++){
        float v = leaky(acc[mi][ni][reg] + b1v[ni]) * mk;
        t += v * w2v[ni];
      }
      t += __shfl_xor(t, 1); t += __shfl_xor(t, 2);
      t += __shfl_xor(t, 4); t += __shfl_xor(t, 8);
      if (l16 == 0 && ok){
        float zv = leaky(t + b2) * mk;
        z2[r] = zv;
        unsigned u = __float_as_uint(zv);
        unsigned key = (u & 0x80000000u) ? ~u : (u | 0x80000000u);
        int gg = batch[r];
        atomicMax(&smx[gg], key); atomicMin(&smn[gg], key);
      }
    }
  }
  __syncthreads();
  if (tid < 64){
    unsigned vx = smx[tid], vn = smn[tid];
    if (vx != 0u)          atomicMax(&mx[tid], vx);
    if (vn != 0xFFFFFFFFu) atomicMin(&mn[tid], vn);
  }
}

// ---------------- BN apply: T = (affineP(T_prev) + leaky(bn(Hin)))*mask*invs ; stats of T -> st2 ----------------
template<bool RESID>
__global__ void k_bn_apply_stats(const unsigned* __restrict__ Hu, const float* __restrict__ g,
    const float* __restrict__ bb, const float* __restrict__ st,
    const unsigned* __restrict__ Pu, const float* __restrict__ stP,
    const float* __restrict__ gP, const float* __restrict__ bP,
    const int* __restrict__ mask, const float* __restrict__ invs,
    unsigned* __restrict__ Tu, float* __restrict__ st2)
{
  int tid = threadIdx.x; int c = tid<<1;
  const float inv_n = 1.f/(float)NN;
  float mu0 = st[c]*inv_n, mu1 = st[c+1]*inv_n;
  float var0 = st[HD+c]*inv_n - mu0*mu0;
  float var1 = st[HD+c+1]*inv_n - mu1*mu1;
  float sc0 = g[c]*rsqrtf(var0+BN_EPS), sc1 = g[c+1]*rsqrtf(var1+BN_EPS);
  float sh0 = bb[c] - mu0*sc0, sh1 = bb[c+1] - mu1*sc1;
  float pc0=0.f, pc1=0.f, ps0=0.f, ps1=0.f;
  if (RESID){
    float muP0 = stP[c]*inv_n, muP1 = stP[c+1]*inv_n;
    float varP0 = stP[HD+c]*inv_n - muP0*muP0;
    float varP1 = stP[HD+c+1]*inv_n - muP1*muP1;
    pc0 = gP[c]*rsqrtf(varP0+BN_EPS); pc1 = gP[c+1]*rsqrtf(varP1+BN_EPS);
    ps0 = bP[c] - muP0*pc0; ps1 = bP[c+1] - muP1*pc1;
  }
  float s0=0,s1=0,q0=0,q1=0;
  for (int r = blockIdx.x; r < NN; r += gridDim.x){
    unsigned u = Hu[(size_t)r*256 + tid];
    float v0 = leaky(fmaf(h2fu(u&0xFFFF), sc0, sh0));
    float v1 = leaky(fmaf(h2fu(u>>16),   sc1, sh1));
    if (RESID){
      unsigned pu = Pu[(size_t)r*256 + tid];
      v0 += fmaf(h2fu(pu&0xFFFF), pc0, ps0);
      v1 += fmaf(h2fu(pu>>16),    pc1, ps1);
    }
    float ww = mask[r] ? invs[r] : 0.f;
    v0 *= ww; v1 *= ww;
    Tu[(size_t)r*256 + tid] = packh2(v0, v1);
    s0+=v0; s1+=v1; q0+=v0*v0; q1+=v1*v1;
  }
  unsafeAtomicAdd(&st2[c],s0);      unsafeAtomicAdd(&st2[c+1],s1);
  unsafeAtomicAdd(&st2[HD+c],q0);   unsafeAtomicAdd(&st2[HD+c+1],q1);
}
// Xh(fp16) = affine(T) with stats st, params g,bb  (used once, before head)
__global__ void k_bn_final(const unsigned* __restrict__ Tu, const float* __restrict__ g,
    const float* __restrict__ bb, const float* __restrict__ st, unsigned* __restrict__ Xhu)
{
  long i = (long)blockIdx.x*blockDim.x + threadIdx.x;
  if (i >= (long)NN*256) return;
  int c = ((int)(i & 255)) << 1;
  const float inv_n = 1.f/(float)NN;
  float mu0 = st[c]*inv_n, mu1 = st[c+1]*inv_n;
  float var0 = st[HD+c]*inv_n - mu0*mu0;
  float var1 = st[HD+c+1]*inv_n - mu1*mu1;
  float sc0 = g[c]*rsqrtf(var0+BN_EPS), sc1 = g[c+1]*rsqrtf(var1+BN_EPS);
  float sh0 = bb[c] - mu0*sc0, sh1 = bb[c+1] - mu1*sc1;
  unsigned u = Tu[i];
  Xhu[i] = packh2(fmaf(h2fu(u&0xFFFF), sc0, sh0), fmaf(h2fu(u>>16), sc1, sh1));
}

// ---------------- final normalize ----------------
__device__ __forceinline__ float funkey(unsigned k){
  unsigned u = (k & 0x80000000u) ? (k & 0x7fffffffu) : ~k;
  return __uint_as_float(u);
}
__global__ void k_final(const float* __restrict__ z2, const int* __restrict__ batch,
                        const unsigned* __restrict__ mx, const unsigned* __restrict__ mn,
                        float* __restrict__ out){
  int i = blockIdx.x*blockDim.x + threadIdx.x;
  if (i < NN){
    int g = batch[i];
    float bmax = funkey(mx[g]), bmin = funkey(mn[g]);
    out[i] = (z2[i] - bmin) / ((bmax + 1e-6f) - bmin);
  }
}

extern "C" void kernel_launch(void* const* d_in, const int* in_sizes, int n_in,
                              void* d_out, int out_size, void* d_ws, size_t ws_size,
                              hipStream_t stream)
{
  const float* x      = (const float*)d_in[0];
  const int*   ei     = (const int*)d_in[1];
  const int*   src    = ei;
  const int*   dst    = ei + NE;
  const int*   batch  = (const int*)d_in[2];
  const float* c1_w1  = (const float*)d_in[3];
  const float* c1_b1  = (const float*)d_in[4];
  const float* c1_w2  = (const float*)d_in[5];
  const float* c1_b2  = (const float*)d_in[6];
  const float* c1_bng = (const float*)d_in[7];
  const float* c1_bnb = (const float*)d_in[8];
  const float* eps1   = (const float*)d_in[9];
  const float* bn1_g  = (const float*)d_in[10];
  const float* bn1_b  = (const float*)d_in[11];
  const float* cw1    = (const float*)d_in[12];
  const float* cb1    = (const float*)d_in[13];
  const float* cw2    = (const float*)d_in[14];
  const float* cb2    = (const float*)d_in[15];
  const float* cbn_g  = (const float*)d_in[16];
  const float* cbn_b  = (const float*)d_in[17];
  const float* ceps   = (const float*)d_in[18];
  const float* bns_g  = (const float*)d_in[19];
  const float* bns_b  = (const float*)d_in[20];
  const float* l1_w   = (const float*)d_in[21];
  const float* l1_b   = (const float*)d_in[22];
  const float* l2_w   = (const float*)d_in[23];
  const float* l2_b   = (const float*)d_in[24];
  float* out = (float*)d_out;

  const size_t NH = (size_t)NN*HD;
  unsigned short* buf0 = (unsigned short*)d_ws;   // fp16 NH
  unsigned short* buf1 = buf0 + NH;               // fp16 NH
  unsigned short* buf2 = buf1 + NH;               // fp16 NH
  float* h0   = (float*)(buf2 + NH);              // NN
  float* invs = h0 + NN;                          // NN
  float* z2   = invs + NN;                        // NN
  float* stG  = z2 + NN;                          // 1024
  float* stT  = stG + 1024;                       // 4 x 1024
  int* counts = (int*)(stT + 4*1024);             // 64
  unsigned* mx = (unsigned*)(counts + 64);        // 64
  unsigned* mn = mx + 64;                         // 64
  int* deg  = (int*)(mn + 64);                    // NN
  int* off  = deg + NN;                           // NN
  int* cur  = off + NN;                           // NN
  int* srcs = cur + NN;                           // NE
  int* m[5];
  m[0] = srcs + NE;
  for (int k=1;k<5;k++) m[k] = m[k-1] + NN;
  unsigned short* wt[7];
  wt[0] = (unsigned short*)(m[4] + NN);
  for (int k=1;k<7;k++) wt[k] = wt[k-1] + HD*HD;
  unsigned short* w1t = wt[6] + HD*HD;            // 64*512 fp16

  const int TPB = 256;
  dim3 gN((NN+TPB-1)/TPB);
  dim3 gE((NE+TPB-1)/TPB);
  dim3 gNH((unsigned)((NH + TPB-1)/TPB));
  dim3 gNH2((unsigned)((NH/2 + TPB-1)/TPB));
  dim3 gmfma((NN+127)/128, HD/128);
  dim3 gtr(HD/32, HD/32);
  dim3 ghead((NN+127)/128);

  // setup
  k_counts_bs<<<1, 64, 0, stream>>>(batch, counts);
  k_invs_mask0<<<gN, TPB, 0, stream>>>(batch, counts, x, invs, m[0]);
  for (int k=1;k<5;k++){
    k_mask_copy<<<gN,TPB,0,stream>>>(m[k-1], m[k]);
    k_mask_prop<<<gE,TPB,0,stream>>>(m[k-1], m[k], src, dst);
  }
  // CSR by dst
  hipMemsetAsync(deg, 0, NN*sizeof(int), stream);
  k_deg<<<gE,TPB,0,stream>>>(dst, deg);
  k_scan<<<1,1024,0,stream>>>(deg, off, cur);
  k_scatter<<<gE,TPB,0,stream>>>(src, dst, cur, srcs);
  // weight prep (fp16 transposed)
  k_w2ht<<<gtr,256,0,stream>>>(c1_w2, wt[0], HD, HD);
  for (int i=0;i<3;i++){
    k_w2ht<<<gtr,256,0,stream>>>(cw1 + (size_t)i*HD*HD, wt[1+i], HD, HD);
    k_w2ht<<<gtr,256,0,stream>>>(cw2 + (size_t)i*HD*HD, wt[4+i], HD, HD);
  }
  k_w2ht<<<dim3(HD/32, HIDN/32),256,0,stream>>>(l1_w, w1t, HD, HIDN);

  // conv1: h1->buf1, gemm(+stats)->buf2, apply<false>->buf0 (= T0, stats stT[0])
  k_sagg_csr<<<gN,TPB,0,stream>>>(x, off, deg, srcs, eps1, h0);
  k_conv1_h1<<<gNH,TPB,0,stream>>>(h0, c1_w1, c1_b1, buf1);
  hipMemsetAsync(stG, 0, 1024*sizeof(float), stream);
  k_gemm_mfma<true><<<gmfma,256,0,stream>>>((const _Float16*)buf1, (const _Float16*)wt[0], c1_b2, (_Float16*)buf2, stG, NN);
  hipMemsetAsync(stT, 0, 1024*sizeof(float), stream);
  k_bn_apply_stats<false><<<512,256,0,stream>>>((unsigned*)buf2, c1_bng, c1_bnb, stG,
      nullptr, nullptr, nullptr, nullptr, m[1], invs, (unsigned*)buf0, stT);

  // rotation state
  unsigned short *P = buf0, *Q = buf1, *R = buf2;
  const float* stPrev = stT;
  const float* gPrev = bn1_g;
  const float* bPrev = bn1_b;

  for (int i=0;i<3;i++){
    k_agg_csr<<<NN,64,0,stream>>>((const _Float16*)P, off, deg, srcs, ceps+i,
                                  stPrev, gPrev, bPrev, (_Float16*)Q);
    k_gemm_mfma<false><<<gmfma,256,0,stream>>>((const _Float16*)Q, (const _Float16*)wt[1+i], cb1 + (size_t)i*HD, (_Float16*)R, nullptr, NN);
    hipMemsetAsync(stG, 0, 1024*sizeof(float), stream);
    k_gemm_mfma<true><<<gmfma,256,0,stream>>>((const _Float16*)R, (const _Float16*)wt[4+i], cb2 + (size_t)i*HD, (_Float16*)Q, stG, NN);
    float* stCur = stT + (i+1)*1024;
    hipMemsetAsync(stCur, 0, 1024*sizeof(float), stream);
    k_bn_apply_stats<true><<<512,256,0,stream>>>((unsigned*)Q, cbn_g + (size_t)i*HD, cbn_b + (size_t)i*HD, stG,
        (unsigned*)P, stPrev, gPrev, bPrev, m[i+2], invs, (unsigned*)R, stCur);
    unsigned short* tmp = P; P = R; R = tmp;
    stPrev = stCur;
    gPrev = bns_g + (size_t)i*HD;
    bPrev = bns_b + (size_t)i*HD;
  }

  // materialize Xh once: Q = affinePrev(P)
  k_bn_final<<<gNH2,TPB,0,stream>>>((const unsigned*)P, gPrev, bPrev, stPrev, (unsigned*)Q);

  // head: fused lin1+lin2 + per-block LDS minmax, then normalize
  hipMemsetAsync(mx, 0x00, 64*sizeof(unsigned), stream);
  hipMemsetAsync(mn, 0xFF, 64*sizeof(unsigned), stream);
  k_head<<<ghead,256,0,stream>>>((const _Float16*)Q, (const _Float16*)w1t, l1_b, l2_w, l2_b,
                                 m[4], batch, z2, mx, mn, NN);
  k_final<<<gN,TPB,0,stream>>>(z2, batch, mx, mn, out);
}

// Round 11
// 1330.430 us; speedup vs baseline: 1.4238x; 1.0795x over previous
//
#include <hip/hip_runtime.h>
#include <hip/hip_fp16.h>

#define NN 50000
#define NE 150000
#define HD 512
#define HIDN 64
#define BN_EPS 1e-5f
#define SLOPE 0.01f
#define NPART 196   // ceil(NN/256)

typedef _Float16 half8 __attribute__((ext_vector_type(8)));
typedef float floatx4 __attribute__((ext_vector_type(4)));

__device__ __forceinline__ float leaky(float v){ return v > 0.f ? v : SLOPE*v; }
__device__ __forceinline__ float h2fu(unsigned short u){ return __half2float(__ushort_as_half(u)); }
__device__ __forceinline__ unsigned short f2hu(float f){ return __half_as_ushort(__float2half(f)); }
__device__ __forceinline__ unsigned packh2(float a, float b){
  return (unsigned)f2hu(a) | ((unsigned)f2hu(b) << 16);
}

// ---------------- setup ----------------
__global__ void k_counts_bs(const int* __restrict__ batch, int* __restrict__ counts){
  int g = threadIdx.x;   // 0..63
  int lo = 0, hi = NN;
  while (lo < hi){ int mid = (lo+hi)>>1; if (batch[mid] <  g) lo = mid+1; else hi = mid; }
  int start = lo;
  lo = 0; hi = NN;
  while (lo < hi){ int mid = (lo+hi)>>1; if (batch[mid] <= g) lo = mid+1; else hi = mid; }
  counts[g] = lo - start;
}
__global__ void k_invs_mask0(const int* __restrict__ batch, const int* __restrict__ counts,
                             const float* __restrict__ x, float* __restrict__ invs, int* __restrict__ m0){
  int i = blockIdx.x*blockDim.x + threadIdx.x;
  if (i < NN){
    invs[i] = rsqrtf((float)counts[batch[i]]);
    m0[i] = (fabsf(x[i]) > 0.f) ? 1 : 0;
  }
}
__global__ void k_mask_copy(const int* __restrict__ a, int* __restrict__ b){
  int i = blockIdx.x*blockDim.x + threadIdx.x;
  if (i < NN) b[i] = a[i];
}
__global__ void k_mask_prop(const int* __restrict__ mi, int* __restrict__ mo,
                            const int* __restrict__ src, const int* __restrict__ dst){
  int e = blockIdx.x*blockDim.x + threadIdx.x;
  if (e < NE){ if (mi[src[e]]) atomicOr(&mo[dst[e]], 1); }
}

// ---------------- CSR build (by dst) ----------------
__global__ void k_deg(const int* __restrict__ dst, int* __restrict__ deg){
  int e = blockIdx.x*blockDim.x + threadIdx.x;
  if (e < NE) atomicAdd(&deg[dst[e]], 1);
}
// 3-phase parallel exclusive scan (replaces 128us single-block scan)
__global__ void k_scan1(const int* __restrict__ deg, int* __restrict__ part){
  __shared__ int s[256];
  int t = threadIdx.x;
  int i = blockIdx.x*256 + t;
  s[t] = (i < NN) ? deg[i] : 0;
  __syncthreads();
  for (int d = 128; d > 0; d >>= 1){
    if (t < d) s[t] += s[t+d];
    __syncthreads();
  }
  if (t == 0) part[blockIdx.x] = s[0];
}
__global__ void k_scan2(int* __restrict__ part){
  __shared__ int s[256];
  int t = threadIdx.x;
  int own = (t < NPART) ? part[t] : 0;
  s[t] = own;
  __syncthreads();
  for (int d = 1; d < 256; d <<= 1){
    int v = (t >= d) ? s[t-d] : 0;
    __syncthreads();
    s[t] += v;
    __syncthreads();
  }
  if (t < NPART) part[t] = s[t] - own;   // exclusive
}
__global__ void k_scan3(const int* __restrict__ deg, const int* __restrict__ part,
                        int* __restrict__ off, int* __restrict__ cur){
  __shared__ int s[256];
  int t = threadIdx.x;
  int i = blockIdx.x*256 + t;
  int own = (i < NN) ? deg[i] : 0;
  s[t] = own;
  __syncthreads();
  for (int d = 1; d < 256; d <<= 1){
    int v = (t >= d) ? s[t-d] : 0;
    __syncthreads();
    s[t] += v;
    __syncthreads();
  }
  if (i < NN){
    int e = s[t] - own + part[blockIdx.x];
    off[i] = e; cur[i] = e;
  }
}
__global__ void k_scatter(const int* __restrict__ src, const int* __restrict__ dst,
                          int* __restrict__ cur, int* __restrict__ srcs){
  int e = blockIdx.x*blockDim.x + threadIdx.x;
  if (e < NE){
    int pos = atomicAdd(&cur[dst[e]], 1);
    srcs[pos] = src[e];
  }
}

// ---------------- weight prep: all 8 transposes in one launch (z-gridded) ----------------
struct W8 { const float* s[8]; unsigned short* d[8]; int N[8]; };
__global__ void k_w2ht8(W8 p){
  int z = blockIdx.z;
  const float* W = p.s[z]; unsigned short* Wt = p.d[z]; int N = p.N[z];
  int kb = blockIdx.x*32, nb = blockIdx.y*32;
  if (nb >= N) return;
  __shared__ float t[32][33];
  int tx = threadIdx.x & 31, ty = threadIdx.x >> 5;   // 32 x 8
  for (int r = 0; r < 32; r += 8)
    t[ty+r][tx] = W[(size_t)(kb+ty+r)*N + nb+tx];
  __syncthreads();
  for (int r = 0; r < 32; r += 8)
    Wt[(size_t)(nb+ty+r)*HD + kb+tx] = f2hu(t[tx][ty+r]);
}

// ---------------- conv1 front ----------------
__global__ void k_sagg_csr(const float* __restrict__ x, const int* __restrict__ off,
                           const int* __restrict__ deg, const int* __restrict__ srcs,
                           const float* __restrict__ epsp, float* __restrict__ h0){
  int i = blockIdx.x*blockDim.x + threadIdx.x;
  if (i < NN){
    float s = (1.f + epsp[0]) * x[i];
    int o = off[i], d = deg[i];
    for (int j = 0; j < d; j++) s += x[srcs[o + j]];
    h0[i] = s;
  }
}
__global__ void k_conv1_h1(const float* __restrict__ h0, const float* __restrict__ w1,
                           const float* __restrict__ b1, unsigned short* __restrict__ C){
  long idx = (long)blockIdx.x*blockDim.x + threadIdx.x;
  if (idx >= (long)NN*HD) return;
  int i = (int)(idx >> 9), c = (int)(idx & (HD-1));
  float v = fmaf(h0[i], w1[c], b1[c]);
  C[idx] = f2hu(v > 0.f ? v : 0.f);
}

// ---------------- gather+combine with on-the-fly BN affine ----------------
__global__ void k_agg_csr(const _Float16* __restrict__ T, const int* __restrict__ off,
                          const int* __restrict__ deg, const int* __restrict__ srcs,
                          const float* __restrict__ epsp,
                          const float* __restrict__ st, const float* __restrict__ g,
                          const float* __restrict__ bb, _Float16* __restrict__ G){
  int i = blockIdx.x;
  int t = threadIdx.x;          // 64 threads, 8 channels each
  int c0 = t << 3;
  const float inv_n = 1.f/(float)NN;
  float sc[8], sh[8];
  #pragma unroll
  for (int k = 0; k < 8; k++){
    int c = c0 + k;
    float mu = st[c]*inv_n;
    float var = st[HD+c]*inv_n - mu*mu;
    float s = g[c]*rsqrtf(var+BN_EPS);
    sc[k] = s; sh[k] = bb[c] - mu*s;
  }
  const half8* Tv = (const half8*)T;
  half8 p = Tv[(size_t)i*64 + t];
  float ep = 1.f + epsp[0];
  float acc[8];
  #pragma unroll
  for (int k = 0; k < 8; k++) acc[k] = (float)p[k] * ep;
  int o = off[i], d = deg[i];
  for (int j = 0; j < d; j++){
    int s = srcs[o + j];
    half8 q = Tv[(size_t)s*64 + t];
    #pragma unroll
    for (int k = 0; k < 8; k++) acc[k] += (float)q[k];
  }
  float cnt = ep + (float)d;
  half8 r;
  #pragma unroll
  for (int k = 0; k < 8; k++) r[k] = (_Float16)fmaf(sc[k], acc[k], cnt*sh[k]);
  ((half8*)G)[(size_t)i*64 + t] = r;
}

// ---------------- MFMA GEMM, software-pipelined register staging ----------------
// 128x128 tile, 4 waves x 64x64, BK=64, padded LDS (PK=72).
// Pipeline: regs for iter k+1 are loaded AFTER k's ds_write, consumed at (k+1)'s
// ds_write -> global latency hidden by k's MFMA + barrier (VGPR loads need no
// vmcnt drain at __syncthreads, unlike global_load_lds).
template<bool STATS>
__global__ __launch_bounds__(256) void k_gemm_mfma(const _Float16* __restrict__ A,
    const _Float16* __restrict__ Wt, const float* __restrict__ bias,
    _Float16* __restrict__ C, float* __restrict__ st, int M)
{
  constexpr int PK = 72;
  __shared__ __attribute__((aligned(16))) _Float16 As[128*PK];
  __shared__ __attribute__((aligned(16))) _Float16 Bs[128*PK];
  const int tid = threadIdx.x;
  const int m0 = blockIdx.x * 128;
  const int n0 = blockIdx.y * 128;
  const int w = tid >> 6, lane = tid & 63;
  const int wm = (w >> 1) << 6, wn = (w & 1) << 6;
  const int quad = lane >> 4, l16 = lane & 15;

  floatx4 acc[4][4] = {};

  const int srow = tid >> 1;                 // 0..127
  const int skoff = (tid & 1) << 5;          // 0 or 32 halves
  int arow = m0 + srow; if (arow > M-1) arow = M-1;   // clamp (stores/stats guarded)
  const _Float16* Ag = A  + (size_t)arow*HD + skoff;
  const _Float16* Bg = Wt + (size_t)(n0 + srow)*HD + skoff;
  _Float16* Asw = As + srow*PK + skoff;
  _Float16* Bsw = Bs + srow*PK + skoff;

  half8 ca[4], cb[4], na[4], nb[4];
  #pragma unroll
  for (int j = 0; j < 4; j++){
    ca[j] = *(const half8*)(Ag + j*8);
    cb[j] = *(const half8*)(Bg + j*8);
  }

  #pragma unroll
  for (int kt = 0; kt < HD; kt += 64){
    __syncthreads();
    #pragma unroll
    for (int j = 0; j < 4; j++){
      *(half8*)(Asw + j*8) = ca[j];
      *(half8*)(Bsw + j*8) = cb[j];
    }
    if (kt + 64 < HD){
      #pragma unroll
      for (int j = 0; j < 4; j++){
        na[j] = *(const half8*)(Ag + kt + 64 + j*8);
        nb[j] = *(const half8*)(Bg + kt + 64 + j*8);
      }
    }
    __syncthreads();
    #pragma unroll
    for (int k0 = 0; k0 < 64; k0 += 32){
      half8 af[4], bf[4];
      #pragma unroll
      for (int t4 = 0; t4 < 4; t4++){
        af[t4] = *(const half8*)(As + (wm + t4*16 + l16)*PK + k0 + quad*8);
        bf[t4] = *(const half8*)(Bs + (wn + t4*16 + l16)*PK + k0 + quad*8);
      }
      #pragma unroll
      for (int mi = 0; mi < 4; mi++){
        #pragma unroll
        for (int ni = 0; ni < 4; ni++){
          acc[mi][ni] = __builtin_amdgcn_mfma_f32_16x16x32_f16(af[mi], bf[ni], acc[mi][ni], 0, 0, 0);
        }
      }
    }
    #pragma unroll
    for (int j = 0; j < 4; j++){ ca[j] = na[j]; cb[j] = nb[j]; }
  }

  // epilogue: D row = quad*4+reg, col = l16 ; bias+relu+store (+stats)
  float sv[4] = {0,0,0,0}, qv[4] = {0,0,0,0};
  #pragma unroll
  for (int ni = 0; ni < 4; ni++){
    int ccol = n0 + wn + ni*16 + l16;
    float bs = bias[ccol];
    #pragma unroll
    for (int mi = 0; mi < 4; mi++){
      #pragma unroll
      for (int reg = 0; reg < 4; reg++){
        int r = m0 + wm + mi*16 + quad*4 + reg;
        float v = acc[mi][ni][reg] + bs;
        v = v > 0.f ? v : 0.f;
        if (r < M){
          C[(size_t)r*HD + ccol] = (_Float16)v;
          if (STATS){ sv[ni] += v; qv[ni] += v*v; }
        }
      }
    }
  }
  if (STATS){
    #pragma unroll
    for (int ni = 0; ni < 4; ni++){
      float s = sv[ni], q = qv[ni];
      s += __shfl_xor(s, 16); s += __shfl_xor(s, 32);
      q += __shfl_xor(q, 16); q += __shfl_xor(q, 32);
      if (quad == 0){
        int ccol = n0 + wn + ni*16 + l16;
        unsafeAtomicAdd(&st[ccol], s);
        unsafeAtomicAdd(&st[HD+ccol], q);
      }
    }
  }
}

// ---------------- fused head (pipelined) with per-block LDS min/max reduction ----------------
__global__ __launch_bounds__(256) void k_head(const _Float16* __restrict__ Xh,
    const _Float16* __restrict__ W1t, const float* __restrict__ b1,
    const float* __restrict__ w2, const float* __restrict__ b2p,
    const int* __restrict__ mask, const int* __restrict__ batch,
    float* __restrict__ z2, unsigned* __restrict__ mx, unsigned* __restrict__ mn, int M)
{
  constexpr int PK = 72;
  __shared__ __attribute__((aligned(16))) _Float16 As[128*PK];
  __shared__ __attribute__((aligned(16))) _Float16 Bs[64*PK];
  __shared__ unsigned smx[64], smn[64];
  const int tid = threadIdx.x;
  const int m0 = blockIdx.x * 128;
  const int w = tid >> 6, lane = tid & 63;
  const int wm = w << 5;
  const int quad = lane >> 4, l16 = lane & 15;

  if (tid < 64){ smx[tid] = 0u; smn[tid] = 0xFFFFFFFFu; }

  floatx4 acc[2][4] = {};

  const int srow = tid >> 1;
  const int skoff = (tid & 1) << 5;
  int arow = m0 + srow; if (arow > M-1) arow = M-1;
  const _Float16* Ag = Xh + (size_t)arow*HD + skoff;
  _Float16* Asw = As + srow*PK + skoff;
  const int brow = tid >> 2;
  const int bkoff = (tid & 3) << 4;
  const _Float16* Bg = W1t + (size_t)brow*HD + bkoff;
  _Float16* Bsw = Bs + brow*PK + bkoff;

  half8 ca[4], cb[2], na[4], nb[2];
  #pragma unroll
  for (int j = 0; j < 4; j++) ca[j] = *(const half8*)(Ag + j*8);
  cb[0] = *(const half8*)(Bg); cb[1] = *(const half8*)(Bg + 8);

  #pragma unroll
  for (int kt = 0; kt < HD; kt += 64){
    __syncthreads();
    #pragma unroll
    for (int j = 0; j < 4; j++) *(half8*)(Asw + j*8) = ca[j];
    *(half8*)(Bsw) = cb[0]; *(half8*)(Bsw + 8) = cb[1];
    if (kt + 64 < HD){
      #pragma unroll
      for (int j = 0; j < 4; j++) na[j] = *(const half8*)(Ag + kt + 64 + j*8);
      nb[0] = *(const half8*)(Bg + kt + 64); nb[1] = *(const half8*)(Bg + kt + 72);
    }
    __syncthreads();
    #pragma unroll
    for (int k0 = 0; k0 < 64; k0 += 32){
      half8 af[2], bf[4];
      #pragma unroll
      for (int mi = 0; mi < 2; mi++) af[mi] = *(const half8*)&As[(wm + mi*16 + l16)*PK + k0 + quad*8];
      #pragma unroll
      for (int ni = 0; ni < 4; ni++) bf[ni] = *(const half8*)&Bs[(ni*16 + l16)*PK + k0 + quad*8];
      #pragma unroll
      for (int mi = 0; mi < 2; mi++){
        #pragma unroll
        for (int ni = 0; ni < 4; ni++){
          acc[mi][ni] = __builtin_amdgcn_mfma_f32_16x16x32_f16(af[mi], bf[ni], acc[mi][ni], 0, 0, 0);
        }
      }
    }
    #pragma unroll
    for (int j = 0; j < 4; j++) ca[j] = na[j];
    cb[0] = nb[0]; cb[1] = nb[1];
  }

  float b1v[4], w2v[4];
  #pragma unroll
  for (int ni = 0; ni < 4; ni++){ b1v[ni] = b1[ni*16 + l16]; w2v[ni] = w2[ni*16 + l16]; }
  const float b2 = b2p[0];
  #pragma unroll
  for (int mi = 0; mi < 2; mi++){
    #pragma unroll
    for (int reg = 0; reg < 4; reg++){
      int r = m0 + wm + mi*16 + quad*4 + reg;
      bool ok = r < M;
      float mk = (ok && mask[r]) ? 1.f : 0.f;
      float t = 0.f;
      #pragma unroll
      for (int ni = 0; ni < 4; ni++){
        float v = leaky(acc[mi][ni][reg] + b1v[ni]) * mk;
        t += v * w2v[ni];
      }
      t += __shfl_xor(t, 1); t += __shfl_xor(t, 2);
      t += __shfl_xor(t, 4); t += __shfl_xor(t, 8);
      if (l16 == 0 && ok){
        float zv = leaky(t + b2) * mk;
        z2[r] = zv;
        unsigned u = __float_as_uint(zv);
        unsigned key = (u & 0x80000000u) ? ~u : (u | 0x80000000u);
        int gg = batch[r];
        atomicMax(&smx[gg], key); atomicMin(&smn[gg], key);
      }
    }
  }
  __syncthreads();
  if (tid < 64){
    unsigned vx = smx[tid], vn = smn[tid];
    if (vx != 0u)          atomicMax(&mx[tid], vx);
    if (vn != 0xFFFFFFFFu) atomicMin(&mn[tid], vn);
  }
}

// ---------------- BN apply: T = (affineP(T_prev) + leaky(bn(Hin)))*mask*invs ; stats of T -> st2 ----------------
template<bool RESID>
__global__ void k_bn_apply_stats(const unsigned* __restrict__ Hu, const float* __restrict__ g,
    const float* __restrict__ bb, const float* __restrict__ st,
    const unsigned* __restrict__ Pu, const float* __restrict__ stP,
    const float* __restrict__ gP, const float* __restrict__ bP,
    const int* __restrict__ mask, const float* __restrict__ invs,
    unsigned* __restrict__ Tu, float* __restrict__ st2)
{
  int tid = threadIdx.x; int c = tid<<1;
  const float inv_n = 1.f/(float)NN;
  float mu0 = st[c]*inv_n, mu1 = st[c+1]*inv_n;
  float var0 = st[HD+c]*inv_n - mu0*mu0;
  float var1 = st[HD+c+1]*inv_n - mu1*mu1;
  float sc0 = g[c]*rsqrtf(var0+BN_EPS), sc1 = g[c+1]*rsqrtf(var1+BN_EPS);
  float sh0 = bb[c] - mu0*sc0, sh1 = bb[c+1] - mu1*sc1;
  float pc0=0.f, pc1=0.f, ps0=0.f, ps1=0.f;
  if (RESID){
    float muP0 = stP[c]*inv_n, muP1 = stP[c+1]*inv_n;
    float varP0 = stP[HD+c]*inv_n - muP0*muP0;
    float varP1 = stP[HD+c+1]*inv_n - muP1*muP1;
    pc0 = gP[c]*rsqrtf(varP0+BN_EPS); pc1 = gP[c+1]*rsqrtf(varP1+BN_EPS);
    ps0 = bP[c] - muP0*pc0; ps1 = bP[c+1] - muP1*pc1;
  }
  float s0=0,s1=0,q0=0,q1=0;
  for (int r = blockIdx.x; r < NN; r += gridDim.x){
    unsigned u = Hu[(size_t)r*256 + tid];
    float v0 = leaky(fmaf(h2fu(u&0xFFFF), sc0, sh0));
    float v1 = leaky(fmaf(h2fu(u>>16),   sc1, sh1));
    if (RESID){
      unsigned pu = Pu[(size_t)r*256 + tid];
      v0 += fmaf(h2fu(pu&0xFFFF), pc0, ps0);
      v1 += fmaf(h2fu(pu>>16),    pc1, ps1);
    }
    float ww = mask[r] ? invs[r] : 0.f;
    v0 *= ww; v1 *= ww;
    Tu[(size_t)r*256 + tid] = packh2(v0, v1);
    s0+=v0; s1+=v1; q0+=v0*v0; q1+=v1*v1;
  }
  unsafeAtomicAdd(&st2[c],s0);      unsafeAtomicAdd(&st2[c+1],s1);
  unsafeAtomicAdd(&st2[HD+c],q0);   unsafeAtomicAdd(&st2[HD+c+1],q1);
}
// Xh(fp16) = affine(T) with stats st, params g,bb  (used once, before head)
__global__ void k_bn_final(const unsigned* __restrict__ Tu, const float* __restrict__ g,
    const float* __restrict__ bb, const float* __restrict__ st, unsigned* __restrict__ Xhu)
{
  long i = (long)blockIdx.x*blockDim.x + threadIdx.x;
  if (i >= (long)NN*256) return;
  int c = ((int)(i & 255)) << 1;
  const float inv_n = 1.f/(float)NN;
  float mu0 = st[c]*inv_n, mu1 = st[c+1]*inv_n;
  float var0 = st[HD+c]*inv_n - mu0*mu0;
  float var1 = st[HD+c+1]*inv_n - mu1*mu1;
  float sc0 = g[c]*rsqrtf(var0+BN_EPS), sc1 = g[c+1]*rsqrtf(var1+BN_EPS);
  float sh0 = bb[c] - mu0*sc0, sh1 = bb[c+1] - mu1*sc1;
  unsigned u = Tu[i];
  Xhu[i] = packh2(fmaf(h2fu(u&0xFFFF), sc0, sh0), fmaf(h2fu(u>>16), sc1, sh1));
}

// ---------------- final normalize ----------------
__device__ __forceinline__ float funkey(unsigned k){
  unsigned u = (k & 0x80000000u) ? (k & 0x7fffffffu) : ~k;
  return __uint_as_float(u);
}
__global__ void k_final(const float* __restrict__ z2, const int* __restrict__ batch,
                        const unsigned* __restrict__ mx, const unsigned* __restrict__ mn,
                        float* __restrict__ out){
  int i = blockIdx.x*blockDim.x + threadIdx.x;
  if (i < NN){
    int g = batch[i];
    float bmax = funkey(mx[g]), bmin = funkey(mn[g]);
    out[i] = (z2[i] - bmin) / ((bmax + 1e-6f) - bmin);
  }
}

extern "C" void kernel_launch(void* const* d_in, const int* in_sizes, int n_in,
                              void* d_out, int out_size, void* d_ws, size_t ws_size,
                              hipStream_t stream)
{
  const float* x      = (const float*)d_in[0];
  const int*   ei     = (const int*)d_in[1];
  const int*   src    = ei;
  const int*   dst    = ei + NE;
  const int*   batch  = (const int*)d_in[2];
  const float* c1_w1  = (const float*)d_in[3];
  const float* c1_b1  = (const float*)d_in[4];
  const float* c1_w2  = (const float*)d_in[5];
  const float* c1_b2  = (const float*)d_in[6];
  const float* c1_bng = (const float*)d_in[7];
  const float* c1_bnb = (const float*)d_in[8];
  const float* eps1   = (const float*)d_in[9];
  const float* bn1_g  = (const float*)d_in[10];
  const float* bn1_b  = (const float*)d_in[11];
  const float* cw1    = (const float*)d_in[12];
  const float* cb1    = (const float*)d_in[13];
  const float* cw2    = (const float*)d_in[14];
  const float* cb2    = (const float*)d_in[15];
  const float* cbn_g  = (const float*)d_in[16];
  const float* cbn_b  = (const float*)d_in[17];
  const float* ceps   = (const float*)d_in[18];
  const float* bns_g  = (const float*)d_in[19];
  const float* bns_b  = (const float*)d_in[20];
  const float* l1_w   = (const float*)d_in[21];
  const float* l1_b   = (const float*)d_in[22];
  const float* l2_w   = (const float*)d_in[23];
  const float* l2_b   = (const float*)d_in[24];
  float* out = (float*)d_out;

  const size_t NH = (size_t)NN*HD;
  unsigned short* buf0 = (unsigned short*)d_ws;   // fp16 NH
  unsigned short* buf1 = buf0 + NH;               // fp16 NH
  unsigned short* buf2 = buf1 + NH;               // fp16 NH
  float* h0   = (float*)(buf2 + NH);              // NN
  float* invs = h0 + NN;                          // NN
  float* z2   = invs + NN;                        // NN
  float* stG  = z2 + NN;                          // 1024
  float* stT  = stG + 1024;                       // 4 x 1024
  int* counts = (int*)(stT + 4*1024);             // 64
  unsigned* mx = (unsigned*)(counts + 64);        // 64
  unsigned* mn = mx + 64;                         // 64
  int* part = (int*)(mn + 64);                    // 256 (scan partials)
  int* deg  = part + 256;                         // NN
  int* off  = deg + NN;                           // NN
  int* cur  = off + NN;                           // NN
  int* srcs = cur + NN;                           // NE
  int* m[5];
  m[0] = srcs + NE;
  for (int k=1;k<5;k++) m[k] = m[k-1] + NN;
  unsigned short* wt[7];
  wt[0] = (unsigned short*)(m[4] + NN);
  for (int k=1;k<7;k++) wt[k] = wt[k-1] + HD*HD;
  unsigned short* w1t = wt[6] + HD*HD;            // 64*512 fp16

  const int TPB = 256;
  dim3 gN((NN+TPB-1)/TPB);
  dim3 gE((NE+TPB-1)/TPB);
  dim3 gNH((unsigned)((NH + TPB-1)/TPB));
  dim3 gNH2((unsigned)((NH/2 + TPB-1)/TPB));
  dim3 gmfma((NN+127)/128, HD/128);
  dim3 ghead((NN+127)/128);

  // setup
  k_counts_bs<<<1, 64, 0, stream>>>(batch, counts);
  k_invs_mask0<<<gN, TPB, 0, stream>>>(batch, counts, x, invs, m[0]);
  for (int k=1;k<5;k++){
    k_mask_copy<<<gN,TPB,0,stream>>>(m[k-1], m[k]);
    k_mask_prop<<<gE,TPB,0,stream>>>(m[k-1], m[k], src, dst);
  }
  // CSR by dst (parallel 3-phase scan)
  hipMemsetAsync(deg, 0, NN*sizeof(int), stream);
  k_deg<<<gE,TPB,0,stream>>>(dst, deg);
  k_scan1<<<NPART,256,0,stream>>>(deg, part);
  k_scan2<<<1,256,0,stream>>>(part);
  k_scan3<<<NPART,256,0,stream>>>(deg, part, off, cur);
  k_scatter<<<gE,TPB,0,stream>>>(src, dst, cur, srcs);
  // weight prep: all 8 transposes in one launch
  W8 wp;
  wp.s[0] = c1_w2; wp.d[0] = wt[0]; wp.N[0] = HD;
  for (int i=0;i<3;i++){
    wp.s[1+i] = cw1 + (size_t)i*HD*HD; wp.d[1+i] = wt[1+i]; wp.N[1+i] = HD;
    wp.s[4+i] = cw2 + (size_t)i*HD*HD; wp.d[4+i] = wt[4+i]; wp.N[4+i] = HD;
  }
  wp.s[7] = l1_w; wp.d[7] = w1t; wp.N[7] = HIDN;
  k_w2ht8<<<dim3(HD/32, HD/32, 8),256,0,stream>>>(wp);

  // conv1: h1->buf1, gemm(+stats)->buf2, apply<false>->buf0 (= T0, stats stT[0])
  k_sagg_csr<<<gN,TPB,0,stream>>>(x, off, deg, srcs, eps1, h0);
  k_conv1_h1<<<gNH,TPB,0,stream>>>(h0, c1_w1, c1_b1, buf1);
  hipMemsetAsync(stG, 0, 1024*sizeof(float), stream);
  k_gemm_mfma<true><<<gmfma,256,0,stream>>>((const _Float16*)buf1, (const _Float16*)wt[0], c1_b2, (_Float16*)buf2, stG, NN);
  hipMemsetAsync(stT, 0, 1024*sizeof(float), stream);
  k_bn_apply_stats<false><<<512,256,0,stream>>>((unsigned*)buf2, c1_bng, c1_bnb, stG,
      nullptr, nullptr, nullptr, nullptr, m[1], invs, (unsigned*)buf0, stT);

  // rotation state
  unsigned short *P = buf0, *Q = buf1, *R = buf2;
  const float* stPrev = stT;
  const float* gPrev = bn1_g;
  const float* bPrev = bn1_b;

  for (int i=0;i<3;i++){
    k_agg_csr<<<NN,64,0,stream>>>((const _Float16*)P, off, deg, srcs, ceps+i,
                                  stPrev, gPrev, bPrev, (_Float16*)Q);
    k_gemm_mfma<false><<<gmfma,256,0,stream>>>((const _Float16*)Q, (const _Float16*)wt[1+i], cb1 + (size_t)i*HD, (_Float16*)R, nullptr, NN);
    hipMemsetAsync(stG, 0, 1024*sizeof(float), stream);
    k_gemm_mfma<true><<<gmfma,256,0,stream>>>((const _Float16*)R, (const _Float16*)wt[4+i], cb2 + (size_t)i*HD, (_Float16*)Q, stG, NN);
    float* stCur = stT + (i+1)*1024;
    hipMemsetAsync(stCur, 0, 1024*sizeof(float), stream);
    k_bn_apply_stats<true><<<512,256,0,stream>>>((unsigned*)Q, cbn_g + (size_t)i*HD, cbn_b + (size_t)i*HD, stG,
        (unsigned*)P, stPrev, gPrev, bPrev, m[i+2], invs, (unsigned*)R, stCur);
    unsigned short* tmp = P; P = R; R = tmp;
    stPrev = stCur;
    gPrev = bns_g + (size_t)i*HD;
    bPrev = bns_b + (size_t)i*HD;
  }

  // materialize Xh once: Q = affinePrev(P)
  k_bn_final<<<gNH2,TPB,0,stream>>>((const unsigned*)P, gPrev, bPrev, stPrev, (unsigned*)Q);

  // head: fused lin1+lin2 + per-block LDS minmax, then normalize
  hipMemsetAsync(mx, 0x00, 64*sizeof(unsigned), stream);
  hipMemsetAsync(mn, 0xFF, 64*sizeof(unsigned), stream);
  k_head<<<ghead,256,0,stream>>>((const _Float16*)Q, (const _Float16*)w1t, l1_b, l2_w, l2_b,
                                 m[4], batch, z2, mx, mn, NN);
  k_final<<<gN,TPB,0,stream>>>(z2, batch, mx, mn, out);
}

// Round 12
// 1245.710 us; speedup vs baseline: 1.5206x; 1.0680x over previous
//
#include <hip/hip_runtime.h>
#include <hip/hip_fp16.h>

#define NN 50000
#define NE 150000
#define HD 512
#define HIDN 64
#define BN_EPS 1e-5f
#define SLOPE 0.01f
#define NPART 196   // ceil(NN/256)

typedef _Float16 half8 __attribute__((ext_vector_type(8)));
typedef float floatx4 __attribute__((ext_vector_type(4)));

__device__ __forceinline__ float leaky(float v){ return v > 0.f ? v : SLOPE*v; }
__device__ __forceinline__ float h2fu(unsigned short u){ return __half2float(__ushort_as_half(u)); }
__device__ __forceinline__ unsigned short f2hu(float f){ return __half_as_ushort(__float2half(f)); }
__device__ __forceinline__ unsigned packh2(float a, float b){
  return (unsigned)f2hu(a) | ((unsigned)f2hu(b) << 16);
}

// ---------------- setup ----------------
__global__ void k_counts_bs(const int* __restrict__ batch, int* __restrict__ counts){
  int g = threadIdx.x;   // 0..63
  int lo = 0, hi = NN;
  while (lo < hi){ int mid = (lo+hi)>>1; if (batch[mid] <  g) lo = mid+1; else hi = mid; }
  int start = lo;
  lo = 0; hi = NN;
  while (lo < hi){ int mid = (lo+hi)>>1; if (batch[mid] <= g) lo = mid+1; else hi = mid; }
  counts[g] = lo - start;
}
__global__ void k_invs_mask0(const int* __restrict__ batch, const int* __restrict__ counts,
                             const float* __restrict__ x, float* __restrict__ invs, int* __restrict__ m0){
  int i = blockIdx.x*blockDim.x + threadIdx.x;
  if (i < NN){
    invs[i] = rsqrtf((float)counts[batch[i]]);
    m0[i] = (fabsf(x[i]) > 0.f) ? 1 : 0;
  }
}
__global__ void k_mask_copy(const int* __restrict__ a, int* __restrict__ b){
  int i = blockIdx.x*blockDim.x + threadIdx.x;
  if (i < NN) b[i] = a[i];
}
__global__ void k_mask_prop(const int* __restrict__ mi, int* __restrict__ mo,
                            const int* __restrict__ src, const int* __restrict__ dst){
  int e = blockIdx.x*blockDim.x + threadIdx.x;
  if (e < NE){ if (mi[src[e]]) atomicOr(&mo[dst[e]], 1); }
}

// ---------------- CSR build (by dst) ----------------
__global__ void k_deg(const int* __restrict__ dst, int* __restrict__ deg){
  int e = blockIdx.x*blockDim.x + threadIdx.x;
  if (e < NE) atomicAdd(&deg[dst[e]], 1);
}
__global__ void k_scan1(const int* __restrict__ deg, int* __restrict__ part){
  __shared__ int s[256];
  int t = threadIdx.x;
  int i = blockIdx.x*256 + t;
  s[t] = (i < NN) ? deg[i] : 0;
  __syncthreads();
  for (int d = 128; d > 0; d >>= 1){
    if (t < d) s[t] += s[t+d];
    __syncthreads();
  }
  if (t == 0) part[blockIdx.x] = s[0];
}
__global__ void k_scan2(int* __restrict__ part){
  __shared__ int s[256];
  int t = threadIdx.x;
  int own = (t < NPART) ? part[t] : 0;
  s[t] = own;
  __syncthreads();
  for (int d = 1; d < 256; d <<= 1){
    int v = (t >= d) ? s[t-d] : 0;
    __syncthreads();
    s[t] += v;
    __syncthreads();
  }
  if (t < NPART) part[t] = s[t] - own;   // exclusive
}
__global__ void k_scan3(const int* __restrict__ deg, const int* __restrict__ part,
                        int* __restrict__ off, int* __restrict__ cur){
  __shared__ int s[256];
  int t = threadIdx.x;
  int i = blockIdx.x*256 + t;
  int own = (i < NN) ? deg[i] : 0;
  s[t] = own;
  __syncthreads();
  for (int d = 1; d < 256; d <<= 1){
    int v = (t >= d) ? s[t-d] : 0;
    __syncthreads();
    s[t] += v;
    __syncthreads();
  }
  if (i < NN){
    int e = s[t] - own + part[blockIdx.x];
    off[i] = e; cur[i] = e;
  }
}
__global__ void k_scatter(const int* __restrict__ src, const int* __restrict__ dst,
                          int* __restrict__ cur, int* __restrict__ srcs){
  int e = blockIdx.x*blockDim.x + threadIdx.x;
  if (e < NE){
    int pos = atomicAdd(&cur[dst[e]], 1);
    srcs[pos] = src[e];
  }
}

// ---------------- weight prep: all 8 transposes in one launch (z-gridded) ----------------
struct W8 { const float* s[8]; unsigned short* d[8]; int N[8]; };
__global__ void k_w2ht8(W8 p){
  int z = blockIdx.z;
  const float* W = p.s[z]; unsigned short* Wt = p.d[z]; int N = p.N[z];
  int kb = blockIdx.x*32, nb = blockIdx.y*32;
  if (nb >= N) return;
  __shared__ float t[32][33];
  int tx = threadIdx.x & 31, ty = threadIdx.x >> 5;   // 32 x 8
  for (int r = 0; r < 32; r += 8)
    t[ty+r][tx] = W[(size_t)(kb+ty+r)*N + nb+tx];
  __syncthreads();
  for (int r = 0; r < 32; r += 8)
    Wt[(size_t)(nb+ty+r)*HD + kb+tx] = f2hu(t[tx][ty+r]);
}

// ---------------- conv1 front ----------------
__global__ void k_sagg_csr(const float* __restrict__ x, const int* __restrict__ off,
                           const int* __restrict__ deg, const int* __restrict__ srcs,
                           const float* __restrict__ epsp, float* __restrict__ h0){
  int i = blockIdx.x*blockDim.x + threadIdx.x;
  if (i < NN){
    float s = (1.f + epsp[0]) * x[i];
    int o = off[i], d = deg[i];
    for (int j = 0; j < d; j++) s += x[srcs[o + j]];
    h0[i] = s;
  }
}
__global__ void k_conv1_h1(const float* __restrict__ h0, const float* __restrict__ w1,
                           const float* __restrict__ b1, unsigned short* __restrict__ C){
  long idx = (long)blockIdx.x*blockDim.x + threadIdx.x;
  if (idx >= (long)NN*HD) return;
  int i = (int)(idx >> 9), c = (int)(idx & (HD-1));
  float v = fmaf(h0[i], w1[c], b1[c]);
  C[idx] = f2hu(v > 0.f ? v : 0.f);
}

// ---------------- gather+combine with on-the-fly BN affine ----------------
__global__ void k_agg_csr(const _Float16* __restrict__ T, const int* __restrict__ off,
                          const int* __restrict__ deg, const int* __restrict__ srcs,
                          const float* __restrict__ epsp,
                          const float* __restrict__ st, const float* __restrict__ g,
                          const float* __restrict__ bb, _Float16* __restrict__ G){
  int i = blockIdx.x;
  int t = threadIdx.x;          // 64 threads, 8 channels each
  int c0 = t << 3;
  const float inv_n = 1.f/(float)NN;
  float sc[8], sh[8];
  #pragma unroll
  for (int k = 0; k < 8; k++){
    int c = c0 + k;
    float mu = st[c]*inv_n;
    float var = st[HD+c]*inv_n - mu*mu;
    float s = g[c]*rsqrtf(var+BN_EPS);
    sc[k] = s; sh[k] = bb[c] - mu*s;
  }
  const half8* Tv = (const half8*)T;
  half8 p = Tv[(size_t)i*64 + t];
  float ep = 1.f + epsp[0];
  float acc[8];
  #pragma unroll
  for (int k = 0; k < 8; k++) acc[k] = (float)p[k] * ep;
  int o = off[i], d = deg[i];
  for (int j = 0; j < d; j++){
    int s = srcs[o + j];
    half8 q = Tv[(size_t)s*64 + t];
    #pragma unroll
    for (int k = 0; k < 8; k++) acc[k] += (float)q[k];
  }
  float cnt = ep + (float)d;
  half8 r;
  #pragma unroll
  for (int k = 0; k < 8; k++) r[k] = (_Float16)fmaf(sc[k], acc[k], cnt*sh[k]);
  ((half8*)G)[(size_t)i*64 + t] = r;
}

// ---------------- MFMA GEMM, distance-2 software pipeline ----------------
// 128x128 tile, 4 waves x 64x64, BK=64, padded LDS (PK=72), ring-of-3 reg sets.
// r11 distance-1: 112us, MfmaUtil 8.9% — one MFMA window (~600cy) < HBM latency
// (~900cy), ds_write still stalls. Distance-2 gives each load 2 windows.
// Grid: bx = N-tile (fast), by = M-tile -> the 4 N-tiles sharing an A-block are
// dispatched adjacently -> A re-reads hit L3/L2 (r11 FETCH was 2x A).
template<bool STATS>
__global__ __launch_bounds__(256) void k_gemm_mfma(const _Float16* __restrict__ A,
    const _Float16* __restrict__ Wt, const float* __restrict__ bias,
    _Float16* __restrict__ C, float* __restrict__ st, int M)
{
  constexpr int PK = 72;
  __shared__ __attribute__((aligned(16))) _Float16 As[128*PK];
  __shared__ __attribute__((aligned(16))) _Float16 Bs[128*PK];
  const int tid = threadIdx.x;
  const int m0 = blockIdx.y * 128;
  const int n0 = blockIdx.x * 128;
  const int w = tid >> 6, lane = tid & 63;
  const int wm = (w >> 1) << 6, wn = (w & 1) << 6;
  const int quad = lane >> 4, l16 = lane & 15;

  floatx4 acc[4][4] = {};

  const int srow = tid >> 1;                 // 0..127
  const int skoff = (tid & 1) << 5;          // 0 or 32 halves
  int arow = m0 + srow; if (arow > M-1) arow = M-1;   // clamp (stores/stats guarded)
  const _Float16* Ag = A  + (size_t)arow*HD + skoff;
  const _Float16* Bg = Wt + (size_t)(n0 + srow)*HD + skoff;
  _Float16* Asw = As + srow*PK + skoff;
  _Float16* Bsw = Bs + srow*PK + skoff;

  half8 ra[3][4], rb[3][4];
  #pragma unroll
  for (int j = 0; j < 4; j++){
    ra[0][j] = *(const half8*)(Ag + j*8);       rb[0][j] = *(const half8*)(Bg + j*8);
    ra[1][j] = *(const half8*)(Ag + 64 + j*8);  rb[1][j] = *(const half8*)(Bg + 64 + j*8);
  }

  #pragma unroll
  for (int it = 0; it < 8; it++){
    const int cur = it % 3, nxt = (it + 2) % 3;
    __syncthreads();
    #pragma unroll
    for (int j = 0; j < 4; j++){
      *(half8*)(Asw + j*8) = ra[cur][j];
      *(half8*)(Bsw + j*8) = rb[cur][j];
    }
    if (it + 2 < 8){
      #pragma unroll
      for (int j = 0; j < 4; j++){
        ra[nxt][j] = *(const half8*)(Ag + (it+2)*64 + j*8);
        rb[nxt][j] = *(const half8*)(Bg + (it+2)*64 + j*8);
      }
    }
    __syncthreads();
    #pragma unroll
    for (int k0 = 0; k0 < 64; k0 += 32){
      half8 af[4], bf[4];
      #pragma unroll
      for (int t4 = 0; t4 < 4; t4++){
        af[t4] = *(const half8*)(As + (wm + t4*16 + l16)*PK + k0 + quad*8);
        bf[t4] = *(const half8*)(Bs + (wn + t4*16 + l16)*PK + k0 + quad*8);
      }
      #pragma unroll
      for (int mi = 0; mi < 4; mi++){
        #pragma unroll
        for (int ni = 0; ni < 4; ni++){
          acc[mi][ni] = __builtin_amdgcn_mfma_f32_16x16x32_f16(af[mi], bf[ni], acc[mi][ni], 0, 0, 0);
        }
      }
    }
  }

  // epilogue: D row = quad*4+reg, col = l16 ; bias+relu+store (+stats)
  float sv[4] = {0,0,0,0}, qv[4] = {0,0,0,0};
  #pragma unroll
  for (int ni = 0; ni < 4; ni++){
    int ccol = n0 + wn + ni*16 + l16;
    float bs = bias[ccol];
    #pragma unroll
    for (int mi = 0; mi < 4; mi++){
      #pragma unroll
      for (int reg = 0; reg < 4; reg++){
        int r = m0 + wm + mi*16 + quad*4 + reg;
        float v = acc[mi][ni][reg] + bs;
        v = v > 0.f ? v : 0.f;
        if (r < M){
          C[(size_t)r*HD + ccol] = (_Float16)v;
          if (STATS){ sv[ni] += v; qv[ni] += v*v; }
        }
      }
    }
  }
  if (STATS){
    #pragma unroll
    for (int ni = 0; ni < 4; ni++){
      float s = sv[ni], q = qv[ni];
      s += __shfl_xor(s, 16); s += __shfl_xor(s, 32);
      q += __shfl_xor(q, 16); q += __shfl_xor(q, 32);
      if (quad == 0){
        int ccol = n0 + wn + ni*16 + l16;
        unsafeAtomicAdd(&st[ccol], s);
        unsafeAtomicAdd(&st[HD+ccol], q);
      }
    }
  }
}

// ---------------- fused head (pipelined) with per-block LDS min/max reduction ----------------
__global__ __launch_bounds__(256) void k_head(const _Float16* __restrict__ Xh,
    const _Float16* __restrict__ W1t, const float* __restrict__ b1,
    const float* __restrict__ w2, const float* __restrict__ b2p,
    const int* __restrict__ mask, const int* __restrict__ batch,
    float* __restrict__ z2, unsigned* __restrict__ mx, unsigned* __restrict__ mn, int M)
{
  constexpr int PK = 72;
  __shared__ __attribute__((aligned(16))) _Float16 As[128*PK];
  __shared__ __attribute__((aligned(16))) _Float16 Bs[64*PK];
  __shared__ unsigned smx[64], smn[64];
  const int tid = threadIdx.x;
  const int m0 = blockIdx.x * 128;
  const int w = tid >> 6, lane = tid & 63;
  const int wm = w << 5;
  const int quad = lane >> 4, l16 = lane & 15;

  if (tid < 64){ smx[tid] = 0u; smn[tid] = 0xFFFFFFFFu; }

  floatx4 acc[2][4] = {};

  const int srow = tid >> 1;
  const int skoff = (tid & 1) << 5;
  int arow = m0 + srow; if (arow > M-1) arow = M-1;
  const _Float16* Ag = Xh + (size_t)arow*HD + skoff;
  _Float16* Asw = As + srow*PK + skoff;
  const int brow = tid >> 2;
  const int bkoff = (tid & 3) << 4;
  const _Float16* Bg = W1t + (size_t)brow*HD + bkoff;
  _Float16* Bsw = Bs + brow*PK + bkoff;

  half8 ca[4], cb[2], na[4], nb[2];
  #pragma unroll
  for (int j = 0; j < 4; j++) ca[j] = *(const half8*)(Ag + j*8);
  cb[0] = *(const half8*)(Bg); cb[1] = *(const half8*)(Bg + 8);

  #pragma unroll
  for (int kt = 0; kt < HD; kt += 64){
    __syncthreads();
    #pragma unroll
    for (int j = 0; j < 4; j++) *(half8*)(Asw + j*8) = ca[j];
    *(half8*)(Bsw) = cb[0]; *(half8*)(Bsw + 8) = cb[1];
    if (kt + 64 < HD){
      #pragma unroll
      for (int j = 0; j < 4; j++) na[j] = *(const half8*)(Ag + kt + 64 + j*8);
      nb[0] = *(const half8*)(Bg + kt + 64); nb[1] = *(const half8*)(Bg + kt + 72);
    }
    __syncthreads();
    #pragma unroll
    for (int k0 = 0; k0 < 64; k0 += 32){
      half8 af[2], bf[4];
      #pragma unroll
      for (int mi = 0; mi < 2; mi++) af[mi] = *(const half8*)&As[(wm + mi*16 + l16)*PK + k0 + quad*8];
      #pragma unroll
      for (int ni = 0; ni < 4; ni++) bf[ni] = *(const half8*)&Bs[(ni*16 + l16)*PK + k0 + quad*8];
      #pragma unroll
      for (int mi = 0; mi < 2; mi++){
        #pragma unroll
        for (int ni = 0; ni < 4; ni++){
          acc[mi][ni] = __builtin_amdgcn_mfma_f32_16x16x32_f16(af[mi], bf[ni], acc[mi][ni], 0, 0, 0);
        }
      }
    }
    #pragma unroll
    for (int j = 0; j < 4; j++) ca[j] = na[j];
    cb[0] = nb[0]; cb[1] = nb[1];
  }

  float b1v[4], w2v[4];
  #pragma unroll
  for (int ni = 0; ni < 4; ni++){ b1v[ni] = b1[ni*16 + l16]; w2v[ni] = w2[ni*16 + l16]; }
  const float b2 = b2p[0];
  #pragma unroll
  for (int mi = 0; mi < 2; mi++){
    #pragma unroll
    for (int reg = 0; reg < 4; reg++){
      int r = m0 + wm + mi*16 + quad*4 + reg;
      bool ok = r < M;
      float mk = (ok && mask[r]) ? 1.f : 0.f;
      float t = 0.f;
      #pragma unroll
      for (int ni = 0; ni < 4; ni++){
        float v = leaky(acc[mi][ni][reg] + b1v[ni]) * mk;
        t += v * w2v[ni];
      }
      t += __shfl_xor(t, 1); t += __shfl_xor(t, 2);
      t += __shfl_xor(t, 4); t += __shfl_xor(t, 8);
      if (l16 == 0 && ok){
        float zv = leaky(t + b2) * mk;
        z2[r] = zv;
        unsigned u = __float_as_uint(zv);
        unsigned key = (u & 0x80000000u) ? ~u : (u | 0x80000000u);
        int gg = batch[r];
        atomicMax(&smx[gg], key); atomicMin(&smn[gg], key);
      }
    }
  }
  __syncthreads();
  if (tid < 64){
    unsigned vx = smx[tid], vn = smn[tid];
    if (vx != 0u)          atomicMax(&mx[tid], vx);
    if (vn != 0xFFFFFFFFu) atomicMin(&mn[tid], vn);
  }
}

// ---------------- BN apply: T = (affineP(T_prev) + leaky(bn(Hin)))*mask*invs ; stats of T -> st2 ----------------
template<bool RESID>
__global__ void k_bn_apply_stats(const unsigned* __restrict__ Hu, const float* __restrict__ g,
    const float* __restrict__ bb, const float* __restrict__ st,
    const unsigned* __restrict__ Pu, const float* __restrict__ stP,
    const float* __restrict__ gP, const float* __restrict__ bP,
    const int* __restrict__ mask, const float* __restrict__ invs,
    unsigned* __restrict__ Tu, float* __restrict__ st2)
{
  int tid = threadIdx.x; int c = tid<<1;
  const float inv_n = 1.f/(float)NN;
  float mu0 = st[c]*inv_n, mu1 = st[c+1]*inv_n;
  float var0 = st[HD+c]*inv_n - mu0*mu0;
  float var1 = st[HD+c+1]*inv_n - mu1*mu1;
  float sc0 = g[c]*rsqrtf(var0+BN_EPS), sc1 = g[c+1]*rsqrtf(var1+BN_EPS);
  float sh0 = bb[c] - mu0*sc0, sh1 = bb[c+1] - mu1*sc1;
  float pc0=0.f, pc1=0.f, ps0=0.f, ps1=0.f;
  if (RESID){
    float muP0 = stP[c]*inv_n, muP1 = stP[c+1]*inv_n;
    float varP0 = stP[HD+c]*inv_n - muP0*muP0;
    float varP1 = stP[HD+c+1]*inv_n - muP1*muP1;
    pc0 = gP[c]*rsqrtf(varP0+BN_EPS); pc1 = gP[c+1]*rsqrtf(varP1+BN_EPS);
    ps0 = bP[c] - muP0*pc0; ps1 = bP[c+1] - muP1*pc1;
  }
  float s0=0,s1=0,q0=0,q1=0;
  for (int r = blockIdx.x; r < NN; r += gridDim.x){
    unsigned u = Hu[(size_t)r*256 + tid];
    float v0 = leaky(fmaf(h2fu(u&0xFFFF), sc0, sh0));
    float v1 = leaky(fmaf(h2fu(u>>16),   sc1, sh1));
    if (RESID){
      unsigned pu = Pu[(size_t)r*256 + tid];
      v0 += fmaf(h2fu(pu&0xFFFF), pc0, ps0);
      v1 += fmaf(h2fu(pu>>16),    pc1, ps1);
    }
    float ww = mask[r] ? invs[r] : 0.f;
    v0 *= ww; v1 *= ww;
    Tu[(size_t)r*256 + tid] = packh2(v0, v1);
    s0+=v0; s1+=v1; q0+=v0*v0; q1+=v1*v1;
  }
  unsafeAtomicAdd(&st2[c],s0);      unsafeAtomicAdd(&st2[c+1],s1);
  unsafeAtomicAdd(&st2[HD+c],q0);   unsafeAtomicAdd(&st2[HD+c+1],q1);
}
// Xh(fp16) = affine(T) with stats st, params g,bb  (used once, before head)
__global__ void k_bn_final(const unsigned* __restrict__ Tu, const float* __restrict__ g,
    const float* __restrict__ bb, const float* __restrict__ st, unsigned* __restrict__ Xhu)
{
  long i = (long)blockIdx.x*blockDim.x + threadIdx.x;
  if (i >= (long)NN*256) return;
  int c = ((int)(i & 255)) << 1;
  const float inv_n = 1.f/(float)NN;
  float mu0 = st[c]*inv_n, mu1 = st[c+1]*inv_n;
  float var0 = st[HD+c]*inv_n - mu0*mu0;
  float var1 = st[HD+c+1]*inv_n - mu1*mu1;
  float sc0 = g[c]*rsqrtf(var0+BN_EPS), sc1 = g[c+1]*rsqrtf(var1+BN_EPS);
  float sh0 = bb[c] - mu0*sc0, sh1 = bb[c+1] - mu1*sc1;
  unsigned u = Tu[i];
  Xhu[i] = packh2(fmaf(h2fu(u&0xFFFF), sc0, sh0), fmaf(h2fu(u>>16), sc1, sh1));
}

// ---------------- final normalize ----------------
__device__ __forceinline__ float funkey(unsigned k){
  unsigned u = (k & 0x80000000u) ? (k & 0x7fffffffu) : ~k;
  return __uint_as_float(u);
}
__global__ void k_final(const float* __restrict__ z2, const int* __restrict__ batch,
                        const unsigned* __restrict__ mx, const unsigned* __restrict__ mn,
                        float* __restrict__ out){
  int i = blockIdx.x*blockDim.x + threadIdx.x;
  if (i < NN){
    int g = batch[i];
    float bmax = funkey(mx[g]), bmin = funkey(mn[g]);
    out[i] = (z2[i] - bmin) / ((bmax + 1e-6f) - bmin);
  }
}

extern "C" void kernel_launch(void* const* d_in, const int* in_sizes, int n_in,
                              void* d_out, int out_size, void* d_ws, size_t ws_size,
                              hipStream_t stream)
{
  const float* x      = (const float*)d_in[0];
  const int*   ei     = (const int*)d_in[1];
  const int*   src    = ei;
  const int*   dst    = ei + NE;
  const int*   batch  = (const int*)d_in[2];
  const float* c1_w1  = (const float*)d_in[3];
  const float* c1_b1  = (const float*)d_in[4];
  const float* c1_w2  = (const float*)d_in[5];
  const float* c1_b2  = (const float*)d_in[6];
  const float* c1_bng = (const float*)d_in[7];
  const float* c1_bnb = (const float*)d_in[8];
  const float* eps1   = (const float*)d_in[9];
  const float* bn1_g  = (const float*)d_in[10];
  const float* bn1_b  = (const float*)d_in[11];
  const float* cw1    = (const float*)d_in[12];
  const float* cb1    = (const float*)d_in[13];
  const float* cw2    = (const float*)d_in[14];
  const float* cb2    = (const float*)d_in[15];
  const float* cbn_g  = (const float*)d_in[16];
  const float* cbn_b  = (const float*)d_in[17];
  const float* ceps   = (const float*)d_in[18];
  const float* bns_g  = (const float*)d_in[19];
  const float* bns_b  = (const float*)d_in[20];
  const float* l1_w   = (const float*)d_in[21];
  const float* l1_b   = (const float*)d_in[22];
  const float* l2_w   = (const float*)d_in[23];
  const float* l2_b   = (const float*)d_in[24];
  float* out = (float*)d_out;

  const size_t NH = (size_t)NN*HD;
  unsigned short* buf0 = (unsigned short*)d_ws;   // fp16 NH
  unsigned short* buf1 = buf0 + NH;               // fp16 NH
  unsigned short* buf2 = buf1 + NH;               // fp16 NH
  float* h0   = (float*)(buf2 + NH);              // NN
  float* invs = h0 + NN;                          // NN
  float* z2   = invs + NN;                        // NN
  float* stG  = z2 + NN;                          // 1024
  float* stT  = stG + 1024;                       // 4 x 1024
  int* counts = (int*)(stT + 4*1024);             // 64
  unsigned* mx = (unsigned*)(counts + 64);        // 64
  unsigned* mn = mx + 64;                         // 64
  int* part = (int*)(mn + 64);                    // 256 (scan partials)
  int* deg  = part + 256;                         // NN
  int* off  = deg + NN;                           // NN
  int* cur  = off + NN;                           // NN
  int* srcs = cur + NN;                           // NE
  int* m[5];
  m[0] = srcs + NE;
  for (int k=1;k<5;k++) m[k] = m[k-1] + NN;
  unsigned short* wt[7];
  wt[0] = (unsigned short*)(m[4] + NN);
  for (int k=1;k<7;k++) wt[k] = wt[k-1] + HD*HD;
  unsigned short* w1t = wt[6] + HD*HD;            // 64*512 fp16

  const int TPB = 256;
  dim3 gN((NN+TPB-1)/TPB);
  dim3 gE((NE+TPB-1)/TPB);
  dim3 gNH((unsigned)((NH + TPB-1)/TPB));
  dim3 gNH2((unsigned)((NH/2 + TPB-1)/TPB));
  dim3 gmfma(HD/128, (NN+127)/128);   // bx = N-tile (fast) -> A-block L3 reuse
  dim3 ghead((NN+127)/128);

  // setup
  k_counts_bs<<<1, 64, 0, stream>>>(batch, counts);
  k_invs_mask0<<<gN, TPB, 0, stream>>>(batch, counts, x, invs, m[0]);
  for (int k=1;k<5;k++){
    k_mask_copy<<<gN,TPB,0,stream>>>(m[k-1], m[k]);
    k_mask_prop<<<gE,TPB,0,stream>>>(m[k-1], m[k], src, dst);
  }
  // CSR by dst (parallel 3-phase scan)
  hipMemsetAsync(deg, 0, NN*sizeof(int), stream);
  k_deg<<<gE,TPB,0,stream>>>(dst, deg);
  k_scan1<<<NPART,256,0,stream>>>(deg, part);
  k_scan2<<<1,256,0,stream>>>(part);
  k_scan3<<<NPART,256,0,stream>>>(deg, part, off, cur);
  k_scatter<<<gE,TPB,0,stream>>>(src, dst, cur, srcs);
  // weight prep: all 8 transposes in one launch
  W8 wp;
  wp.s[0] = c1_w2; wp.d[0] = wt[0]; wp.N[0] = HD;
  for (int i=0;i<3;i++){
    wp.s[1+i] = cw1 + (size_t)i*HD*HD; wp.d[1+i] = wt[1+i]; wp.N[1+i] = HD;
    wp.s[4+i] = cw2 + (size_t)i*HD*HD; wp.d[4+i] = wt[4+i]; wp.N[4+i] = HD;
  }
  wp.s[7] = l1_w; wp.d[7] = w1t; wp.N[7] = HIDN;
  k_w2ht8<<<dim3(HD/32, HD/32, 8),256,0,stream>>>(wp);

  // conv1: h1->buf1, gemm(+stats)->buf2, apply<false>->buf0 (= T0, stats stT[0])
  k_sagg_csr<<<gN,TPB,0,stream>>>(x, off, deg, srcs, eps1, h0);
  k_conv1_h1<<<gNH,TPB,0,stream>>>(h0, c1_w1, c1_b1, buf1);
  hipMemsetAsync(stG, 0, 1024*sizeof(float), stream);
  k_gemm_mfma<true><<<gmfma,256,0,stream>>>((const _Float16*)buf1, (const _Float16*)wt[0], c1_b2, (_Float16*)buf2, stG, NN);
  hipMemsetAsync(stT, 0, 1024*sizeof(float), stream);
  k_bn_apply_stats<false><<<512,256,0,stream>>>((unsigned*)buf2, c1_bng, c1_bnb, stG,
      nullptr, nullptr, nullptr, nullptr, m[1], invs, (unsigned*)buf0, stT);

  // rotation state
  unsigned short *P = buf0, *Q = buf1, *R = buf2;
  const float* stPrev = stT;
  const float* gPrev = bn1_g;
  const float* bPrev = bn1_b;

  for (int i=0;i<3;i++){
    k_agg_csr<<<NN,64,0,stream>>>((const _Float16*)P, off, deg, srcs, ceps+i,
                                  stPrev, gPrev, bPrev, (_Float16*)Q);
    k_gemm_mfma<false><<<gmfma,256,0,stream>>>((const _Float16*)Q, (const _Float16*)wt[1+i], cb1 + (size_t)i*HD, (_Float16*)R, nullptr, NN);
    hipMemsetAsync(stG, 0, 1024*sizeof(float), stream);
    k_gemm_mfma<true><<<gmfma,256,0,stream>>>((const _Float16*)R, (const _Float16*)wt[4+i], cb2 + (size_t)i*HD, (_Float16*)Q, stG, NN);
    float* stCur = stT + (i+1)*1024;
    hipMemsetAsync(stCur, 0, 1024*sizeof(float), stream);
    k_bn_apply_stats<true><<<512,256,0,stream>>>((unsigned*)Q, cbn_g + (size_t)i*HD, cbn_b + (size_t)i*HD, stG,
        (unsigned*)P, stPrev, gPrev, bPrev, m[i+2], invs, (unsigned*)R, stCur);
    unsigned short* tmp = P; P = R; R = tmp;
    stPrev = stCur;
    gPrev = bns_g + (size_t)i*HD;
    bPrev = bns_b + (size_t)i*HD;
  }

  // materialize Xh once: Q = affinePrev(P)
  k_bn_final<<<gNH2,TPB,0,stream>>>((const unsigned*)P, gPrev, bPrev, stPrev, (unsigned*)Q);

  // head: fused lin1+lin2 + per-block LDS minmax, then normalize
  hipMemsetAsync(mx, 0x00, 64*sizeof(unsigned), stream);
  hipMemsetAsync(mn, 0xFF, 64*sizeof(unsigned), stream);
  k_head<<<ghead,256,0,stream>>>((const _Float16*)Q, (const _Float16*)w1t, l1_b, l2_w, l2_b,
                                 m[4], batch, z2, mx, mn, NN);
  k_final<<<gN,TPB,0,stream>>>(z2, batch, mx, mn, out);
}

// Round 13
// 1205.204 us; speedup vs baseline: 1.5717x; 1.0336x over previous
//
#include <hip/hip_runtime.h>
#include <hip/hip_fp16.h>

#define NN 50000
#define NE 150000
#define HD 512
#define HIDN 64
#define BN_EPS 1e-5f
#define SLOPE 0.01f
#define NPART 196   // ceil(NN/256)

typedef _Float16 half8 __attribute__((ext_vector_type(8)));
typedef float floatx4 __attribute__((ext_vector_type(4)));

__device__ __forceinline__ float leaky(float v){ return v > 0.f ? v : SLOPE*v; }
__device__ __forceinline__ float h2fu(unsigned short u){ return __half2float(__ushort_as_half(u)); }
__device__ __forceinline__ unsigned short f2hu(float f){ return __half_as_ushort(__float2half(f)); }
__device__ __forceinline__ unsigned packh2(float a, float b){
  return (unsigned)f2hu(a) | ((unsigned)f2hu(b) << 16);
}

// ---------------- setup ----------------
__global__ void k_counts_bs(const int* __restrict__ batch, int* __restrict__ counts){
  int g = threadIdx.x;   // 0..63
  int lo = 0, hi = NN;
  while (lo < hi){ int mid = (lo+hi)>>1; if (batch[mid] <  g) lo = mid+1; else hi = mid; }
  int start = lo;
  lo = 0; hi = NN;
  while (lo < hi){ int mid = (lo+hi)>>1; if (batch[mid] <= g) lo = mid+1; else hi = mid; }
  counts[g] = lo - start;
}
// also zeros deg (runs before CSR build)
__global__ void k_invs_mask0(const int* __restrict__ batch, const int* __restrict__ counts,
                             const float* __restrict__ x, float* __restrict__ invs,
                             int* __restrict__ m0, int* __restrict__ deg){
  int i = blockIdx.x*blockDim.x + threadIdx.x;
  if (i < NN){
    invs[i] = rsqrtf((float)counts[batch[i]]);
    m0[i] = (fabsf(x[i]) > 0.f) ? 1 : 0;
    deg[i] = 0;
  }
}
// mask propagation via CSR gather (replaces copy+atomic-prop pairs)
__global__ void k_mask_gather(const int* __restrict__ mi, int* __restrict__ mo,
                              const int* __restrict__ off, const int* __restrict__ deg,
                              const int* __restrict__ srcs){
  int i = blockIdx.x*blockDim.x + threadIdx.x;
  if (i < NN){
    int v = mi[i];
    int o = off[i], d = deg[i];
    for (int j = 0; j < d; j++) v |= mi[srcs[o+j]];
    mo[i] = v ? 1 : 0;
  }
}

// ---------------- CSR build (by dst) ----------------
__global__ void k_deg(const int* __restrict__ dst, int* __restrict__ deg){
  int e = blockIdx.x*blockDim.x + threadIdx.x;
  if (e < NE) atomicAdd(&deg[dst[e]], 1);
}
__global__ void k_scan1(const int* __restrict__ deg, int* __restrict__ part){
  __shared__ int s[256];
  int t = threadIdx.x;
  int i = blockIdx.x*256 + t;
  s[t] = (i < NN) ? deg[i] : 0;
  __syncthreads();
  for (int d = 128; d > 0; d >>= 1){
    if (t < d) s[t] += s[t+d];
    __syncthreads();
  }
  if (t == 0) part[blockIdx.x] = s[0];
}
__global__ void k_scan2(int* __restrict__ part){
  __shared__ int s[256];
  int t = threadIdx.x;
  int own = (t < NPART) ? part[t] : 0;
  s[t] = own;
  __syncthreads();
  for (int d = 1; d < 256; d <<= 1){
    int v = (t >= d) ? s[t-d] : 0;
    __syncthreads();
    s[t] += v;
    __syncthreads();
  }
  if (t < NPART) part[t] = s[t] - own;   // exclusive
}
__global__ void k_scan3(const int* __restrict__ deg, const int* __restrict__ part,
                        int* __restrict__ off, int* __restrict__ cur){
  __shared__ int s[256];
  int t = threadIdx.x;
  int i = blockIdx.x*256 + t;
  int own = (i < NN) ? deg[i] : 0;
  s[t] = own;
  __syncthreads();
  for (int d = 1; d < 256; d <<= 1){
    int v = (t >= d) ? s[t-d] : 0;
    __syncthreads();
    s[t] += v;
    __syncthreads();
  }
  if (i < NN){
    int e = s[t] - own + part[blockIdx.x];
    off[i] = e; cur[i] = e;
  }
}
__global__ void k_scatter(const int* __restrict__ src, const int* __restrict__ dst,
                          int* __restrict__ cur, int* __restrict__ srcs){
  int e = blockIdx.x*blockDim.x + threadIdx.x;
  if (e < NE){
    int pos = atomicAdd(&cur[dst[e]], 1);
    srcs[pos] = src[e];
  }
}

// ---------------- weight prep: all 8 transposes in one launch (z-gridded) ----------------
struct W8 { const float* s[8]; unsigned short* d[8]; int N[8]; };
__global__ void k_w2ht8(W8 p){
  int z = blockIdx.z;
  const float* W = p.s[z]; unsigned short* Wt = p.d[z]; int N = p.N[z];
  int kb = blockIdx.x*32, nb = blockIdx.y*32;
  if (nb >= N) return;
  __shared__ float t[32][33];
  int tx = threadIdx.x & 31, ty = threadIdx.x >> 5;   // 32 x 8
  for (int r = 0; r < 32; r += 8)
    t[ty+r][tx] = W[(size_t)(kb+ty+r)*N + nb+tx];
  __syncthreads();
  for (int r = 0; r < 32; r += 8)
    Wt[(size_t)(nb+ty+r)*HD + kb+tx] = f2hu(t[tx][ty+r]);
}

// ---------------- conv1 front ----------------
__global__ void k_sagg_csr(const float* __restrict__ x, const int* __restrict__ off,
                           const int* __restrict__ deg, const int* __restrict__ srcs,
                           const float* __restrict__ epsp, float* __restrict__ h0){
  int i = blockIdx.x*blockDim.x + threadIdx.x;
  if (i < NN){
    float s = (1.f + epsp[0]) * x[i];
    int o = off[i], d = deg[i];
    for (int j = 0; j < d; j++) s += x[srcs[o + j]];
    h0[i] = s;
  }
}
// also zeros stG (z1) and stT (z2)
__global__ void k_conv1_h1(const float* __restrict__ h0, const float* __restrict__ w1,
                           const float* __restrict__ b1, unsigned short* __restrict__ C,
                           float* __restrict__ z1, float* __restrict__ z2){
  long idx = (long)blockIdx.x*blockDim.x + threadIdx.x;
  if (idx >= (long)NN*HD) return;
  if (idx < 1024) z1[idx] = 0.f;
  else if (idx < 2048) z2[idx-1024] = 0.f;
  int i = (int)(idx >> 9), c = (int)(idx & (HD-1));
  float v = fmaf(h0[i], w1[c], b1[c]);
  C[idx] = f2hu(v > 0.f ? v : 0.f);
}

// ---------------- gather+combine with on-the-fly BN affine (also zeros stGz) ----------------
__global__ void k_agg_csr(const _Float16* __restrict__ T, const int* __restrict__ off,
                          const int* __restrict__ deg, const int* __restrict__ srcs,
                          const float* __restrict__ epsp,
                          const float* __restrict__ st, const float* __restrict__ g,
                          const float* __restrict__ bb, _Float16* __restrict__ G,
                          float* __restrict__ stGz){
  int i = blockIdx.x;
  int t = threadIdx.x;          // 64 threads, 8 channels each
  if (i < 16) stGz[i*64 + t] = 0.f;
  int c0 = t << 3;
  const float inv_n = 1.f/(float)NN;
  float sc[8], sh[8];
  #pragma unroll
  for (int k = 0; k < 8; k++){
    int c = c0 + k;
    float mu = st[c]*inv_n;
    float var = st[HD+c]*inv_n - mu*mu;
    float s = g[c]*rsqrtf(var+BN_EPS);
    sc[k] = s; sh[k] = bb[c] - mu*s;
  }
  const half8* Tv = (const half8*)T;
  half8 p = Tv[(size_t)i*64 + t];
  float ep = 1.f + epsp[0];
  float acc[8];
  #pragma unroll
  for (int k = 0; k < 8; k++) acc[k] = (float)p[k] * ep;
  int o = off[i], d = deg[i];
  int j = 0;
  for (; j + 1 < d; j += 2){       // unroll-2: two row loads in flight
    int s0 = srcs[o + j], s1 = srcs[o + j + 1];
    half8 q0 = Tv[(size_t)s0*64 + t];
    half8 q1 = Tv[(size_t)s1*64 + t];
    #pragma unroll
    for (int k = 0; k < 8; k++) acc[k] += (float)q0[k] + (float)q1[k];
  }
  if (j < d){
    half8 q = Tv[(size_t)srcs[o + j]*64 + t];
    #pragma unroll
    for (int k = 0; k < 8; k++) acc[k] += (float)q[k];
  }
  float cnt = ep + (float)d;
  half8 r;
  #pragma unroll
  for (int k = 0; k < 8; k++) r[k] = (_Float16)fmaf(sc[k], acc[k], cnt*sh[k]);
  ((half8*)G)[(size_t)i*64 + t] = r;
}

// ---------------- MFMA GEMM: double-buffered LDS, ONE barrier/iter, dist-2 reg ring ----------------
// 128x128 tile, 4 waves x 64x64, BK=64, PK=72, LDS 2x36.9=73.7KB -> 2 blocks/CU.
// Hazard: writes(it) to buf[it&1] vs reads(it-2) of same buf are separated by barrier(it-1). Safe.
// zbuf (optional): block(0,0) zeros 1024 floats (stat buffer for a LATER kernel).
template<bool STATS>
__global__ __launch_bounds__(256) void k_gemm_mfma(const _Float16* __restrict__ A,
    const _Float16* __restrict__ Wt, const float* __restrict__ bias,
    _Float16* __restrict__ C, float* __restrict__ st, float* __restrict__ zbuf, int M)
{
  constexpr int PK = 72;
  constexpr int BUF = 128*PK;
  __shared__ __attribute__((aligned(16))) _Float16 As[2*BUF];
  __shared__ __attribute__((aligned(16))) _Float16 Bs[2*BUF];
  const int tid = threadIdx.x;
  if (zbuf && blockIdx.x == 0 && blockIdx.y == 0){
    for (int c = tid; c < 1024; c += 256) zbuf[c] = 0.f;
  }
  const int m0 = blockIdx.y * 128;
  const int n0 = blockIdx.x * 128;
  const int w = tid >> 6, lane = tid & 63;
  const int wm = (w >> 1) << 6, wn = (w & 1) << 6;
  const int quad = lane >> 4, l16 = lane & 15;

  floatx4 acc[4][4] = {};

  const int srow = tid >> 1;                 // 0..127
  const int skoff = (tid & 1) << 5;          // 0 or 32 halves
  int arow = m0 + srow; if (arow > M-1) arow = M-1;   // clamp (stores/stats guarded)
  const _Float16* Ag = A  + (size_t)arow*HD + skoff;
  const _Float16* Bg = Wt + (size_t)(n0 + srow)*HD + skoff;
  const int soff = srow*PK + skoff;

  half8 ra[3][4], rb[3][4];
  #pragma unroll
  for (int j = 0; j < 4; j++){
    ra[0][j] = *(const half8*)(Ag + j*8);       rb[0][j] = *(const half8*)(Bg + j*8);
    ra[1][j] = *(const half8*)(Ag + 64 + j*8);  rb[1][j] = *(const half8*)(Bg + 64 + j*8);
  }

  #pragma unroll
  for (int it = 0; it < 8; it++){
    const int cur = it % 3, nxt = (it + 2) % 3;
    const int b = (it & 1) * BUF;
    if (it + 2 < 8){
      #pragma unroll
      for (int j = 0; j < 4; j++){
        ra[nxt][j] = *(const half8*)(Ag + (it+2)*64 + j*8);
        rb[nxt][j] = *(const half8*)(Bg + (it+2)*64 + j*8);
      }
    }
    #pragma unroll
    for (int j = 0; j < 4; j++){
      *(half8*)(As + b + soff + j*8) = ra[cur][j];
      *(half8*)(Bs + b + soff + j*8) = rb[cur][j];
    }
    __syncthreads();
    #pragma unroll
    for (int k0 = 0; k0 < 64; k0 += 32){
      half8 af[4], bf[4];
      #pragma unroll
      for (int t4 = 0; t4 < 4; t4++){
        af[t4] = *(const half8*)(As + b + (wm + t4*16 + l16)*PK + k0 + quad*8);
        bf[t4] = *(const half8*)(Bs + b + (wn + t4*16 + l16)*PK + k0 + quad*8);
      }
      #pragma unroll
      for (int mi = 0; mi < 4; mi++){
        #pragma unroll
        for (int ni = 0; ni < 4; ni++){
          acc[mi][ni] = __builtin_amdgcn_mfma_f32_16x16x32_f16(af[mi], bf[ni], acc[mi][ni], 0, 0, 0);
        }
      }
    }
  }

  // epilogue: D row = quad*4+reg, col = l16 ; bias+relu+store (+stats)
  float sv[4] = {0,0,0,0}, qv[4] = {0,0,0,0};
  #pragma unroll
  for (int ni = 0; ni < 4; ni++){
    int ccol = n0 + wn + ni*16 + l16;
    float bs = bias[ccol];
    #pragma unroll
    for (int mi = 0; mi < 4; mi++){
      #pragma unroll
      for (int reg = 0; reg < 4; reg++){
        int r = m0 + wm + mi*16 + quad*4 + reg;
        float v = acc[mi][ni][reg] + bs;
        v = v > 0.f ? v : 0.f;
        if (r < M){
          C[(size_t)r*HD + ccol] = (_Float16)v;
          if (STATS){ sv[ni] += v; qv[ni] += v*v; }
        }
      }
    }
  }
  if (STATS){
    #pragma unroll
    for (int ni = 0; ni < 4; ni++){
      float s = sv[ni], q = qv[ni];
      s += __shfl_xor(s, 16); s += __shfl_xor(s, 32);
      q += __shfl_xor(q, 16); q += __shfl_xor(q, 32);
      if (quad == 0){
        int ccol = n0 + wn + ni*16 + l16;
        unsafeAtomicAdd(&st[ccol], s);
        unsafeAtomicAdd(&st[HD+ccol], q);
      }
    }
  }
}

// ---------------- fused head (pipelined) with per-block LDS min/max reduction ----------------
__global__ __launch_bounds__(256) void k_head(const _Float16* __restrict__ Xh,
    const _Float16* __restrict__ W1t, const float* __restrict__ b1,
    const float* __restrict__ w2, const float* __restrict__ b2p,
    const int* __restrict__ mask, const int* __restrict__ batch,
    float* __restrict__ z2, unsigned* __restrict__ mx, unsigned* __restrict__ mn, int M)
{
  constexpr int PK = 72;
  __shared__ __attribute__((aligned(16))) _Float16 As[128*PK];
  __shared__ __attribute__((aligned(16))) _Float16 Bs[64*PK];
  __shared__ unsigned smx[64], smn[64];
  const int tid = threadIdx.x;
  const int m0 = blockIdx.x * 128;
  const int w = tid >> 6, lane = tid & 63;
  const int wm = w << 5;
  const int quad = lane >> 4, l16 = lane & 15;

  if (tid < 64){ smx[tid] = 0u; smn[tid] = 0xFFFFFFFFu; }

  floatx4 acc[2][4] = {};

  const int srow = tid >> 1;
  const int skoff = (tid & 1) << 5;
  int arow = m0 + srow; if (arow > M-1) arow = M-1;
  const _Float16* Ag = Xh + (size_t)arow*HD + skoff;
  _Float16* Asw = As + srow*PK + skoff;
  const int brow = tid >> 2;
  const int bkoff = (tid & 3) << 4;
  const _Float16* Bg = W1t + (size_t)brow*HD + bkoff;
  _Float16* Bsw = Bs + brow*PK + bkoff;

  half8 ca[4], cb[2], na[4], nb[2];
  #pragma unroll
  for (int j = 0; j < 4; j++) ca[j] = *(const half8*)(Ag + j*8);
  cb[0] = *(const half8*)(Bg); cb[1] = *(const half8*)(Bg + 8);

  #pragma unroll
  for (int kt = 0; kt < HD; kt += 64){
    __syncthreads();
    #pragma unroll
    for (int j = 0; j < 4; j++) *(half8*)(Asw + j*8) = ca[j];
    *(half8*)(Bsw) = cb[0]; *(half8*)(Bsw + 8) = cb[1];
    if (kt + 64 < HD){
      #pragma unroll
      for (int j = 0; j < 4; j++) na[j] = *(const half8*)(Ag + kt + 64 + j*8);
      nb[0] = *(const half8*)(Bg + kt + 64); nb[1] = *(const half8*)(Bg + kt + 72);
    }
    __syncthreads();
    #pragma unroll
    for (int k0 = 0; k0 < 64; k0 += 32){
      half8 af[2], bf[4];
      #pragma unroll
      for (int mi = 0; mi < 2; mi++) af[mi] = *(const half8*)&As[(wm + mi*16 + l16)*PK + k0 + quad*8];
      #pragma unroll
      for (int ni = 0; ni < 4; ni++) bf[ni] = *(const half8*)&Bs[(ni*16 + l16)*PK + k0 + quad*8];
      #pragma unroll
      for (int mi = 0; mi < 2; mi++){
        #pragma unroll
        for (int ni = 0; ni < 4; ni++){
          acc[mi][ni] = __builtin_amdgcn_mfma_f32_16x16x32_f16(af[mi], bf[ni], acc[mi][ni], 0, 0, 0);
        }
      }
    }
    #pragma unroll
    for (int j = 0; j < 4; j++) ca[j] = na[j];
    cb[0] = nb[0]; cb[1] = nb[1];
  }

  float b1v[4], w2v[4];
  #pragma unroll
  for (int ni = 0; ni < 4; ni++){ b1v[ni] = b1[ni*16 + l16]; w2v[ni] = w2[ni*16 + l16]; }
  const float b2 = b2p[0];
  #pragma unroll
  for (int mi = 0; mi < 2; mi++){
    #pragma unroll
    for (int reg = 0; reg < 4; reg++){
      int r = m0 + wm + mi*16 + quad*4 + reg;
      bool ok = r < M;
      float mk = (ok && mask[r]) ? 1.f : 0.f;
      float t = 0.f;
      #pragma unroll
      for (int ni = 0; ni < 4; ni++){
        float v = leaky(acc[mi][ni][reg] + b1v[ni]) * mk;
        t += v * w2v[ni];
      }
      t += __shfl_xor(t, 1); t += __shfl_xor(t, 2);
      t += __shfl_xor(t, 4); t += __shfl_xor(t, 8);
      if (l16 == 0 && ok){
        float zv = leaky(t + b2) * mk;
        z2[r] = zv;
        unsigned u = __float_as_uint(zv);
        unsigned key = (u & 0x80000000u) ? ~u : (u | 0x80000000u);
        int gg = batch[r];
        atomicMax(&smx[gg], key); atomicMin(&smn[gg], key);
      }
    }
  }
  __syncthreads();
  if (tid < 64){
    unsigned vx = smx[tid], vn = smn[tid];
    if (vx != 0u)          atomicMax(&mx[tid], vx);
    if (vn != 0xFFFFFFFFu) atomicMin(&mn[tid], vn);
  }
}

// ---------------- BN apply: T = (affineP(T_prev) + leaky(bn(Hin)))*mask*invs ; stats of T -> st2 ----------------
template<bool RESID>
__global__ void k_bn_apply_stats(const unsigned* __restrict__ Hu, const float* __restrict__ g,
    const float* __restrict__ bb, const float* __restrict__ st,
    const unsigned* __restrict__ Pu, const float* __restrict__ stP,
    const float* __restrict__ gP, const float* __restrict__ bP,
    const int* __restrict__ mask, const float* __restrict__ invs,
    unsigned* __restrict__ Tu, float* __restrict__ st2)
{
  int tid = threadIdx.x; int c = tid<<1;
  const float inv_n = 1.f/(float)NN;
  float mu0 = st[c]*inv_n, mu1 = st[c+1]*inv_n;
  float var0 = st[HD+c]*inv_n - mu0*mu0;
  float var1 = st[HD+c+1]*inv_n - mu1*mu1;
  float sc0 = g[c]*rsqrtf(var0+BN_EPS), sc1 = g[c+1]*rsqrtf(var1+BN_EPS);
  float sh0 = bb[c] - mu0*sc0, sh1 = bb[c+1] - mu1*sc1;
  float pc0=0.f, pc1=0.f, ps0=0.f, ps1=0.f;
  if (RESID){
    float muP0 = stP[c]*inv_n, muP1 = stP[c+1]*inv_n;
    float varP0 = stP[HD+c]*inv_n - muP0*muP0;
    float varP1 = stP[HD+c+1]*inv_n - muP1*muP1;
    pc0 = gP[c]*rsqrtf(varP0+BN_EPS); pc1 = gP[c+1]*rsqrtf(varP1+BN_EPS);
    ps0 = bP[c] - muP0*pc0; ps1 = bP[c+1] - muP1*pc1;
  }
  float s0=0,s1=0,q0=0,q1=0;
  for (int r = blockIdx.x; r < NN; r += gridDim.x){
    unsigned u = Hu[(size_t)r*256 + tid];
    float v0 = leaky(fmaf(h2fu(u&0xFFFF), sc0, sh0));
    float v1 = leaky(fmaf(h2fu(u>>16),   sc1, sh1));
    if (RESID){
      unsigned pu = Pu[(size_t)r*256 + tid];
      v0 += fmaf(h2fu(pu&0xFFFF), pc0, ps0);
      v1 += fmaf(h2fu(pu>>16),    pc1, ps1);
    }
    float ww = mask[r] ? invs[r] : 0.f;
    v0 *= ww; v1 *= ww;
    Tu[(size_t)r*256 + tid] = packh2(v0, v1);
    s0+=v0; s1+=v1; q0+=v0*v0; q1+=v1*v1;
  }
  unsafeAtomicAdd(&st2[c],s0);      unsafeAtomicAdd(&st2[c+1],s1);
  unsafeAtomicAdd(&st2[HD+c],q0);   unsafeAtomicAdd(&st2[HD+c+1],q1);
}
// Xh(fp16) = affine(T); also initializes mx/mn for the head
__global__ void k_bn_final(const unsigned* __restrict__ Tu, const float* __restrict__ g,
    const float* __restrict__ bb, const float* __restrict__ st, unsigned* __restrict__ Xhu,
    unsigned* __restrict__ mx, unsigned* __restrict__ mn)
{
  long i = (long)blockIdx.x*blockDim.x + threadIdx.x;
  if (i >= (long)NN*256) return;
  if (i < 64) mx[i] = 0u;
  else if (i < 128) mn[i-64] = 0xFFFFFFFFu;
  int c = ((int)(i & 255)) << 1;
  const float inv_n = 1.f/(float)NN;
  float mu0 = st[c]*inv_n, mu1 = st[c+1]*inv_n;
  float var0 = st[HD+c]*inv_n - mu0*mu0;
  float var1 = st[HD+c+1]*inv_n - mu1*mu1;
  float sc0 = g[c]*rsqrtf(var0+BN_EPS), sc1 = g[c+1]*rsqrtf(var1+BN_EPS);
  float sh0 = bb[c] - mu0*sc0, sh1 = bb[c+1] - mu1*sc1;
  unsigned u = Tu[i];
  Xhu[i] = packh2(fmaf(h2fu(u&0xFFFF), sc0, sh0), fmaf(h2fu(u>>16), sc1, sh1));
}

// ---------------- final normalize ----------------
__device__ __forceinline__ float funkey(unsigned k){
  unsigned u = (k & 0x80000000u) ? (k & 0x7fffffffu) : ~k;
  return __uint_as_float(u);
}
__global__ void k_final(const float* __restrict__ z2, const int* __restrict__ batch,
                        const unsigned* __restrict__ mx, const unsigned* __restrict__ mn,
                        float* __restrict__ out){
  int i = blockIdx.x*blockDim.x + threadIdx.x;
  if (i < NN){
    int g = batch[i];
    float bmax = funkey(mx[g]), bmin = funkey(mn[g]);
    out[i] = (z2[i] - bmin) / ((bmax + 1e-6f) - bmin);
  }
}

extern "C" void kernel_launch(void* const* d_in, const int* in_sizes, int n_in,
                              void* d_out, int out_size, void* d_ws, size_t ws_size,
                              hipStream_t stream)
{
  const float* x      = (const float*)d_in[0];
  const int*   ei     = (const int*)d_in[1];
  const int*   src    = ei;
  const int*   dst    = ei + NE;
  const int*   batch  = (const int*)d_in[2];
  const float* c1_w1  = (const float*)d_in[3];
  const float* c1_b1  = (const float*)d_in[4];
  const float* c1_w2  = (const float*)d_in[5];
  const float* c1_b2  = (const float*)d_in[6];
  const float* c1_bng = (const float*)d_in[7];
  const float* c1_bnb = (const float*)d_in[8];
  const float* eps1   = (const float*)d_in[9];
  const float* bn1_g  = (const float*)d_in[10];
  const float* bn1_b  = (const float*)d_in[11];
  const float* cw1    = (const float*)d_in[12];
  const float* cb1    = (const float*)d_in[13];
  const float* cw2    = (const float*)d_in[14];
  const float* cb2    = (const float*)d_in[15];
  const float* cbn_g  = (const float*)d_in[16];
  const float* cbn_b  = (const float*)d_in[17];
  const float* ceps   = (const float*)d_in[18];
  const float* bns_g  = (const float*)d_in[19];
  const float* bns_b  = (const float*)d_in[20];
  const float* l1_w   = (const float*)d_in[21];
  const float* l1_b   = (const float*)d_in[22];
  const float* l2_w   = (const float*)d_in[23];
  const float* l2_b   = (const float*)d_in[24];
  float* out = (float*)d_out;

  const size_t NH = (size_t)NN*HD;
  unsigned short* buf0 = (unsigned short*)d_ws;   // fp16 NH
  unsigned short* buf1 = buf0 + NH;               // fp16 NH
  unsigned short* buf2 = buf1 + NH;               // fp16 NH
  float* h0   = (float*)(buf2 + NH);              // NN
  float* invs = h0 + NN;                          // NN
  float* z2   = invs + NN;                        // NN
  float* stG  = z2 + NN;                          // 1024
  float* stT  = stG + 1024;                       // 4 x 1024
  int* counts = (int*)(stT + 4*1024);             // 64
  unsigned* mx = (unsigned*)(counts + 64);        // 64
  unsigned* mn = mx + 64;                         // 64
  int* part = (int*)(mn + 64);                    // 256 (scan partials)
  int* deg  = part + 256;                         // NN
  int* off  = deg + NN;                           // NN
  int* cur  = off + NN;                           // NN
  int* srcs = cur + NN;                           // NE
  int* m[5];
  m[0] = srcs + NE;
  for (int k=1;k<5;k++) m[k] = m[k-1] + NN;
  unsigned short* wt[7];
  wt[0] = (unsigned short*)(m[4] + NN);
  for (int k=1;k<7;k++) wt[k] = wt[k-1] + HD*HD;
  unsigned short* w1t = wt[6] + HD*HD;            // 64*512 fp16

  const int TPB = 256;
  dim3 gN((NN+TPB-1)/TPB);
  dim3 gE((NE+TPB-1)/TPB);
  dim3 gNH((unsigned)((NH + TPB-1)/TPB));
  dim3 gNH2((unsigned)((NH/2 + TPB-1)/TPB));
  dim3 gmfma(HD/128, (NN+127)/128);
  dim3 ghead((NN+127)/128);

  // setup
  k_counts_bs<<<1, 64, 0, stream>>>(batch, counts);
  k_invs_mask0<<<gN, TPB, 0, stream>>>(batch, counts, x, invs, m[0], deg);
  // CSR by dst (parallel 3-phase scan)
  k_deg<<<gE,TPB,0,stream>>>(dst, deg);
  k_scan1<<<NPART,256,0,stream>>>(deg, part);
  k_scan2<<<1,256,0,stream>>>(part);
  k_scan3<<<NPART,256,0,stream>>>(deg, part, off, cur);
  k_scatter<<<gE,TPB,0,stream>>>(src, dst, cur, srcs);
  // masks via CSR gather
  for (int k=1;k<5;k++)
    k_mask_gather<<<gN,TPB,0,stream>>>(m[k-1], m[k], off, deg, srcs);
  // weight prep: all 8 transposes in one launch
  W8 wp;
  wp.s[0] = c1_w2; wp.d[0] = wt[0]; wp.N[0] = HD;
  for (int i=0;i<3;i++){
    wp.s[1+i] = cw1 + (size_t)i*HD*HD; wp.d[1+i] = wt[1+i]; wp.N[1+i] = HD;
    wp.s[4+i] = cw2 + (size_t)i*HD*HD; wp.d[4+i] = wt[4+i]; wp.N[4+i] = HD;
  }
  wp.s[7] = l1_w; wp.d[7] = w1t; wp.N[7] = HIDN;
  k_w2ht8<<<dim3(HD/32, HD/32, 8),256,0,stream>>>(wp);

  // conv1: h1->buf1 (zeros stG,stT), gemm(+stats)->buf2, apply<false>->buf0 (= T0, stats stT[0])
  k_sagg_csr<<<gN,TPB,0,stream>>>(x, off, deg, srcs, eps1, h0);
  k_conv1_h1<<<gNH,TPB,0,stream>>>(h0, c1_w1, c1_b1, buf1, stG, stT);
  k_gemm_mfma<true><<<gmfma,256,0,stream>>>((const _Float16*)buf1, (const _Float16*)wt[0], c1_b2, (_Float16*)buf2, stG, nullptr, NN);
  k_bn_apply_stats<false><<<1024,256,0,stream>>>((unsigned*)buf2, c1_bng, c1_bnb, stG,
      nullptr, nullptr, nullptr, nullptr, m[1], invs, (unsigned*)buf0, stT);

  // rotation state
  unsigned short *P = buf0, *Q = buf1, *R = buf2;
  const float* stPrev = stT;
  const float* gPrev = bn1_g;
  const float* bPrev = bn1_b;

  for (int i=0;i<3;i++){
    float* stCur = stT + (i+1)*1024;
    k_agg_csr<<<NN,64,0,stream>>>((const _Float16*)P, off, deg, srcs, ceps+i,
                                  stPrev, gPrev, bPrev, (_Float16*)Q, stG);
    k_gemm_mfma<false><<<gmfma,256,0,stream>>>((const _Float16*)Q, (const _Float16*)wt[1+i], cb1 + (size_t)i*HD, (_Float16*)R, nullptr, stCur, NN);
    k_gemm_mfma<true><<<gmfma,256,0,stream>>>((const _Float16*)R, (const _Float16*)wt[4+i], cb2 + (size_t)i*HD, (_Float16*)Q, stG, nullptr, NN);
    k_bn_apply_stats<true><<<1024,256,0,stream>>>((unsigned*)Q, cbn_g + (size_t)i*HD, cbn_b + (size_t)i*HD, stG,
        (unsigned*)P, stPrev, gPrev, bPrev, m[i+2], invs, (unsigned*)R, stCur);
    unsigned short* tmp = P; P = R; R = tmp;
    stPrev = stCur;
    gPrev = bns_g + (size_t)i*HD;
    bPrev = bns_b + (size_t)i*HD;
  }

  // materialize Xh once: Q = affinePrev(P); also init mx/mn
  k_bn_final<<<gNH2,TPB,0,stream>>>((const unsigned*)P, gPrev, bPrev, stPrev, (unsigned*)Q, mx, mn);

  // head: fused lin1+lin2 + per-block LDS minmax, then normalize
  k_head<<<ghead,256,0,stream>>>((const _Float16*)Q, (const _Float16*)w1t, l1_b, l2_w, l2_b,
                                 m[4], batch, z2, mx, mn, NN);
  k_final<<<gN,TPB,0,stream>>>(z2, batch, mx, mn, out);
}

// Round 14
// 1094.724 us; speedup vs baseline: 1.7303x; 1.1009x over previous
//
#include <hip/hip_runtime.h>
#include <hip/hip_fp16.h>

#define NN 50000
#define NE 150000
#define HD 512
#define HIDN 64
#define BN_EPS 1e-5f
#define SLOPE 0.01f
#define NPART 196   // ceil(NN/256)

typedef _Float16 half8 __attribute__((ext_vector_type(8)));
typedef float floatx4 __attribute__((ext_vector_type(4)));

__device__ __forceinline__ float leaky(float v){ return v > 0.f ? v : SLOPE*v; }
__device__ __forceinline__ float h2fu(unsigned short u){ return __half2float(__ushort_as_half(u)); }
__device__ __forceinline__ unsigned short f2hu(float f){ return __half_as_ushort(__float2half(f)); }
__device__ __forceinline__ unsigned packh2(float a, float b){
  return (unsigned)f2hu(a) | ((unsigned)f2hu(b) << 16);
}

// ---------------- setup ----------------
__global__ void k_counts_bs(const int* __restrict__ batch, int* __restrict__ counts){
  int g = threadIdx.x;   // 0..63
  int lo = 0, hi = NN;
  while (lo < hi){ int mid = (lo+hi)>>1; if (batch[mid] <  g) lo = mid+1; else hi = mid; }
  int start = lo;
  lo = 0; hi = NN;
  while (lo < hi){ int mid = (lo+hi)>>1; if (batch[mid] <= g) lo = mid+1; else hi = mid; }
  counts[g] = lo - start;
}
// also zeros deg (runs before CSR build)
__global__ void k_invs_mask0(const int* __restrict__ batch, const int* __restrict__ counts,
                             const float* __restrict__ x, float* __restrict__ invs,
                             int* __restrict__ m0, int* __restrict__ deg){
  int i = blockIdx.x*blockDim.x + threadIdx.x;
  if (i < NN){
    invs[i] = rsqrtf((float)counts[batch[i]]);
    m0[i] = (fabsf(x[i]) > 0.f) ? 1 : 0;
    deg[i] = 0;
  }
}
__global__ void k_mask_gather(const int* __restrict__ mi, int* __restrict__ mo,
                              const int* __restrict__ off, const int* __restrict__ deg,
                              const int* __restrict__ srcs){
  int i = blockIdx.x*blockDim.x + threadIdx.x;
  if (i < NN){
    int v = mi[i];
    int o = off[i], d = deg[i];
    for (int j = 0; j < d; j++) v |= mi[srcs[o+j]];
    mo[i] = v ? 1 : 0;
  }
}

// ---------------- CSR build (by dst) ----------------
__global__ void k_deg(const int* __restrict__ dst, int* __restrict__ deg){
  int e = blockIdx.x*blockDim.x + threadIdx.x;
  if (e < NE) atomicAdd(&deg[dst[e]], 1);
}
__global__ void k_scan1(const int* __restrict__ deg, int* __restrict__ part){
  __shared__ int s[256];
  int t = threadIdx.x;
  int i = blockIdx.x*256 + t;
  s[t] = (i < NN) ? deg[i] : 0;
  __syncthreads();
  for (int d = 128; d > 0; d >>= 1){
    if (t < d) s[t] += s[t+d];
    __syncthreads();
  }
  if (t == 0) part[blockIdx.x] = s[0];
}
__global__ void k_scan2(int* __restrict__ part){
  __shared__ int s[256];
  int t = threadIdx.x;
  int own = (t < NPART) ? part[t] : 0;
  s[t] = own;
  __syncthreads();
  for (int d = 1; d < 256; d <<= 1){
    int v = (t >= d) ? s[t-d] : 0;
    __syncthreads();
    s[t] += v;
    __syncthreads();
  }
  if (t < NPART) part[t] = s[t] - own;   // exclusive
}
__global__ void k_scan3(const int* __restrict__ deg, const int* __restrict__ part,
                        int* __restrict__ off, int* __restrict__ cur){
  __shared__ int s[256];
  int t = threadIdx.x;
  int i = blockIdx.x*256 + t;
  int own = (i < NN) ? deg[i] : 0;
  s[t] = own;
  __syncthreads();
  for (int d = 1; d < 256; d <<= 1){
    int v = (t >= d) ? s[t-d] : 0;
    __syncthreads();
    s[t] += v;
    __syncthreads();
  }
  if (i < NN){
    int e = s[t] - own + part[blockIdx.x];
    off[i] = e; cur[i] = e;
  }
}
__global__ void k_scatter(const int* __restrict__ src, const int* __restrict__ dst,
                          int* __restrict__ cur, int* __restrict__ srcs){
  int e = blockIdx.x*blockDim.x + threadIdx.x;
  if (e < NE){
    int pos = atomicAdd(&cur[dst[e]], 1);
    srcs[pos] = src[e];
  }
}

// ---------------- weight prep: all 8 transposes in one launch (z-gridded) ----------------
struct W8 { const float* s[8]; unsigned short* d[8]; int N[8]; };
__global__ void k_w2ht8(W8 p){
  int z = blockIdx.z;
  const float* W = p.s[z]; unsigned short* Wt = p.d[z]; int N = p.N[z];
  int kb = blockIdx.x*32, nb = blockIdx.y*32;
  if (nb >= N) return;
  __shared__ float t[32][33];
  int tx = threadIdx.x & 31, ty = threadIdx.x >> 5;   // 32 x 8
  for (int r = 0; r < 32; r += 8)
    t[ty+r][tx] = W[(size_t)(kb+ty+r)*N + nb+tx];
  __syncthreads();
  for (int r = 0; r < 32; r += 8)
    Wt[(size_t)(nb+ty+r)*HD + kb+tx] = f2hu(t[tx][ty+r]);
}

// ---------------- conv1 front: h0 = (1+eps)x + agg ; also zeros stG/stT ----------------
__global__ void k_sagg_csr(const float* __restrict__ x, const int* __restrict__ off,
                           const int* __restrict__ deg, const int* __restrict__ srcs,
                           const float* __restrict__ epsp, float* __restrict__ h0,
                           float* __restrict__ z1, float* __restrict__ z2){
  int i = blockIdx.x*blockDim.x + threadIdx.x;
  if (i < 1024){ z1[i] = 0.f; z2[i] = 0.f; }
  if (i < NN){
    float s = (1.f + epsp[0]) * x[i];
    int o = off[i], d = deg[i];
    for (int j = 0; j < d; j++) s += x[srcs[o + j]];
    h0[i] = s;
  }
}

// ---------------- gather+combine with on-the-fly BN affine (also zeros stGz) ----------------
__global__ void k_agg_csr(const _Float16* __restrict__ T, const int* __restrict__ off,
                          const int* __restrict__ deg, const int* __restrict__ srcs,
                          const float* __restrict__ epsp,
                          const float* __restrict__ st, const float* __restrict__ g,
                          const float* __restrict__ bb, _Float16* __restrict__ G,
                          float* __restrict__ stGz){
  int i = blockIdx.x;
  int t = threadIdx.x;          // 64 threads, 8 channels each
  if (i < 16) stGz[i*64 + t] = 0.f;
  int c0 = t << 3;
  const float inv_n = 1.f/(float)NN;
  float sc[8], sh[8];
  #pragma unroll
  for (int k = 0; k < 8; k++){
    int c = c0 + k;
    float mu = st[c]*inv_n;
    float var = st[HD+c]*inv_n - mu*mu;
    float s = g[c]*rsqrtf(var+BN_EPS);
    sc[k] = s; sh[k] = bb[c] - mu*s;
  }
  const half8* Tv = (const half8*)T;
  half8 p = Tv[(size_t)i*64 + t];
  float ep = 1.f + epsp[0];
  float acc[8];
  #pragma unroll
  for (int k = 0; k < 8; k++) acc[k] = (float)p[k] * ep;
  int o = off[i], d = deg[i];
  int j = 0;
  for (; j + 1 < d; j += 2){
    int s0 = srcs[o + j], s1 = srcs[o + j + 1];
    half8 q0 = Tv[(size_t)s0*64 + t];
    half8 q1 = Tv[(size_t)s1*64 + t];
    #pragma unroll
    for (int k = 0; k < 8; k++) acc[k] += (float)q0[k] + (float)q1[k];
  }
  if (j < d){
    half8 q = Tv[(size_t)srcs[o + j]*64 + t];
    #pragma unroll
    for (int k = 0; k < 8; k++) acc[k] += (float)q[k];
  }
  float cnt = ep + (float)d;
  half8 r;
  #pragma unroll
  for (int k = 0; k < 8; k++) r[k] = (_Float16)fmaf(sc[k], acc[k], cnt*sh[k]);
  ((half8*)G)[(size_t)i*64 + t] = r;
}

// ---------------- MFMA GEMM: dbuf LDS, dist-2 reg ring, XCD-swizzled 1D grid ----------------
// 128x128 tile, 4 waves x 64x64, BK=64, PK=72. CONV1: A generated on the fly from
// rank-1 relu(h0[i]*w1[k]+b1[k]). Epilogue: D bounced through LDS -> coalesced half8 stores.
// Grid swizzle: the 4 N-tiles sharing an A-block map to the same XCD (flat%8).
template<bool STATS, bool CONV1>
__global__ __launch_bounds__(256) void k_gemm_mfma(const _Float16* __restrict__ A,
    const _Float16* __restrict__ Wt, const float* __restrict__ bias,
    _Float16* __restrict__ C, float* __restrict__ st, float* __restrict__ zbuf,
    const float* __restrict__ h0, const float* __restrict__ w1f, const float* __restrict__ b1f,
    int M)
{
  constexpr int PK = 72;
  constexpr int BUF = 128*PK;
  __shared__ __attribute__((aligned(16))) _Float16 As[2*BUF];
  __shared__ __attribute__((aligned(16))) _Float16 Bs[2*BUF];
  const int tid = threadIdx.x;
  if (zbuf && blockIdx.x == 0){
    for (int c = tid; c < 1024; c += 256) zbuf[c] = 0.f;
  }
  // decode swizzled 1D grid: XCD = flat%8; blocks with same by share XCD
  const int Mb = (M + 127) >> 7;
  const int QB = (Mb + 7) >> 3;
  const int F = blockIdx.x;
  const int S = F & 7, rr = F >> 3;
  const int bx = rr / QB, q = rr % QB;
  const int by = q*8 + S;
  if (by >= Mb) return;
  const int m0 = by * 128;
  const int n0 = bx * 128;
  const int w = tid >> 6, lane = tid & 63;
  const int wm = (w >> 1) << 6, wn = (w & 1) << 6;
  const int quad = lane >> 4, l16 = lane & 15;

  floatx4 acc[4][4] = {};

  const int srow = tid >> 1;                 // 0..127
  const int skoff = (tid & 1) << 5;          // 0 or 32 halves
  int arow = m0 + srow; if (arow > M-1) arow = M-1;   // clamp (stores/stats guarded)
  const _Float16* Ag = A  + (CONV1 ? 0 : (size_t)arow*HD + skoff);
  const _Float16* Bg = Wt + (size_t)(n0 + srow)*HD + skoff;
  const int soff = srow*PK + skoff;
  float h0v = 0.f;
  if (CONV1) h0v = h0[arow];

  half8 ra[3][4], rb[3][4];
  #pragma unroll
  for (int j = 0; j < 4; j++){
    rb[0][j] = *(const half8*)(Bg + j*8);
    rb[1][j] = *(const half8*)(Bg + 64 + j*8);
    if (!CONV1){
      ra[0][j] = *(const half8*)(Ag + j*8);
      ra[1][j] = *(const half8*)(Ag + 64 + j*8);
    }
  }

  #pragma unroll
  for (int it = 0; it < 8; it++){
    const int cur = it % 3, nxt = (it + 2) % 3;
    const int b = (it & 1) * BUF;
    if (it + 2 < 8){
      #pragma unroll
      for (int j = 0; j < 4; j++){
        rb[nxt][j] = *(const half8*)(Bg + (it+2)*64 + j*8);
        if (!CONV1) ra[nxt][j] = *(const half8*)(Ag + (it+2)*64 + j*8);
      }
    }
    if (CONV1){
      const int kb = it*64 + skoff;
      const float4* w4 = (const float4*)(w1f + kb);
      const float4* b4 = (const float4*)(b1f + kb);
      #pragma unroll
      for (int j = 0; j < 4; j++){
        float4 wa = w4[2*j], wb = w4[2*j+1];
        float4 ba = b4[2*j], bb4 = b4[2*j+1];
        half8 av;
        float v0 = fmaf(h0v, wa.x, ba.x);  av[0] = (_Float16)(v0>0.f?v0:0.f);
        float v1 = fmaf(h0v, wa.y, ba.y);  av[1] = (_Float16)(v1>0.f?v1:0.f);
        float v2 = fmaf(h0v, wa.z, ba.z);  av[2] = (_Float16)(v2>0.f?v2:0.f);
        float v3 = fmaf(h0v, wa.w, ba.w);  av[3] = (_Float16)(v3>0.f?v3:0.f);
        float v4 = fmaf(h0v, wb.x, bb4.x); av[4] = (_Float16)(v4>0.f?v4:0.f);
        float v5 = fmaf(h0v, wb.y, bb4.y); av[5] = (_Float16)(v5>0.f?v5:0.f);
        float v6 = fmaf(h0v, wb.z, bb4.z); av[6] = (_Float16)(v6>0.f?v6:0.f);
        float v7 = fmaf(h0v, wb.w, bb4.w); av[7] = (_Float16)(v7>0.f?v7:0.f);
        *(half8*)(As + b + soff + j*8) = av;
        *(half8*)(Bs + b + soff + j*8) = rb[cur][j];
      }
    } else {
      #pragma unroll
      for (int j = 0; j < 4; j++){
        *(half8*)(As + b + soff + j*8) = ra[cur][j];
        *(half8*)(Bs + b + soff + j*8) = rb[cur][j];
      }
    }
    __syncthreads();
    #pragma unroll
    for (int k0 = 0; k0 < 64; k0 += 32){
      half8 af[4], bf[4];
      #pragma unroll
      for (int t4 = 0; t4 < 4; t4++){
        af[t4] = *(const half8*)(As + b + (wm + t4*16 + l16)*PK + k0 + quad*8);
        bf[t4] = *(const half8*)(Bs + b + (wn + t4*16 + l16)*PK + k0 + quad*8);
      }
      #pragma unroll
      for (int mi = 0; mi < 4; mi++){
        #pragma unroll
        for (int ni = 0; ni < 4; ni++){
          acc[mi][ni] = __builtin_amdgcn_mfma_f32_16x16x32_f16(af[mi], bf[ni], acc[mi][ni], 0, 0, 0);
        }
      }
    }
  }

  // epilogue: bias+relu (+stats), bounce D through LDS, coalesced half8 stores.
  __syncthreads();               // all MFMA reads done before As reuse
  constexpr int CP = 136;        // 272B rows, 16B aligned
  _Float16* Ds = As;             // 128*136 halfs = 34.8KB <= 36.9KB
  float sv[4] = {0,0,0,0}, qv[4] = {0,0,0,0};
  #pragma unroll
  for (int ni = 0; ni < 4; ni++){
    int ccol = wn + ni*16 + l16;
    float bs = bias[n0 + ccol];
    #pragma unroll
    for (int mi = 0; mi < 4; mi++){
      #pragma unroll
      for (int reg = 0; reg < 4; reg++){
        int row_l = wm + mi*16 + quad*4 + reg;
        float v = acc[mi][ni][reg] + bs;
        v = v > 0.f ? v : 0.f;
        Ds[row_l*CP + ccol] = (_Float16)v;
        if (STATS && (m0 + row_l < M)){ sv[ni] += v; qv[ni] += v*v; }
      }
    }
  }
  if (STATS){
    #pragma unroll
    for (int ni = 0; ni < 4; ni++){
      float s = sv[ni], qq = qv[ni];
      s += __shfl_xor(s, 16); s += __shfl_xor(s, 32);
      qq += __shfl_xor(qq, 16); qq += __shfl_xor(qq, 32);
      if (quad == 0){
        int ccol = n0 + wn + ni*16 + l16;
        unsafeAtomicAdd(&st[ccol], s);
        unsafeAtomicAdd(&st[HD+ccol], qq);
      }
    }
  }
  __syncthreads();
  #pragma unroll
  for (int s = 0; s < 8; s++){
    int chunk = tid + s*256;          // 0..2047
    int row_l = chunk >> 4;
    int colc  = (chunk & 15) << 3;
    int r = m0 + row_l;
    if (r < M)
      *(half8*)&C[(size_t)r*HD + n0 + colc] = *(const half8*)&Ds[row_l*CP + colc];
  }
}

// ---------------- head prep: fold last BN affine into lin1 weights; init mx/mn ----------------
// w1s[n][k] = sc[k]*w1t[n][k] (fp16) ; b1p[n] = b1[n] + sum_k sh[k]*w1t[n][k]
__global__ void k_headprep(const unsigned short* __restrict__ w1t, const float* __restrict__ b1,
    const float* __restrict__ st, const float* __restrict__ g, const float* __restrict__ bb,
    unsigned short* __restrict__ w1s, float* __restrict__ b1p,
    unsigned* __restrict__ mx, unsigned* __restrict__ mn){
  int n = blockIdx.x; int t = threadIdx.x;
  if (n == 0 && t < 64){ mx[t] = 0u; }
  if (n == 1 && t < 64){ mn[t] = 0xFFFFFFFFu; }
  __shared__ float red[256];
  const float inv_n = 1.f/(float)NN;
  float acc = 0.f;
  #pragma unroll
  for (int kk = 0; kk < 2; kk++){
    int k = t + kk*256;
    float mu = st[k]*inv_n;
    float var = st[HD+k]*inv_n - mu*mu;
    float sc = g[k]*rsqrtf(var+BN_EPS);
    float sh = bb[k] - mu*sc;
    float wv = h2fu(w1t[(size_t)n*HD + k]);
    w1s[(size_t)n*HD + k] = f2hu(sc*wv);
    acc += sh*wv;
  }
  red[t] = acc; __syncthreads();
  for (int d = 128; d > 0; d >>= 1){ if (t < d) red[t] += red[t+d]; __syncthreads(); }
  if (t == 0) b1p[n] = b1[n] + red[0];
}

// ---------------- fused head (pipelined) with per-block LDS min/max reduction ----------------
__global__ __launch_bounds__(256) void k_head(const _Float16* __restrict__ Xh,
    const _Float16* __restrict__ W1t, const float* __restrict__ b1,
    const float* __restrict__ w2, const float* __restrict__ b2p,
    const int* __restrict__ mask, const int* __restrict__ batch,
    float* __restrict__ z2, unsigned* __restrict__ mx, unsigned* __restrict__ mn, int M)
{
  constexpr int PK = 72;
  __shared__ __attribute__((aligned(16))) _Float16 As[128*PK];
  __shared__ __attribute__((aligned(16))) _Float16 Bs[64*PK];
  __shared__ unsigned smx[64], smn[64];
  const int tid = threadIdx.x;
  const int m0 = blockIdx.x * 128;
  const int w = tid >> 6, lane = tid & 63;
  const int wm = w << 5;
  const int quad = lane >> 4, l16 = lane & 15;

  if (tid < 64){ smx[tid] = 0u; smn[tid] = 0xFFFFFFFFu; }

  floatx4 acc[2][4] = {};

  const int srow = tid >> 1;
  const int skoff = (tid & 1) << 5;
  int arow = m0 + srow; if (arow > M-1) arow = M-1;
  const _Float16* Ag = Xh + (size_t)arow*HD + skoff;
  _Float16* Asw = As + srow*PK + skoff;
  const int brow = tid >> 2;
  const int bkoff = (tid & 3) << 4;
  const _Float16* Bg = W1t + (size_t)brow*HD + bkoff;
  _Float16* Bsw = Bs + brow*PK + bkoff;

  half8 ca[4], cb[2], na[4], nb[2];
  #pragma unroll
  for (int j = 0; j < 4; j++) ca[j] = *(const half8*)(Ag + j*8);
  cb[0] = *(const half8*)(Bg); cb[1] = *(const half8*)(Bg + 8);

  #pragma unroll
  for (int kt = 0; kt < HD; kt += 64){
    __syncthreads();
    #pragma unroll
    for (int j = 0; j < 4; j++) *(half8*)(Asw + j*8) = ca[j];
    *(half8*)(Bsw) = cb[0]; *(half8*)(Bsw + 8) = cb[1];
    if (kt + 64 < HD){
      #pragma unroll
      for (int j = 0; j < 4; j++) na[j] = *(const half8*)(Ag + kt + 64 + j*8);
      nb[0] = *(const half8*)(Bg + kt + 64); nb[1] = *(const half8*)(Bg + kt + 72);
    }
    __syncthreads();
    #pragma unroll
    for (int k0 = 0; k0 < 64; k0 += 32){
      half8 af[2], bf[4];
      #pragma unroll
      for (int mi = 0; mi < 2; mi++) af[mi] = *(const half8*)&As[(wm + mi*16 + l16)*PK + k0 + quad*8];
      #pragma unroll
      for (int ni = 0; ni < 4; ni++) bf[ni] = *(const half8*)&Bs[(ni*16 + l16)*PK + k0 + quad*8];
      #pragma unroll
      for (int mi = 0; mi < 2; mi++){
        #pragma unroll
        for (int ni = 0; ni < 4; ni++){
          acc[mi][ni] = __builtin_amdgcn_mfma_f32_16x16x32_f16(af[mi], bf[ni], acc[mi][ni], 0, 0, 0);
        }
      }
    }
    #pragma unroll
    for (int j = 0; j < 4; j++) ca[j] = na[j];
    cb[0] = nb[0]; cb[1] = nb[1];
  }

  float b1v[4], w2v[4];
  #pragma unroll
  for (int ni = 0; ni < 4; ni++){ b1v[ni] = b1[ni*16 + l16]; w2v[ni] = w2[ni*16 + l16]; }
  const float b2 = b2p[0];
  #pragma unroll
  for (int mi = 0; mi < 2; mi++){
    #pragma unroll
    for (int reg = 0; reg < 4; reg++){
      int r = m0 + wm + mi*16 + quad*4 + reg;
      bool ok = r < M;
      float mk = (ok && mask[r]) ? 1.f : 0.f;
      float t = 0.f;
      #pragma unroll
      for (int ni = 0; ni < 4; ni++){
        float v = leaky(acc[mi][ni][reg] + b1v[ni]) * mk;
        t += v * w2v[ni];
      }
      t += __shfl_xor(t, 1); t += __shfl_xor(t, 2);
      t += __shfl_xor(t, 4); t += __shfl_xor(t, 8);
      if (l16 == 0 && ok){
        float zv = leaky(t + b2) * mk;
        z2[r] = zv;
        unsigned u = __float_as_uint(zv);
        unsigned key = (u & 0x80000000u) ? ~u : (u | 0x80000000u);
        int gg = batch[r];
        atomicMax(&smx[gg], key); atomicMin(&smn[gg], key);
      }
    }
  }
  __syncthreads();
  if (tid < 64){
    unsigned vx = smx[tid], vn = smn[tid];
    if (vx != 0u)          atomicMax(&mx[tid], vx);
    if (vn != 0xFFFFFFFFu) atomicMin(&mn[tid], vn);
  }
}

// ---------------- BN apply: T = (affineP(T_prev) + leaky(bn(Hin)))*mask*invs ; stats of T -> st2 ----------------
template<bool RESID>
__global__ void k_bn_apply_stats(const unsigned* __restrict__ Hu, const float* __restrict__ g,
    const float* __restrict__ bb, const float* __restrict__ st,
    const unsigned* __restrict__ Pu, const float* __restrict__ stP,
    const float* __restrict__ gP, const float* __restrict__ bP,
    const int* __restrict__ mask, const float* __restrict__ invs,
    unsigned* __restrict__ Tu, float* __restrict__ st2)
{
  int tid = threadIdx.x; int c = tid<<1;
  const float inv_n = 1.f/(float)NN;
  float mu0 = st[c]*inv_n, mu1 = st[c+1]*inv_n;
  float var0 = st[HD+c]*inv_n - mu0*mu0;
  float var1 = st[HD+c+1]*inv_n - mu1*mu1;
  float sc0 = g[c]*rsqrtf(var0+BN_EPS), sc1 = g[c+1]*rsqrtf(var1+BN_EPS);
  float sh0 = bb[c] - mu0*sc0, sh1 = bb[c+1] - mu1*sc1;
  float pc0=0.f, pc1=0.f, ps0=0.f, ps1=0.f;
  if (RESID){
    float muP0 = stP[c]*inv_n, muP1 = stP[c+1]*inv_n;
    float varP0 = stP[HD+c]*inv_n - muP0*muP0;
    float varP1 = stP[HD+c+1]*inv_n - muP1*muP1;
    pc0 = gP[c]*rsqrtf(varP0+BN_EPS); pc1 = gP[c+1]*rsqrtf(varP1+BN_EPS);
    ps0 = bP[c] - muP0*pc0; ps1 = bP[c+1] - muP1*pc1;
  }
  float s0=0,s1=0,q0=0,q1=0;
  for (int r = blockIdx.x; r < NN; r += gridDim.x){
    unsigned u = Hu[(size_t)r*256 + tid];
    float v0 = leaky(fmaf(h2fu(u&0xFFFF), sc0, sh0));
    float v1 = leaky(fmaf(h2fu(u>>16),   sc1, sh1));
    if (RESID){
      unsigned pu = Pu[(size_t)r*256 + tid];
      v0 += fmaf(h2fu(pu&0xFFFF), pc0, ps0);
      v1 += fmaf(h2fu(pu>>16),    pc1, ps1);
    }
    float ww = mask[r] ? invs[r] : 0.f;
    v0 *= ww; v1 *= ww;
    Tu[(size_t)r*256 + tid] = packh2(v0, v1);
    s0+=v0; s1+=v1; q0+=v0*v0; q1+=v1*v1;
  }
  unsafeAtomicAdd(&st2[c],s0);      unsafeAtomicAdd(&st2[c+1],s1);
  unsafeAtomicAdd(&st2[HD+c],q0);   unsafeAtomicAdd(&st2[HD+c+1],q1);
}

// ---------------- final normalize ----------------
__device__ __forceinline__ float funkey(unsigned k){
  unsigned u = (k & 0x80000000u) ? (k & 0x7fffffffu) : ~k;
  return __uint_as_float(u);
}
__global__ void k_final(const float* __restrict__ z2, const int* __restrict__ batch,
                        const unsigned* __restrict__ mx, const unsigned* __restrict__ mn,
                        float* __restrict__ out){
  int i = blockIdx.x*blockDim.x + threadIdx.x;
  if (i < NN){
    int g = batch[i];
    float bmax = funkey(mx[g]), bmin = funkey(mn[g]);
    out[i] = (z2[i] - bmin) / ((bmax + 1e-6f) - bmin);
  }
}

extern "C" void kernel_launch(void* const* d_in, const int* in_sizes, int n_in,
                              void* d_out, int out_size, void* d_ws, size_t ws_size,
                              hipStream_t stream)
{
  const float* x      = (const float*)d_in[0];
  const int*   ei     = (const int*)d_in[1];
  const int*   src    = ei;
  const int*   dst    = ei + NE;
  const int*   batch  = (const int*)d_in[2];
  const float* c1_w1  = (const float*)d_in[3];
  const float* c1_b1  = (const float*)d_in[4];
  const float* c1_w2  = (const float*)d_in[5];
  const float* c1_b2  = (const float*)d_in[6];
  const float* c1_bng = (const float*)d_in[7];
  const float* c1_bnb = (const float*)d_in[8];
  const float* eps1   = (const float*)d_in[9];
  const float* bn1_g  = (const float*)d_in[10];
  const float* bn1_b  = (const float*)d_in[11];
  const float* cw1    = (const float*)d_in[12];
  const float* cb1    = (const float*)d_in[13];
  const float* cw2    = (const float*)d_in[14];
  const float* cb2    = (const float*)d_in[15];
  const float* cbn_g  = (const float*)d_in[16];
  const float* cbn_b  = (const float*)d_in[17];
  const float* ceps   = (const float*)d_in[18];
  const float* bns_g  = (const float*)d_in[19];
  const float* bns_b  = (const float*)d_in[20];
  const float* l1_w   = (const float*)d_in[21];
  const float* l1_b   = (const float*)d_in[22];
  const float* l2_w   = (const float*)d_in[23];
  const float* l2_b   = (const float*)d_in[24];
  float* out = (float*)d_out;

  const size_t NH = (size_t)NN*HD;
  unsigned short* buf0 = (unsigned short*)d_ws;   // fp16 NH
  unsigned short* buf1 = buf0 + NH;               // fp16 NH
  unsigned short* buf2 = buf1 + NH;               // fp16 NH
  float* h0   = (float*)(buf2 + NH);              // NN
  float* invs = h0 + NN;                          // NN
  float* z2   = invs + NN;                        // NN
  float* stG  = z2 + NN;                          // 1024
  float* stT  = stG + 1024;                       // 4 x 1024
  int* counts = (int*)(stT + 4*1024);             // 64
  unsigned* mx = (unsigned*)(counts + 64);        // 64
  unsigned* mn = mx + 64;                         // 64
  float* b1p  = (float*)(mn + 64);                // 64
  int* part = (int*)(b1p + 64);                   // 256 (scan partials)
  int* deg  = part + 256;                         // NN
  int* off  = deg + NN;                           // NN
  int* cur  = off + NN;                           // NN
  int* srcs = cur + NN;                           // NE
  int* m[5];
  m[0] = srcs + NE;
  for (int k=1;k<5;k++) m[k] = m[k-1] + NN;
  unsigned short* wt[7];
  wt[0] = (unsigned short*)(m[4] + NN);
  for (int k=1;k<7;k++) wt[k] = wt[k-1] + HD*HD;
  unsigned short* w1t = wt[6] + HD*HD;            // 64*512 fp16
  unsigned short* w1s = w1t + (size_t)HIDN*HD;    // 64*512 fp16 (affine-folded)

  const int TPB = 256;
  dim3 gN((NN+TPB-1)/TPB);
  dim3 gE((NE+TPB-1)/TPB);
  const int Mb = (NN+127)/128;          // 391
  const int QB = (Mb+7)/8;              // 49
  dim3 gmfma(32*QB);                    // 1568 swizzled 1D blocks
  dim3 ghead((NN+127)/128);

  // setup
  k_counts_bs<<<1, 64, 0, stream>>>(batch, counts);
  k_invs_mask0<<<gN, TPB, 0, stream>>>(batch, counts, x, invs, m[0], deg);
  // CSR by dst (parallel 3-phase scan)
  k_deg<<<gE,TPB,0,stream>>>(dst, deg);
  k_scan1<<<NPART,256,0,stream>>>(deg, part);
  k_scan2<<<1,256,0,stream>>>(part);
  k_scan3<<<NPART,256,0,stream>>>(deg, part, off, cur);
  k_scatter<<<gE,TPB,0,stream>>>(src, dst, cur, srcs);
  // masks via CSR gather
  for (int k=1;k<5;k++)
    k_mask_gather<<<gN,TPB,0,stream>>>(m[k-1], m[k], off, deg, srcs);
  // weight prep: all 8 transposes in one launch
  W8 wp;
  wp.s[0] = c1_w2; wp.d[0] = wt[0]; wp.N[0] = HD;
  for (int i=0;i<3;i++){
    wp.s[1+i] = cw1 + (size_t)i*HD*HD; wp.d[1+i] = wt[1+i]; wp.N[1+i] = HD;
    wp.s[4+i] = cw2 + (size_t)i*HD*HD; wp.d[4+i] = wt[4+i]; wp.N[4+i] = HD;
  }
  wp.s[7] = l1_w; wp.d[7] = w1t; wp.N[7] = HIDN;
  k_w2ht8<<<dim3(HD/32, HD/32, 8),256,0,stream>>>(wp);

  // conv1: h0 (zeros stG,stT[0]), fused rank-1 GEMM(+stats)->buf2, apply<false>->buf0
  k_sagg_csr<<<gN,TPB,0,stream>>>(x, off, deg, srcs, eps1, h0, stG, stT);
  k_gemm_mfma<true,true><<<gmfma,256,0,stream>>>(nullptr, (const _Float16*)wt[0], c1_b2,
      (_Float16*)buf2, stG, nullptr, h0, c1_w1, c1_b1, NN);
  k_bn_apply_stats<false><<<1024,256,0,stream>>>((unsigned*)buf2, c1_bng, c1_bnb, stG,
      nullptr, nullptr, nullptr, nullptr, m[1], invs, (unsigned*)buf0, stT);

  // rotation state
  unsigned short *P = buf0, *Q = buf1, *R = buf2;
  const float* stPrev = stT;
  const float* gPrev = bn1_g;
  const float* bPrev = bn1_b;

  for (int i=0;i<3;i++){
    float* stCur = stT + (i+1)*1024;
    k_agg_csr<<<NN,64,0,stream>>>((const _Float16*)P, off, deg, srcs, ceps+i,
                                  stPrev, gPrev, bPrev, (_Float16*)Q, stG);
    k_gemm_mfma<false,false><<<gmfma,256,0,stream>>>((const _Float16*)Q, (const _Float16*)wt[1+i],
        cb1 + (size_t)i*HD, (_Float16*)R, nullptr, stCur, nullptr, nullptr, nullptr, NN);
    k_gemm_mfma<true,false><<<gmfma,256,0,stream>>>((const _Float16*)R, (const _Float16*)wt[4+i],
        cb2 + (size_t)i*HD, (_Float16*)Q, stG, nullptr, nullptr, nullptr, nullptr, NN);
    k_bn_apply_stats<true><<<1024,256,0,stream>>>((unsigned*)Q, cbn_g + (size_t)i*HD, cbn_b + (size_t)i*HD, stG,
        (unsigned*)P, stPrev, gPrev, bPrev, m[i+2], invs, (unsigned*)R, stCur);
    unsigned short* tmp = P; P = R; R = tmp;
    stPrev = stCur;
    gPrev = bns_g + (size_t)i*HD;
    bPrev = bns_b + (size_t)i*HD;
  }

  // head: fold final BN affine into lin1 weights (also inits mx/mn), then fused head on raw P
  k_headprep<<<HIDN,256,0,stream>>>(w1t, l1_b, stPrev, gPrev, bPrev, w1s, b1p, mx, mn);
  k_head<<<ghead,256,0,stream>>>((const _Float16*)P, (const _Float16*)w1s, b1p, l2_w, l2_b,
                                 m[4], batch, z2, mx, mn, NN);
  k_final<<<gN,TPB,0,stream>>>(z2, batch, mx, mn, out);
}

// Round 15
// 938.241 us; speedup vs baseline: 2.0189x; 1.1668x over previous
//
#include <hip/hip_runtime.h>
#include <hip/hip_fp16.h>

#define NN 50000
#define NE 150000
#define HD 512
#define HIDN 64
#define BN_EPS 1e-5f
#define SLOPE 0.01f
#define NPART 196   // ceil(NN/256)

typedef _Float16 half8 __attribute__((ext_vector_type(8)));
typedef float floatx4 __attribute__((ext_vector_type(4)));

__device__ __forceinline__ float leaky(float v){ return v > 0.f ? v : SLOPE*v; }
__device__ __forceinline__ float h2fu(unsigned short u){ return __half2float(__ushort_as_half(u)); }
__device__ __forceinline__ unsigned short f2hu(float f){ return __half_as_ushort(__float2half(f)); }
__device__ __forceinline__ unsigned packh2(float a, float b){
  return (unsigned)f2hu(a) | ((unsigned)f2hu(b) << 16);
}

// ---------------- setup: invs (via inline binary-search counts) + mask0 + deg-zero ----------------
__global__ void k_invs_mask0(const int* __restrict__ batch, const float* __restrict__ x,
                             float* __restrict__ invs, int* __restrict__ m0, int* __restrict__ deg){
  int i = blockIdx.x*blockDim.x + threadIdx.x;
  if (i < NN){
    int g = batch[i];
    int lo = 0, hi = NN;
    while (lo < hi){ int mid = (lo+hi)>>1; if (batch[mid] <  g) lo = mid+1; else hi = mid; }
    int start = lo;
    lo = 0; hi = NN;
    while (lo < hi){ int mid = (lo+hi)>>1; if (batch[mid] <= g) lo = mid+1; else hi = mid; }
    invs[i] = rsqrtf((float)(lo - start));
    m0[i] = (fabsf(x[i]) > 0.f) ? 1 : 0;
    deg[i] = 0;
  }
}
__global__ void k_mask_gather(const int* __restrict__ mi, int* __restrict__ mo,
                              const int* __restrict__ off, const int* __restrict__ deg,
                              const int* __restrict__ srcs){
  int i = blockIdx.x*blockDim.x + threadIdx.x;
  if (i < NN){
    int v = mi[i];
    int o = off[i], d = deg[i];
    for (int j = 0; j < d; j++) v |= mi[srcs[o+j]];
    mo[i] = v ? 1 : 0;
  }
}

// ---------------- CSR build (by dst) ----------------
__global__ void k_deg(const int* __restrict__ dst, int* __restrict__ deg){
  int e = blockIdx.x*blockDim.x + threadIdx.x;
  if (e < NE) atomicAdd(&deg[dst[e]], 1);
}
__global__ void k_scan1(const int* __restrict__ deg, int* __restrict__ part){
  __shared__ int s[256];
  int t = threadIdx.x;
  int i = blockIdx.x*256 + t;
  s[t] = (i < NN) ? deg[i] : 0;
  __syncthreads();
  for (int d = 128; d > 0; d >>= 1){
    if (t < d) s[t] += s[t+d];
    __syncthreads();
  }
  if (t == 0) part[blockIdx.x] = s[0];
}
__global__ void k_scan2(int* __restrict__ part){
  __shared__ int s[256];
  int t = threadIdx.x;
  int own = (t < NPART) ? part[t] : 0;
  s[t] = own;
  __syncthreads();
  for (int d = 1; d < 256; d <<= 1){
    int v = (t >= d) ? s[t-d] : 0;
    __syncthreads();
    s[t] += v;
    __syncthreads();
  }
  if (t < NPART) part[t] = s[t] - own;   // exclusive
}
__global__ void k_scan3(const int* __restrict__ deg, const int* __restrict__ part,
                        int* __restrict__ off, int* __restrict__ cur){
  __shared__ int s[256];
  int t = threadIdx.x;
  int i = blockIdx.x*256 + t;
  int own = (i < NN) ? deg[i] : 0;
  s[t] = own;
  __syncthreads();
  for (int d = 1; d < 256; d <<= 1){
    int v = (t >= d) ? s[t-d] : 0;
    __syncthreads();
    s[t] += v;
    __syncthreads();
  }
  if (i < NN){
    int e = s[t] - own + part[blockIdx.x];
    off[i] = e; cur[i] = e;
  }
}
__global__ void k_scatter(const int* __restrict__ src, const int* __restrict__ dst,
                          int* __restrict__ cur, int* __restrict__ srcs){
  int e = blockIdx.x*blockDim.x + threadIdx.x;
  if (e < NE){
    int pos = atomicAdd(&cur[dst[e]], 1);
    srcs[pos] = src[e];
  }
}

// ---------------- weight prep: all 8 transposes in one launch (z-gridded) ----------------
struct W8 { const float* s[8]; unsigned short* d[8]; int N[8]; };
__global__ void k_w2ht8(W8 p){
  int z = blockIdx.z;
  const float* W = p.s[z]; unsigned short* Wt = p.d[z]; int N = p.N[z];
  int kb = blockIdx.x*32, nb = blockIdx.y*32;
  if (nb >= N) return;
  __shared__ float t[32][33];
  int tx = threadIdx.x & 31, ty = threadIdx.x >> 5;   // 32 x 8
  for (int r = 0; r < 32; r += 8)
    t[ty+r][tx] = W[(size_t)(kb+ty+r)*N + nb+tx];
  __syncthreads();
  for (int r = 0; r < 32; r += 8)
    Wt[(size_t)(nb+ty+r)*HD + kb+tx] = f2hu(t[tx][ty+r]);
}

// ---------------- conv1 front: h0 = (1+eps)x + agg ; also zeros stG/stT ----------------
__global__ void k_sagg_csr(const float* __restrict__ x, const int* __restrict__ off,
                           const int* __restrict__ deg, const int* __restrict__ srcs,
                           const float* __restrict__ epsp, float* __restrict__ h0,
                           float* __restrict__ z1, float* __restrict__ z2){
  int i = blockIdx.x*blockDim.x + threadIdx.x;
  if (i < 1024){ z1[i] = 0.f; z2[i] = 0.f; }
  if (i < NN){
    float s = (1.f + epsp[0]) * x[i];
    int o = off[i], d = deg[i];
    for (int j = 0; j < d; j++) s += x[srcs[o + j]];
    h0[i] = s;
  }
}

// ---------------- gather+combine with on-the-fly BN affine (also zeros stGz) ----------------
__global__ void k_agg_csr(const _Float16* __restrict__ T, const int* __restrict__ off,
                          const int* __restrict__ deg, const int* __restrict__ srcs,
                          const float* __restrict__ epsp,
                          const float* __restrict__ st, const float* __restrict__ g,
                          const float* __restrict__ bb, _Float16* __restrict__ G,
                          float* __restrict__ stGz){
  int i = blockIdx.x;
  int t = threadIdx.x;          // 64 threads, 8 channels each
  if (i < 16) stGz[i*64 + t] = 0.f;
  int c0 = t << 3;
  const float inv_n = 1.f/(float)NN;
  float sc[8], sh[8];
  #pragma unroll
  for (int k = 0; k < 8; k++){
    int c = c0 + k;
    float mu = st[c]*inv_n;
    float var = st[HD+c]*inv_n - mu*mu;
    float s = g[c]*rsqrtf(var+BN_EPS);
    sc[k] = s; sh[k] = bb[c] - mu*s;
  }
  const half8* Tv = (const half8*)T;
  half8 p = Tv[(size_t)i*64 + t];
  float ep = 1.f + epsp[0];
  float acc[8];
  #pragma unroll
  for (int k = 0; k < 8; k++) acc[k] = (float)p[k] * ep;
  int o = off[i], d = deg[i];
  int j = 0;
  for (; j + 1 < d; j += 2){
    int s0 = srcs[o + j], s1 = srcs[o + j + 1];
    half8 q0 = Tv[(size_t)s0*64 + t];
    half8 q1 = Tv[(size_t)s1*64 + t];
    #pragma unroll
    for (int k = 0; k < 8; k++) acc[k] += (float)q0[k] + (float)q1[k];
  }
  if (j < d){
    half8 q = Tv[(size_t)srcs[o + j]*64 + t];
    #pragma unroll
    for (int k = 0; k < 8; k++) acc[k] += (float)q[k];
  }
  float cnt = ep + (float)d;
  half8 r;
  #pragma unroll
  for (int k = 0; k < 8; k++) r[k] = (_Float16)fmaf(sc[k], acc[k], cnt*sh[k]);
  ((half8*)G)[(size_t)i*64 + t] = r;
}

// ---------------- MFMA GEMM: BK=32 single-buffer, dist-2 reg ring, XCD swizzle ----------------
// 128x128 tile, 4 waves x 64x64. LDS: A/B 2x10.2KB (+4KB conv1 w/b) -> 4-6 blocks/CU
// (r14 dbuf 73.7KB = 2 blocks/CU was the limiter: conv1 GEMM 112us with zero mem traffic).
// Epilogue: two 64-row LDS-bounce passes (fits small LDS), coalesced half8 stores.
template<bool STATS, bool CONV1>
__global__ __launch_bounds__(256) void k_gemm_mfma(const _Float16* __restrict__ A,
    const _Float16* __restrict__ Wt, const float* __restrict__ bias,
    _Float16* __restrict__ C, float* __restrict__ st, float* __restrict__ zbuf,
    const float* __restrict__ h0, const float* __restrict__ w1f, const float* __restrict__ b1f,
    int M)
{
  constexpr int PKh = 40;                 // padded K row (halves): 80B
  constexpr int HTILE = 128*PKh;          // 5120 halves
  __shared__ __attribute__((aligned(16))) _Float16 pool[2*HTILE + (CONV1 ? 2048 : 0)];
  _Float16* As = pool;
  _Float16* Bs = pool + HTILE;
  float* wbF = (float*)(pool + 2*HTILE);  // CONV1: w1[512], b1[512]
  const int tid = threadIdx.x;
  if (zbuf && blockIdx.x == 0){
    for (int c = tid; c < 1024; c += 256) zbuf[c] = 0.f;
  }
  // swizzled 1D grid: XCD = flat%8; the 4 N-tiles of an M-block share an XCD
  const int Mb = (M + 127) >> 7;
  const int QB = (Mb + 7) >> 3;
  const int F = blockIdx.x;
  const int S = F & 7, rr = F >> 3;
  const int bx = rr / QB, q = rr % QB;
  const int by = q*8 + S;
  if (by >= Mb) return;
  const int m0 = by * 128;
  const int n0 = bx * 128;
  const int w = tid >> 6, lane = tid & 63;
  const int wm = (w >> 1) << 6, wn = (w & 1) << 6;
  const int quad = lane >> 4, l16 = lane & 15;

  floatx4 acc[4][4] = {};

  const int srow = tid >> 1;                 // 0..127
  const int skoff = (tid & 1) << 4;          // 0 or 16 halves
  int arow = m0 + srow; if (arow > M-1) arow = M-1;
  const _Float16* Ag = A  + (CONV1 ? 0 : (size_t)arow*HD + skoff);
  const _Float16* Bg = Wt + (size_t)(n0 + srow)*HD + skoff;
  const int soff = srow*PKh + skoff;
  float h0v = 0.f;
  if (CONV1){
    h0v = h0[arow];
    for (int i2 = tid; i2 < 512; i2 += 256){
      wbF[i2] = w1f[i2]; wbF[512 + i2] = b1f[i2];
    }
  }

  half8 ra[3][2], rb[3][2];
  #pragma unroll
  for (int j = 0; j < 2; j++){
    rb[0][j] = *(const half8*)(Bg + j*8);
    rb[1][j] = *(const half8*)(Bg + 32 + j*8);
    if (!CONV1){
      ra[0][j] = *(const half8*)(Ag + j*8);
      ra[1][j] = *(const half8*)(Ag + 32 + j*8);
    }
  }

  #pragma unroll
  for (int it = 0; it < 16; it++){
    const int cur = it % 3, nxt = (it + 2) % 3;
    __syncthreads();                 // prior reads done (also covers wbF staging at it=0)
    if (CONV1){
      #pragma unroll
      for (int j = 0; j < 2; j++){
        half8 av;
        #pragma unroll
        for (int e = 0; e < 8; e++){
          int k = it*32 + skoff + j*8 + e;
          float v = fmaf(h0v, wbF[k], wbF[512 + k]);
          av[e] = (_Float16)(v > 0.f ? v : 0.f);
        }
        *(half8*)(As + soff + j*8) = av;
        *(half8*)(Bs + soff + j*8) = rb[cur][j];
      }
    } else {
      #pragma unroll
      for (int j = 0; j < 2; j++){
        *(half8*)(As + soff + j*8) = ra[cur][j];
        *(half8*)(Bs + soff + j*8) = rb[cur][j];
      }
    }
    if (it + 2 < 16){
      #pragma unroll
      for (int j = 0; j < 2; j++){
        rb[nxt][j] = *(const half8*)(Bg + (it+2)*32 + j*8);
        if (!CONV1) ra[nxt][j] = *(const half8*)(Ag + (it+2)*32 + j*8);
      }
    }
    __syncthreads();
    half8 af[4], bf[4];
    #pragma unroll
    for (int t4 = 0; t4 < 4; t4++){
      af[t4] = *(const half8*)(As + (wm + t4*16 + l16)*PKh + quad*8);
      bf[t4] = *(const half8*)(Bs + (wn + t4*16 + l16)*PKh + quad*8);
    }
    #pragma unroll
    for (int mi = 0; mi < 4; mi++){
      #pragma unroll
      for (int ni = 0; ni < 4; ni++){
        acc[mi][ni] = __builtin_amdgcn_mfma_f32_16x16x32_f16(af[mi], bf[ni], acc[mi][ni], 0, 0, 0);
      }
    }
  }

  // epilogue: two 64-row bounce passes through LDS (Ds = 64 x 136 halves, overlays A/B)
  constexpr int CP = 136;
  _Float16* Ds = pool;
  float sv[4] = {0,0,0,0}, qv[4] = {0,0,0,0};
  __syncthreads();                   // last MFMA reads done
  // pass A: waves 0,1 (local rows 0..63)
  if (w < 2){
    #pragma unroll
    for (int ni = 0; ni < 4; ni++){
      int ccol = wn + ni*16 + l16;
      float bs = bias[n0 + ccol];
      #pragma unroll
      for (int mi = 0; mi < 4; mi++){
        #pragma unroll
        for (int reg = 0; reg < 4; reg++){
          int rl = mi*16 + quad*4 + reg;     // 0..63
          float v = acc[mi][ni][reg] + bs;
          v = v > 0.f ? v : 0.f;
          Ds[rl*CP + ccol] = (_Float16)v;
          if (STATS && (m0 + rl < M)){ sv[ni] += v; qv[ni] += v*v; }
        }
      }
    }
  }
  __syncthreads();
  #pragma unroll
  for (int s = 0; s < 4; s++){
    int chunk = tid + s*256;               // 0..1023
    int rl = chunk >> 4, colc = (chunk & 15) << 3;
    int r = m0 + rl;
    if (r < M)
      *(half8*)&C[(size_t)r*HD + n0 + colc] = *(const half8*)&Ds[rl*CP + colc];
  }
  __syncthreads();
  // pass B: waves 2,3 (local rows 64..127)
  if (w >= 2){
    #pragma unroll
    for (int ni = 0; ni < 4; ni++){
      int ccol = wn + ni*16 + l16;
      float bs = bias[n0 + ccol];
      #pragma unroll
      for (int mi = 0; mi < 4; mi++){
        #pragma unroll
        for (int reg = 0; reg < 4; reg++){
          int rl = 64 + mi*16 + quad*4 + reg;  // 64..127
          float v = acc[mi][ni][reg] + bs;
          v = v > 0.f ? v : 0.f;
          Ds[(rl-64)*CP + ccol] = (_Float16)v;
          if (STATS && (m0 + rl < M)){ sv[ni] += v; qv[ni] += v*v; }
        }
      }
    }
  }
  __syncthreads();
  #pragma unroll
  for (int s = 0; s < 4; s++){
    int chunk = tid + s*256;
    int rl = chunk >> 4, colc = (chunk & 15) << 3;
    int r = m0 + 64 + rl;
    if (r < M)
      *(half8*)&C[(size_t)r*HD + n0 + colc] = *(const half8*)&Ds[rl*CP + colc];
  }
  if (STATS){
    #pragma unroll
    for (int ni = 0; ni < 4; ni++){
      float s = sv[ni], qq = qv[ni];
      s += __shfl_xor(s, 16); s += __shfl_xor(s, 32);
      qq += __shfl_xor(qq, 16); qq += __shfl_xor(qq, 32);
      if (quad == 0){
        int ccol = n0 + wn + ni*16 + l16;
        unsafeAtomicAdd(&st[ccol], s);
        unsafeAtomicAdd(&st[HD+ccol], qq);
      }
    }
  }
}

// ---------------- head prep: fold last BN affine into lin1 weights; init mx/mn ----------------
__global__ void k_headprep(const unsigned short* __restrict__ w1t, const float* __restrict__ b1,
    const float* __restrict__ st, const float* __restrict__ g, const float* __restrict__ bb,
    unsigned short* __restrict__ w1s, float* __restrict__ b1p,
    unsigned* __restrict__ mx, unsigned* __restrict__ mn){
  int n = blockIdx.x; int t = threadIdx.x;
  if (n == 0 && t < 64){ mx[t] = 0u; }
  if (n == 1 && t < 64){ mn[t] = 0xFFFFFFFFu; }
  __shared__ float red[256];
  const float inv_n = 1.f/(float)NN;
  float acc = 0.f;
  #pragma unroll
  for (int kk = 0; kk < 2; kk++){
    int k = t + kk*256;
    float mu = st[k]*inv_n;
    float var = st[HD+k]*inv_n - mu*mu;
    float sc = g[k]*rsqrtf(var+BN_EPS);
    float sh = bb[k] - mu*sc;
    float wv = h2fu(w1t[(size_t)n*HD + k]);
    w1s[(size_t)n*HD + k] = f2hu(sc*wv);
    acc += sh*wv;
  }
  red[t] = acc; __syncthreads();
  for (int d = 128; d > 0; d >>= 1){ if (t < d) red[t] += red[t+d]; __syncthreads(); }
  if (t == 0) b1p[n] = b1[n] + red[0];
}

// ---------------- fused head (pipelined) with per-block LDS min/max reduction ----------------
__global__ __launch_bounds__(256) void k_head(const _Float16* __restrict__ Xh,
    const _Float16* __restrict__ W1t, const float* __restrict__ b1,
    const float* __restrict__ w2, const float* __restrict__ b2p,
    const int* __restrict__ mask, const int* __restrict__ batch,
    float* __restrict__ z2, unsigned* __restrict__ mx, unsigned* __restrict__ mn, int M)
{
  constexpr int PK = 72;
  __shared__ __attribute__((aligned(16))) _Float16 As[128*PK];
  __shared__ __attribute__((aligned(16))) _Float16 Bs[64*PK];
  __shared__ unsigned smx[64], smn[64];
  const int tid = threadIdx.x;
  const int m0 = blockIdx.x * 128;
  const int w = tid >> 6, lane = tid & 63;
  const int wm = w << 5;
  const int quad = lane >> 4, l16 = lane & 15;

  if (tid < 64){ smx[tid] = 0u; smn[tid] = 0xFFFFFFFFu; }

  floatx4 acc[2][4] = {};

  const int srow = tid >> 1;
  const int skoff = (tid & 1) << 5;
  int arow = m0 + srow; if (arow > M-1) arow = M-1;
  const _Float16* Ag = Xh + (size_t)arow*HD + skoff;
  _Float16* Asw = As + srow*PK + skoff;
  const int brow = tid >> 2;
  const int bkoff = (tid & 3) << 4;
  const _Float16* Bg = W1t + (size_t)brow*HD + bkoff;
  _Float16* Bsw = Bs + brow*PK + bkoff;

  half8 ca[4], cb[2], na[4], nb[2];
  #pragma unroll
  for (int j = 0; j < 4; j++) ca[j] = *(const half8*)(Ag + j*8);
  cb[0] = *(const half8*)(Bg); cb[1] = *(const half8*)(Bg + 8);

  #pragma unroll
  for (int kt = 0; kt < HD; kt += 64){
    __syncthreads();
    #pragma unroll
    for (int j = 0; j < 4; j++) *(half8*)(Asw + j*8) = ca[j];
    *(half8*)(Bsw) = cb[0]; *(half8*)(Bsw + 8) = cb[1];
    if (kt + 64 < HD){
      #pragma unroll
      for (int j = 0; j < 4; j++) na[j] = *(const half8*)(Ag + kt + 64 + j*8);
      nb[0] = *(const half8*)(Bg + kt + 64); nb[1] = *(const half8*)(Bg + kt + 72);
    }
    __syncthreads();
    #pragma unroll
    for (int k0 = 0; k0 < 64; k0 += 32){
      half8 af[2], bf[4];
      #pragma unroll
      for (int mi = 0; mi < 2; mi++) af[mi] = *(const half8*)&As[(wm + mi*16 + l16)*PK + k0 + quad*8];
      #pragma unroll
      for (int ni = 0; ni < 4; ni++) bf[ni] = *(const half8*)&Bs[(ni*16 + l16)*PK + k0 + quad*8];
      #pragma unroll
      for (int mi = 0; mi < 2; mi++){
        #pragma unroll
        for (int ni = 0; ni < 4; ni++){
          acc[mi][ni] = __builtin_amdgcn_mfma_f32_16x16x32_f16(af[mi], bf[ni], acc[mi][ni], 0, 0, 0);
        }
      }
    }
    #pragma unroll
    for (int j = 0; j < 4; j++) ca[j] = na[j];
    cb[0] = nb[0]; cb[1] = nb[1];
  }

  float b1v[4], w2v[4];
  #pragma unroll
  for (int ni = 0; ni < 4; ni++){ b1v[ni] = b1[ni*16 + l16]; w2v[ni] = w2[ni*16 + l16]; }
  const float b2 = b2p[0];
  #pragma unroll
  for (int mi = 0; mi < 2; mi++){
    #pragma unroll
    for (int reg = 0; reg < 4; reg++){
      int r = m0 + wm + mi*16 + quad*4 + reg;
      bool ok = r < M;
      float mk = (ok && mask[r]) ? 1.f : 0.f;
      float t = 0.f;
      #pragma unroll
      for (int ni = 0; ni < 4; ni++){
        float v = leaky(acc[mi][ni][reg] + b1v[ni]) * mk;
        t += v * w2v[ni];
      }
      t += __shfl_xor(t, 1); t += __shfl_xor(t, 2);
      t += __shfl_xor(t, 4); t += __shfl_xor(t, 8);
      if (l16 == 0 && ok){
        float zv = leaky(t + b2) * mk;
        z2[r] = zv;
        unsigned u = __float_as_uint(zv);
        unsigned key = (u & 0x80000000u) ? ~u : (u | 0x80000000u);
        int gg = batch[r];
        atomicMax(&smx[gg], key); atomicMin(&smn[gg], key);
      }
    }
  }
  __syncthreads();
  if (tid < 64){
    unsigned vx = smx[tid], vn = smn[tid];
    if (vx != 0u)          atomicMax(&mx[tid], vx);
    if (vn != 0xFFFFFFFFu) atomicMin(&mn[tid], vn);
  }
}

// ---------------- BN apply: wave-per-row uint4, LDS stats reduction ----------------
// T = (affineP(T_prev) + leaky(bn(Hin)))*mask*invs ; stats of T -> st2. 512 blocks.
template<bool RESID>
__global__ __launch_bounds__(256) void k_bn_apply_stats(const uint4* __restrict__ Hu,
    const float* __restrict__ g, const float* __restrict__ bb, const float* __restrict__ st,
    const uint4* __restrict__ Pu, const float* __restrict__ stP,
    const float* __restrict__ gP, const float* __restrict__ bP,
    const int* __restrict__ mask, const float* __restrict__ invs,
    uint4* __restrict__ Tu, float* __restrict__ st2)
{
  __shared__ float ls[2048], lq[2048];
  const int tid = threadIdx.x;
  const int wave = tid >> 6, lane = tid & 63;
  const int c8 = lane << 3;
  const float inv_n = 1.f/(float)NN;
  float sc[8], sh[8], pc[8], ps[8];
  #pragma unroll
  for (int k = 0; k < 8; k++){
    int c = c8 + k;
    float mu = st[c]*inv_n;
    float var = st[HD+c]*inv_n - mu*mu;
    float s = g[c]*rsqrtf(var+BN_EPS);
    sc[k] = s; sh[k] = bb[c] - mu*s;
    if (RESID){
      float muP = stP[c]*inv_n;
      float varP = stP[HD+c]*inv_n - muP*muP;
      float sP = gP[c]*rsqrtf(varP+BN_EPS);
      pc[k] = sP; ps[k] = bP[c] - muP*sP;
    }
  }
  float s8[8] = {}, q8[8] = {};
  for (int r = blockIdx.x*4 + wave; r < NN; r += gridDim.x*4){
    uint4 u = Hu[(size_t)r*64 + lane];
    float hv[8];
    hv[0]=h2fu(u.x&0xFFFF); hv[1]=h2fu(u.x>>16);
    hv[2]=h2fu(u.y&0xFFFF); hv[3]=h2fu(u.y>>16);
    hv[4]=h2fu(u.z&0xFFFF); hv[5]=h2fu(u.z>>16);
    hv[6]=h2fu(u.w&0xFFFF); hv[7]=h2fu(u.w>>16);
    float v[8];
    #pragma unroll
    for (int k = 0; k < 8; k++) v[k] = leaky(fmaf(hv[k], sc[k], sh[k]));
    if (RESID){
      uint4 p = Pu[(size_t)r*64 + lane];
      float pv[8];
      pv[0]=h2fu(p.x&0xFFFF); pv[1]=h2fu(p.x>>16);
      pv[2]=h2fu(p.y&0xFFFF); pv[3]=h2fu(p.y>>16);
      pv[4]=h2fu(p.z&0xFFFF); pv[5]=h2fu(p.z>>16);
      pv[6]=h2fu(p.w&0xFFFF); pv[7]=h2fu(p.w>>16);
      #pragma unroll
      for (int k = 0; k < 8; k++) v[k] += fmaf(pv[k], pc[k], ps[k]);
    }
    float ww = mask[r] ? invs[r] : 0.f;
    uint4 o;
    o.x = packh2(v[0]*ww, v[1]*ww); o.y = packh2(v[2]*ww, v[3]*ww);
    o.z = packh2(v[4]*ww, v[5]*ww); o.w = packh2(v[6]*ww, v[7]*ww);
    Tu[(size_t)r*64 + lane] = o;
    #pragma unroll
    for (int k = 0; k < 8; k++){ float t = v[k]*ww; s8[k] += t; q8[k] += t*t; }
  }
  #pragma unroll
  for (int k = 0; k < 8; k++){
    ls[wave*512 + c8 + k] = s8[k];
    lq[wave*512 + c8 + k] = q8[k];
  }
  __syncthreads();
  for (int cc = tid; cc < 512; cc += 256){
    float S = ls[cc] + ls[512+cc] + ls[1024+cc] + ls[1536+cc];
    float Q = lq[cc] + lq[512+cc] + lq[1024+cc] + lq[1536+cc];
    unsafeAtomicAdd(&st2[cc], S);
    unsafeAtomicAdd(&st2[HD+cc], Q);
  }
}

// ---------------- final normalize ----------------
__device__ __forceinline__ float funkey(unsigned k){
  unsigned u = (k & 0x80000000u) ? (k & 0x7fffffffu) : ~k;
  return __uint_as_float(u);
}
__global__ void k_final(const float* __restrict__ z2, const int* __restrict__ batch,
                        const unsigned* __restrict__ mx, const unsigned* __restrict__ mn,
                        float* __restrict__ out){
  int i = blockIdx.x*blockDim.x + threadIdx.x;
  if (i < NN){
    int g = batch[i];
    float bmax = funkey(mx[g]), bmin = funkey(mn[g]);
    out[i] = (z2[i] - bmin) / ((bmax + 1e-6f) - bmin);
  }
}

extern "C" void kernel_launch(void* const* d_in, const int* in_sizes, int n_in,
                              void* d_out, int out_size, void* d_ws, size_t ws_size,
                              hipStream_t stream)
{
  const float* x      = (const float*)d_in[0];
  const int*   ei     = (const int*)d_in[1];
  const int*   src    = ei;
  const int*   dst    = ei + NE;
  const int*   batch  = (const int*)d_in[2];
  const float* c1_w1  = (const float*)d_in[3];
  const float* c1_b1  = (const float*)d_in[4];
  const float* c1_w2  = (const float*)d_in[5];
  const float* c1_b2  = (const float*)d_in[6];
  const float* c1_bng = (const float*)d_in[7];
  const float* c1_bnb = (const float*)d_in[8];
  const float* eps1   = (const float*)d_in[9];
  const float* bn1_g  = (const float*)d_in[10];
  const float* bn1_b  = (const float*)d_in[11];
  const float* cw1    = (const float*)d_in[12];
  const float* cb1    = (const float*)d_in[13];
  const float* cw2    = (const float*)d_in[14];
  const float* cb2    = (const float*)d_in[15];
  const float* cbn_g  = (const float*)d_in[16];
  const float* cbn_b  = (const float*)d_in[17];
  const float* ceps   = (const float*)d_in[18];
  const float* bns_g  = (const float*)d_in[19];
  const float* bns_b  = (const float*)d_in[20];
  const float* l1_w   = (const float*)d_in[21];
  const float* l1_b   = (const float*)d_in[22];
  const float* l2_w   = (const float*)d_in[23];
  const float* l2_b   = (const float*)d_in[24];
  float* out = (float*)d_out;

  const size_t NH = (size_t)NN*HD;
  unsigned short* buf0 = (unsigned short*)d_ws;   // fp16 NH
  unsigned short* buf1 = buf0 + NH;               // fp16 NH
  unsigned short* buf2 = buf1 + NH;               // fp16 NH
  float* h0   = (float*)(buf2 + NH);              // NN
  float* invs = h0 + NN;                          // NN
  float* z2   = invs + NN;                        // NN
  float* stG  = z2 + NN;                          // 1024
  float* stT  = stG + 1024;                       // 4 x 1024
  unsigned* mx = (unsigned*)(stT + 4*1024);       // 64
  unsigned* mn = mx + 64;                         // 64
  float* b1p  = (float*)(mn + 64);                // 64
  int* part = (int*)(b1p + 64);                   // 256 (scan partials)
  int* deg  = part + 256;                         // NN
  int* off  = deg + NN;                           // NN
  int* cur  = off + NN;                           // NN
  int* srcs = cur + NN;                           // NE
  int* m[5];
  m[0] = srcs + NE;
  for (int k=1;k<5;k++) m[k] = m[k-1] + NN;
  unsigned short* wt[7];
  wt[0] = (unsigned short*)(m[4] + NN);
  for (int k=1;k<7;k++) wt[k] = wt[k-1] + HD*HD;
  unsigned short* w1t = wt[6] + HD*HD;            // 64*512 fp16
  unsigned short* w1s = w1t + (size_t)HIDN*HD;    // 64*512 fp16 (affine-folded)

  const int TPB = 256;
  dim3 gN((NN+TPB-1)/TPB);
  dim3 gE((NE+TPB-1)/TPB);
  const int Mb = (NN+127)/128;          // 391
  const int QB = (Mb+7)/8;              // 49
  dim3 gmfma(8*4*QB);                   // 1568 swizzled 1D blocks
  dim3 ghead((NN+127)/128);

  // setup
  k_invs_mask0<<<gN, TPB, 0, stream>>>(batch, x, invs, m[0], deg);
  // CSR by dst (parallel 3-phase scan)
  k_deg<<<gE,TPB,0,stream>>>(dst, deg);
  k_scan1<<<NPART,256,0,stream>>>(deg, part);
  k_scan2<<<1,256,0,stream>>>(part);
  k_scan3<<<NPART,256,0,stream>>>(deg, part, off, cur);
  k_scatter<<<gE,TPB,0,stream>>>(src, dst, cur, srcs);
  // masks via CSR gather
  for (int k=1;k<5;k++)
    k_mask_gather<<<gN,TPB,0,stream>>>(m[k-1], m[k], off, deg, srcs);
  // weight prep: all 8 transposes in one launch
  W8 wp;
  wp.s[0] = c1_w2; wp.d[0] = wt[0]; wp.N[0] = HD;
  for (int i=0;i<3;i++){
    wp.s[1+i] = cw1 + (size_t)i*HD*HD; wp.d[1+i] = wt[1+i]; wp.N[1+i] = HD;
    wp.s[4+i] = cw2 + (size_t)i*HD*HD; wp.d[4+i] = wt[4+i]; wp.N[4+i] = HD;
  }
  wp.s[7] = l1_w; wp.d[7] = w1t; wp.N[7] = HIDN;
  k_w2ht8<<<dim3(HD/32, HD/32, 8),256,0,stream>>>(wp);

  // conv1: h0 (zeros stG,stT[0]), fused rank-1 GEMM(+stats)->buf2, apply<false>->buf0
  k_sagg_csr<<<gN,TPB,0,stream>>>(x, off, deg, srcs, eps1, h0, stG, stT);
  k_gemm_mfma<true,true><<<gmfma,256,0,stream>>>(nullptr, (const _Float16*)wt[0], c1_b2,
      (_Float16*)buf2, stG, nullptr, h0, c1_w1, c1_b1, NN);
  k_bn_apply_stats<false><<<512,256,0,stream>>>((const uint4*)buf2, c1_bng, c1_bnb, stG,
      nullptr, nullptr, nullptr, nullptr, m[1], invs, (uint4*)buf0, stT);

  // rotation state
  unsigned short *P = buf0, *Q = buf1, *R = buf2;
  const float* stPrev = stT;
  const float* gPrev = bn1_g;
  const float* bPrev = bn1_b;

  for (int i=0;i<3;i++){
    float* stCur = stT + (i+1)*1024;
    k_agg_csr<<<NN,64,0,stream>>>((const _Float16*)P, off, deg, srcs, ceps+i,
                                  stPrev, gPrev, bPrev, (_Float16*)Q, stG);
    k_gemm_mfma<false,false><<<gmfma,256,0,stream>>>((const _Float16*)Q, (const _Float16*)wt[1+i],
        cb1 + (size_t)i*HD, (_Float16*)R, nullptr, stCur, nullptr, nullptr, nullptr, NN);
    k_gemm_mfma<true,false><<<gmfma,256,0,stream>>>((const _Float16*)R, (const _Float16*)wt[4+i],
        cb2 + (size_t)i*HD, (_Float16*)Q, stG, nullptr, nullptr, nullptr, nullptr, NN);
    k_bn_apply_stats<true><<<512,256,0,stream>>>((const uint4*)Q, cbn_g + (size_t)i*HD, cbn_b + (size_t)i*HD, stG,
        (const uint4*)P, stPrev, gPrev, bPrev, m[i+2], invs, (uint4*)R, stCur);
    unsigned short* tmp = P; P = R; R = tmp;
    stPrev = stCur;
    gPrev = bns_g + (size_t)i*HD;
    bPrev = bns_b + (size_t)i*HD;
  }

  // head: fold final BN affine into lin1 weights (also inits mx/mn), then fused head on raw P
  k_headprep<<<HIDN,256,0,stream>>>(w1t, l1_b, stPrev, gPrev, bPrev, w1s, b1p, mx, mn);
  k_head<<<ghead,256,0,stream>>>((const _Float16*)P, (const _Float16*)w1s, b1p, l2_w, l2_b,
                                 m[4], batch, z2, mx, mn, NN);
  k_final<<<gN,TPB,0,stream>>>(z2, batch, mx, mn, out);
}

// Round 16
// 934.069 us; speedup vs baseline: 2.0279x; 1.0045x over previous
//
#include <hip/hip_runtime.h>
#include <hip/hip_fp16.h>

#define NN 50000
#define NE 150000
#define HD 512
#define HIDN 64
#define BN_EPS 1e-5f
#define SLOPE 0.01f
#define NPART 196   // ceil(NN/256)

typedef _Float16 half8 __attribute__((ext_vector_type(8)));
typedef float floatx4 __attribute__((ext_vector_type(4)));

__device__ __forceinline__ float leaky(float v){ return v > 0.f ? v : SLOPE*v; }
__device__ __forceinline__ float h2fu(unsigned short u){ return __half2float(__ushort_as_half(u)); }
__device__ __forceinline__ unsigned short f2hu(float f){ return __half_as_ushort(__float2half(f)); }
__device__ __forceinline__ unsigned packh2(float a, float b){
  return (unsigned)f2hu(a) | ((unsigned)f2hu(b) << 16);
}

// ---------------- setup: invs (via inline binary-search counts) + mask0 + deg-zero ----------------
__global__ void k_invs_mask0(const int* __restrict__ batch, const float* __restrict__ x,
                             float* __restrict__ invs, int* __restrict__ m0, int* __restrict__ deg){
  int i = blockIdx.x*blockDim.x + threadIdx.x;
  if (i < NN){
    int g = batch[i];
    int lo = 0, hi = NN;
    while (lo < hi){ int mid = (lo+hi)>>1; if (batch[mid] <  g) lo = mid+1; else hi = mid; }
    int start = lo;
    lo = 0; hi = NN;
    while (lo < hi){ int mid = (lo+hi)>>1; if (batch[mid] <= g) lo = mid+1; else hi = mid; }
    invs[i] = rsqrtf((float)(lo - start));
    m0[i] = (fabsf(x[i]) > 0.f) ? 1 : 0;
    deg[i] = 0;
  }
}
__global__ void k_mask_gather(const int* __restrict__ mi, int* __restrict__ mo,
                              const int* __restrict__ off, const int* __restrict__ deg,
                              const int* __restrict__ srcs){
  int i = blockIdx.x*blockDim.x + threadIdx.x;
  if (i < NN){
    int v = mi[i];
    int o = off[i], d = deg[i];
    for (int j = 0; j < d; j++) v |= mi[srcs[o+j]];
    mo[i] = v ? 1 : 0;
  }
}

// ---------------- CSR build (by dst) ----------------
__global__ void k_deg(const int* __restrict__ dst, int* __restrict__ deg){
  int e = blockIdx.x*blockDim.x + threadIdx.x;
  if (e < NE) atomicAdd(&deg[dst[e]], 1);
}
__global__ void k_scan1(const int* __restrict__ deg, int* __restrict__ part){
  __shared__ int s[256];
  int t = threadIdx.x;
  int i = blockIdx.x*256 + t;
  s[t] = (i < NN) ? deg[i] : 0;
  __syncthreads();
  for (int d = 128; d > 0; d >>= 1){
    if (t < d) s[t] += s[t+d];
    __syncthreads();
  }
  if (t == 0) part[blockIdx.x] = s[0];
}
__global__ void k_scan2(int* __restrict__ part){
  __shared__ int s[256];
  int t = threadIdx.x;
  int own = (t < NPART) ? part[t] : 0;
  s[t] = own;
  __syncthreads();
  for (int d = 1; d < 256; d <<= 1){
    int v = (t >= d) ? s[t-d] : 0;
    __syncthreads();
    s[t] += v;
    __syncthreads();
  }
  if (t < NPART) part[t] = s[t] - own;   // exclusive
}
__global__ void k_scan3(const int* __restrict__ deg, const int* __restrict__ part,
                        int* __restrict__ off, int* __restrict__ cur){
  __shared__ int s[256];
  int t = threadIdx.x;
  int i = blockIdx.x*256 + t;
  int own = (i < NN) ? deg[i] : 0;
  s[t] = own;
  __syncthreads();
  for (int d = 1; d < 256; d <<= 1){
    int v = (t >= d) ? s[t-d] : 0;
    __syncthreads();
    s[t] += v;
    __syncthreads();
  }
  if (i < NN){
    int e = s[t] - own + part[blockIdx.x];
    off[i] = e; cur[i] = e;
  }
}
__global__ void k_scatter(const int* __restrict__ src, const int* __restrict__ dst,
                          int* __restrict__ cur, int* __restrict__ srcs){
  int e = blockIdx.x*blockDim.x + threadIdx.x;
  if (e < NE){
    int pos = atomicAdd(&cur[dst[e]], 1);
    srcs[pos] = src[e];
  }
}

// ---------------- weight prep: all 8 transposes in one launch (z-gridded) ----------------
struct W8 { const float* s[8]; unsigned short* d[8]; int N[8]; };
__global__ void k_w2ht8(W8 p){
  int z = blockIdx.z;
  const float* W = p.s[z]; unsigned short* Wt = p.d[z]; int N = p.N[z];
  int kb = blockIdx.x*32, nb = blockIdx.y*32;
  if (nb >= N) return;
  __shared__ float t[32][33];
  int tx = threadIdx.x & 31, ty = threadIdx.x >> 5;   // 32 x 8
  for (int r = 0; r < 32; r += 8)
    t[ty+r][tx] = W[(size_t)(kb+ty+r)*N + nb+tx];
  __syncthreads();
  for (int r = 0; r < 32; r += 8)
    Wt[(size_t)(nb+ty+r)*HD + kb+tx] = f2hu(t[tx][ty+r]);
}

// ---------------- conv1 front: h0 = (1+eps)x + agg ; also zeros stG/stT ----------------
__global__ void k_sagg_csr(const float* __restrict__ x, const int* __restrict__ off,
                           const int* __restrict__ deg, const int* __restrict__ srcs,
                           const float* __restrict__ epsp, float* __restrict__ h0,
                           float* __restrict__ z1, float* __restrict__ z2){
  int i = blockIdx.x*blockDim.x + threadIdx.x;
  if (i < 1024){ z1[i] = 0.f; z2[i] = 0.f; }
  if (i < NN){
    float s = (1.f + epsp[0]) * x[i];
    int o = off[i], d = deg[i];
    for (int j = 0; j < d; j++) s += x[srcs[o + j]];
    h0[i] = s;
  }
}

// ---------------- gather+combine with on-the-fly BN affine (also zeros stGz) ----------------
// 256 threads = 4 waves, one node per wave (was 1 node / 64-thread block).
__global__ __launch_bounds__(256) void k_agg_csr(const _Float16* __restrict__ T,
                          const int* __restrict__ off,
                          const int* __restrict__ deg, const int* __restrict__ srcs,
                          const float* __restrict__ epsp,
                          const float* __restrict__ st, const float* __restrict__ g,
                          const float* __restrict__ bb, _Float16* __restrict__ G,
                          float* __restrict__ stGz){
  const int tid = threadIdx.x;
  const int wave = tid >> 6, t = tid & 63;
  if (blockIdx.x == 0){
    for (int c = tid; c < 1024; c += 256) stGz[c] = 0.f;
  }
  int i = blockIdx.x*4 + wave;
  if (i >= NN) return;
  int c0 = t << 3;
  const float inv_n = 1.f/(float)NN;
  float sc[8], sh[8];
  #pragma unroll
  for (int k = 0; k < 8; k++){
    int c = c0 + k;
    float mu = st[c]*inv_n;
    float var = st[HD+c]*inv_n - mu*mu;
    float s = g[c]*rsqrtf(var+BN_EPS);
    sc[k] = s; sh[k] = bb[c] - mu*s;
  }
  const half8* Tv = (const half8*)T;
  half8 p = Tv[(size_t)i*64 + t];
  float ep = 1.f + epsp[0];
  float acc[8];
  #pragma unroll
  for (int k = 0; k < 8; k++) acc[k] = (float)p[k] * ep;
  int o = off[i], d = deg[i];
  int j = 0;
  for (; j + 1 < d; j += 2){
    int s0 = srcs[o + j], s1 = srcs[o + j + 1];
    half8 q0 = Tv[(size_t)s0*64 + t];
    half8 q1 = Tv[(size_t)s1*64 + t];
    #pragma unroll
    for (int k = 0; k < 8; k++) acc[k] += (float)q0[k] + (float)q1[k];
  }
  if (j < d){
    half8 q = Tv[(size_t)srcs[o + j]*64 + t];
    #pragma unroll
    for (int k = 0; k < 8; k++) acc[k] += (float)q[k];
  }
  float cnt = ep + (float)d;
  half8 r;
  #pragma unroll
  for (int k = 0; k < 8; k++) r[k] = (_Float16)fmaf(sc[k], acc[k], cnt*sh[k]);
  ((half8*)G)[(size_t)i*64 + t] = r;
}

// ---------------- MFMA GEMM: BK=32 single-buffer, dist-2 reg ring, XCD swizzle ----------------
// 128x128 tile, 4 waves x 64x64. LDS A/B 2x10.2KB (+2KB fp16 conv1 w/b).
// CONV1 A-gen: wbH fp16 LDS read as half8 (4 ds_read_b128/thread/iter; r15's 32 scalar
// ds_read_b32 made conv1 the worst dispatch at 126us, 2x a mid GEMM).
template<bool STATS, bool CONV1>
__global__ __launch_bounds__(256) void k_gemm_mfma(const _Float16* __restrict__ A,
    const _Float16* __restrict__ Wt, const float* __restrict__ bias,
    _Float16* __restrict__ C, float* __restrict__ st, float* __restrict__ zbuf,
    const float* __restrict__ h0, const float* __restrict__ w1f, const float* __restrict__ b1f,
    int M)
{
  constexpr int PKh = 40;                 // padded K row (halves): 80B
  constexpr int HTILE = 128*PKh;          // 5120 halves
  __shared__ __attribute__((aligned(16))) _Float16 pool[2*HTILE + (CONV1 ? 1024 : 0)];
  _Float16* As = pool;
  _Float16* Bs = pool + HTILE;
  _Float16* wbH = pool + 2*HTILE;         // CONV1: w1[512], b1[512] in fp16
  const int tid = threadIdx.x;
  if (zbuf && blockIdx.x == 0){
    for (int c = tid; c < 1024; c += 256) zbuf[c] = 0.f;
  }
  // swizzled 1D grid: XCD = flat%8; the 4 N-tiles of an M-block share an XCD
  const int Mb = (M + 127) >> 7;
  const int QB = (Mb + 7) >> 3;
  const int F = blockIdx.x;
  const int S = F & 7, rr = F >> 3;
  const int bx = rr / QB, q = rr % QB;
  const int by = q*8 + S;
  if (by >= Mb) return;
  const int m0 = by * 128;
  const int n0 = bx * 128;
  const int w = tid >> 6, lane = tid & 63;
  const int wm = (w >> 1) << 6, wn = (w & 1) << 6;
  const int quad = lane >> 4, l16 = lane & 15;

  floatx4 acc[4][4] = {};

  const int srow = tid >> 1;                 // 0..127
  const int skoff = (tid & 1) << 4;          // 0 or 16 halves
  int arow = m0 + srow; if (arow > M-1) arow = M-1;
  const _Float16* Ag = A  + (CONV1 ? 0 : (size_t)arow*HD + skoff);
  const _Float16* Bg = Wt + (size_t)(n0 + srow)*HD + skoff;
  const int soff = srow*PKh + skoff;
  float h0v = 0.f;
  if (CONV1){
    h0v = h0[arow];
    for (int i2 = tid; i2 < 512; i2 += 256){
      wbH[i2] = (_Float16)w1f[i2];
      wbH[512 + i2] = (_Float16)b1f[i2];
    }
  }

  half8 ra[3][2], rb[3][2];
  #pragma unroll
  for (int j = 0; j < 2; j++){
    rb[0][j] = *(const half8*)(Bg + j*8);
    rb[1][j] = *(const half8*)(Bg + 32 + j*8);
    if (!CONV1){
      ra[0][j] = *(const half8*)(Ag + j*8);
      ra[1][j] = *(const half8*)(Ag + 32 + j*8);
    }
  }

  #pragma unroll
  for (int it = 0; it < 16; it++){
    const int cur = it % 3, nxt = (it + 2) % 3;
    __syncthreads();                 // prior reads done (also covers wbH staging at it=0)
    if (CONV1){
      #pragma unroll
      for (int j = 0; j < 2; j++){
        half8 wv = *(const half8*)(wbH + it*32 + skoff + j*8);
        half8 bv = *(const half8*)(wbH + 512 + it*32 + skoff + j*8);
        half8 av;
        #pragma unroll
        for (int e = 0; e < 8; e++){
          float v = fmaf(h0v, (float)wv[e], (float)bv[e]);
          av[e] = (_Float16)(v > 0.f ? v : 0.f);
        }
        *(half8*)(As + soff + j*8) = av;
        *(half8*)(Bs + soff + j*8) = rb[cur][j];
      }
    } else {
      #pragma unroll
      for (int j = 0; j < 2; j++){
        *(half8*)(As + soff + j*8) = ra[cur][j];
        *(half8*)(Bs + soff + j*8) = rb[cur][j];
      }
    }
    if (it + 2 < 16){
      #pragma unroll
      for (int j = 0; j < 2; j++){
        rb[nxt][j] = *(const half8*)(Bg + (it+2)*32 + j*8);
        if (!CONV1) ra[nxt][j] = *(const half8*)(Ag + (it+2)*32 + j*8);
      }
    }
    __syncthreads();
    half8 af[4], bf[4];
    #pragma unroll
    for (int t4 = 0; t4 < 4; t4++){
      af[t4] = *(const half8*)(As + (wm + t4*16 + l16)*PKh + quad*8);
      bf[t4] = *(const half8*)(Bs + (wn + t4*16 + l16)*PKh + quad*8);
    }
    #pragma unroll
    for (int mi = 0; mi < 4; mi++){
      #pragma unroll
      for (int ni = 0; ni < 4; ni++){
        acc[mi][ni] = __builtin_amdgcn_mfma_f32_16x16x32_f16(af[mi], bf[ni], acc[mi][ni], 0, 0, 0);
      }
    }
  }

  // epilogue: two 64-row bounce passes through LDS (Ds = 64 x 136 halves, overlays A/B)
  constexpr int CP = 136;
  _Float16* Ds = pool;
  float sv[4] = {0,0,0,0}, qv[4] = {0,0,0,0};
  __syncthreads();                   // last MFMA reads done
  if (w < 2){
    #pragma unroll
    for (int ni = 0; ni < 4; ni++){
      int ccol = wn + ni*16 + l16;
      float bs = bias[n0 + ccol];
      #pragma unroll
      for (int mi = 0; mi < 4; mi++){
        #pragma unroll
        for (int reg = 0; reg < 4; reg++){
          int rl = mi*16 + quad*4 + reg;     // 0..63
          float v = acc[mi][ni][reg] + bs;
          v = v > 0.f ? v : 0.f;
          Ds[rl*CP + ccol] = (_Float16)v;
          if (STATS && (m0 + rl < M)){ sv[ni] += v; qv[ni] += v*v; }
        }
      }
    }
  }
  __syncthreads();
  #pragma unroll
  for (int s = 0; s < 4; s++){
    int chunk = tid + s*256;               // 0..1023
    int rl = chunk >> 4, colc = (chunk & 15) << 3;
    int r = m0 + rl;
    if (r < M)
      *(half8*)&C[(size_t)r*HD + n0 + colc] = *(const half8*)&Ds[rl*CP + colc];
  }
  __syncthreads();
  if (w >= 2){
    #pragma unroll
    for (int ni = 0; ni < 4; ni++){
      int ccol = wn + ni*16 + l16;
      float bs = bias[n0 + ccol];
      #pragma unroll
      for (int mi = 0; mi < 4; mi++){
        #pragma unroll
        for (int reg = 0; reg < 4; reg++){
          int rl = 64 + mi*16 + quad*4 + reg;  // 64..127
          float v = acc[mi][ni][reg] + bs;
          v = v > 0.f ? v : 0.f;
          Ds[(rl-64)*CP + ccol] = (_Float16)v;
          if (STATS && (m0 + rl < M)){ sv[ni] += v; qv[ni] += v*v; }
        }
      }
    }
  }
  __syncthreads();
  #pragma unroll
  for (int s = 0; s < 4; s++){
    int chunk = tid + s*256;
    int rl = chunk >> 4, colc = (chunk & 15) << 3;
    int r = m0 + 64 + rl;
    if (r < M)
      *(half8*)&C[(size_t)r*HD + n0 + colc] = *(const half8*)&Ds[rl*CP + colc];
  }
  if (STATS){
    #pragma unroll
    for (int ni = 0; ni < 4; ni++){
      float s = sv[ni], qq = qv[ni];
      s += __shfl_xor(s, 16); s += __shfl_xor(s, 32);
      qq += __shfl_xor(qq, 16); qq += __shfl_xor(qq, 32);
      if (quad == 0){
        int ccol = n0 + wn + ni*16 + l16;
        unsafeAtomicAdd(&st[ccol], s);
        unsafeAtomicAdd(&st[HD+ccol], qq);
      }
    }
  }
}

// ---------------- head prep: fold last BN affine into lin1 weights; init mx/mn ----------------
__global__ void k_headprep(const unsigned short* __restrict__ w1t, const float* __restrict__ b1,
    const float* __restrict__ st, const float* __restrict__ g, const float* __restrict__ bb,
    unsigned short* __restrict__ w1s, float* __restrict__ b1p,
    unsigned* __restrict__ mx, unsigned* __restrict__ mn){
  int n = blockIdx.x; int t = threadIdx.x;
  if (n == 0 && t < 64){ mx[t] = 0u; }
  if (n == 1 && t < 64){ mn[t] = 0xFFFFFFFFu; }
  __shared__ float red[256];
  const float inv_n = 1.f/(float)NN;
  float acc = 0.f;
  #pragma unroll
  for (int kk = 0; kk < 2; kk++){
    int k = t + kk*256;
    float mu = st[k]*inv_n;
    float var = st[HD+k]*inv_n - mu*mu;
    float sc = g[k]*rsqrtf(var+BN_EPS);
    float sh = bb[k] - mu*sc;
    float wv = h2fu(w1t[(size_t)n*HD + k]);
    w1s[(size_t)n*HD + k] = f2hu(sc*wv);
    acc += sh*wv;
  }
  red[t] = acc; __syncthreads();
  for (int d = 128; d > 0; d >>= 1){ if (t < d) red[t] += red[t+d]; __syncthreads(); }
  if (t == 0) b1p[n] = b1[n] + red[0];
}

// ---------------- fused head (pipelined) with per-block LDS min/max reduction ----------------
__global__ __launch_bounds__(256) void k_head(const _Float16* __restrict__ Xh,
    const _Float16* __restrict__ W1t, const float* __restrict__ b1,
    const float* __restrict__ w2, const float* __restrict__ b2p,
    const int* __restrict__ mask, const int* __restrict__ batch,
    float* __restrict__ z2, unsigned* __restrict__ mx, unsigned* __restrict__ mn, int M)
{
  constexpr int PK = 72;
  __shared__ __attribute__((aligned(16))) _Float16 As[128*PK];
  __shared__ __attribute__((aligned(16))) _Float16 Bs[64*PK];
  __shared__ unsigned smx[64], smn[64];
  const int tid = threadIdx.x;
  const int m0 = blockIdx.x * 128;
  const int w = tid >> 6, lane = tid & 63;
  const int wm = w << 5;
  const int quad = lane >> 4, l16 = lane & 15;

  if (tid < 64){ smx[tid] = 0u; smn[tid] = 0xFFFFFFFFu; }

  floatx4 acc[2][4] = {};

  const int srow = tid >> 1;
  const int skoff = (tid & 1) << 5;
  int arow = m0 + srow; if (arow > M-1) arow = M-1;
  const _Float16* Ag = Xh + (size_t)arow*HD + skoff;
  _Float16* Asw = As + srow*PK + skoff;
  const int brow = tid >> 2;
  const int bkoff = (tid & 3) << 4;
  const _Float16* Bg = W1t + (size_t)brow*HD + bkoff;
  _Float16* Bsw = Bs + brow*PK + bkoff;

  half8 ca[4], cb[2], na[4], nb[2];
  #pragma unroll
  for (int j = 0; j < 4; j++) ca[j] = *(const half8*)(Ag + j*8);
  cb[0] = *(const half8*)(Bg); cb[1] = *(const half8*)(Bg + 8);

  #pragma unroll
  for (int kt = 0; kt < HD; kt += 64){
    __syncthreads();
    #pragma unroll
    for (int j = 0; j < 4; j++) *(half8*)(Asw + j*8) = ca[j];
    *(half8*)(Bsw) = cb[0]; *(half8*)(Bsw + 8) = cb[1];
    if (kt + 64 < HD){
      #pragma unroll
      for (int j = 0; j < 4; j++) na[j] = *(const half8*)(Ag + kt + 64 + j*8);
      nb[0] = *(const half8*)(Bg + kt + 64); nb[1] = *(const half8*)(Bg + kt + 72);
    }
    __syncthreads();
    #pragma unroll
    for (int k0 = 0; k0 < 64; k0 += 32){
      half8 af[2], bf[4];
      #pragma unroll
      for (int mi = 0; mi < 2; mi++) af[mi] = *(const half8*)&As[(wm + mi*16 + l16)*PK + k0 + quad*8];
      #pragma unroll
      for (int ni = 0; ni < 4; ni++) bf[ni] = *(const half8*)&Bs[(ni*16 + l16)*PK + k0 + quad*8];
      #pragma unroll
      for (int mi = 0; mi < 2; mi++){
        #pragma unroll
        for (int ni = 0; ni < 4; ni++){
          acc[mi][ni] = __builtin_amdgcn_mfma_f32_16x16x32_f16(af[mi], bf[ni], acc[mi][ni], 0, 0, 0);
        }
      }
    }
    #pragma unroll
    for (int j = 0; j < 4; j++) ca[j] = na[j];
    cb[0] = nb[0]; cb[1] = nb[1];
  }

  float b1v[4], w2v[4];
  #pragma unroll
  for (int ni = 0; ni < 4; ni++){ b1v[ni] = b1[ni*16 + l16]; w2v[ni] = w2[ni*16 + l16]; }
  const float b2 = b2p[0];
  #pragma unroll
  for (int mi = 0; mi < 2; mi++){
    #pragma unroll
    for (int reg = 0; reg < 4; reg++){
      int r = m0 + wm + mi*16 + quad*4 + reg;
      bool ok = r < M;
      float mk = (ok && mask[r]) ? 1.f : 0.f;
      float t = 0.f;
      #pragma unroll
      for (int ni = 0; ni < 4; ni++){
        float v = leaky(acc[mi][ni][reg] + b1v[ni]) * mk;
        t += v * w2v[ni];
      }
      t += __shfl_xor(t, 1); t += __shfl_xor(t, 2);
      t += __shfl_xor(t, 4); t += __shfl_xor(t, 8);
      if (l16 == 0 && ok){
        float zv = leaky(t + b2) * mk;
        z2[r] = zv;
        unsigned u = __float_as_uint(zv);
        unsigned key = (u & 0x80000000u) ? ~u : (u | 0x80000000u);
        int gg = batch[r];
        atomicMax(&smx[gg], key); atomicMin(&smn[gg], key);
      }
    }
  }
  __syncthreads();
  if (tid < 64){
    unsigned vx = smx[tid], vn = smn[tid];
    if (vx != 0u)          atomicMax(&mx[tid], vx);
    if (vn != 0xFFFFFFFFu) atomicMin(&mn[tid], vn);
  }
}

// ---------------- BN apply: wave-per-row uint4, LDS stats reduction ----------------
template<bool RESID>
__global__ __launch_bounds__(256) void k_bn_apply_stats(const uint4* __restrict__ Hu,
    const float* __restrict__ g, const float* __restrict__ bb, const float* __restrict__ st,
    const uint4* __restrict__ Pu, const float* __restrict__ stP,
    const float* __restrict__ gP, const float* __restrict__ bP,
    const int* __restrict__ mask, const float* __restrict__ invs,
    uint4* __restrict__ Tu, float* __restrict__ st2)
{
  __shared__ float ls[2048], lq[2048];
  const int tid = threadIdx.x;
  const int wave = tid >> 6, lane = tid & 63;
  const int c8 = lane << 3;
  const float inv_n = 1.f/(float)NN;
  float sc[8], sh[8], pc[8], ps[8];
  #pragma unroll
  for (int k = 0; k < 8; k++){
    int c = c8 + k;
    float mu = st[c]*inv_n;
    float var = st[HD+c]*inv_n - mu*mu;
    float s = g[c]*rsqrtf(var+BN_EPS);
    sc[k] = s; sh[k] = bb[c] - mu*s;
    if (RESID){
      float muP = stP[c]*inv_n;
      float varP = stP[HD+c]*inv_n - muP*muP;
      float sP = gP[c]*rsqrtf(varP+BN_EPS);
      pc[k] = sP; ps[k] = bP[c] - muP*sP;
    }
  }
  float s8[8] = {}, q8[8] = {};
  for (int r = blockIdx.x*4 + wave; r < NN; r += gridDim.x*4){
    uint4 u = Hu[(size_t)r*64 + lane];
    float hv[8];
    hv[0]=h2fu(u.x&0xFFFF); hv[1]=h2fu(u.x>>16);
    hv[2]=h2fu(u.y&0xFFFF); hv[3]=h2fu(u.y>>16);
    hv[4]=h2fu(u.z&0xFFFF); hv[5]=h2fu(u.z>>16);
    hv[6]=h2fu(u.w&0xFFFF); hv[7]=h2fu(u.w>>16);
    float v[8];
    #pragma unroll
    for (int k = 0; k < 8; k++) v[k] = leaky(fmaf(hv[k], sc[k], sh[k]));
    if (RESID){
      uint4 p = Pu[(size_t)r*64 + lane];
      float pv[8];
      pv[0]=h2fu(p.x&0xFFFF); pv[1]=h2fu(p.x>>16);
      pv[2]=h2fu(p.y&0xFFFF); pv[3]=h2fu(p.y>>16);
      pv[4]=h2fu(p.z&0xFFFF); pv[5]=h2fu(p.z>>16);
      pv[6]=h2fu(p.w&0xFFFF); pv[7]=h2fu(p.w>>16);
      #pragma unroll
      for (int k = 0; k < 8; k++) v[k] += fmaf(pv[k], pc[k], ps[k]);
    }
    float ww = mask[r] ? invs[r] : 0.f;
    uint4 o;
    o.x = packh2(v[0]*ww, v[1]*ww); o.y = packh2(v[2]*ww, v[3]*ww);
    o.z = packh2(v[4]*ww, v[5]*ww); o.w = packh2(v[6]*ww, v[7]*ww);
    Tu[(size_t)r*64 + lane] = o;
    #pragma unroll
    for (int k = 0; k < 8; k++){ float t = v[k]*ww; s8[k] += t; q8[k] += t*t; }
  }
  #pragma unroll
  for (int k = 0; k < 8; k++){
    ls[wave*512 + c8 + k] = s8[k];
    lq[wave*512 + c8 + k] = q8[k];
  }
  __syncthreads();
  for (int cc = tid; cc < 512; cc += 256){
    float S = ls[cc] + ls[512+cc] + ls[1024+cc] + ls[1536+cc];
    float Q = lq[cc] + lq[512+cc] + lq[1024+cc] + lq[1536+cc];
    unsafeAtomicAdd(&st2[cc], S);
    unsafeAtomicAdd(&st2[HD+cc], Q);
  }
}

// ---------------- final normalize ----------------
__device__ __forceinline__ float funkey(unsigned k){
  unsigned u = (k & 0x80000000u) ? (k & 0x7fffffffu) : ~k;
  return __uint_as_float(u);
}
__global__ void k_final(const float* __restrict__ z2, const int* __restrict__ batch,
                        const unsigned* __restrict__ mx, const unsigned* __restrict__ mn,
                        float* __restrict__ out){
  int i = blockIdx.x*blockDim.x + threadIdx.x;
  if (i < NN){
    int g = batch[i];
    float bmax = funkey(mx[g]), bmin = funkey(mn[g]);
    out[i] = (z2[i] - bmin) / ((bmax + 1e-6f) - bmin);
  }
}

extern "C" void kernel_launch(void* const* d_in, const int* in_sizes, int n_in,
                              void* d_out, int out_size, void* d_ws, size_t ws_size,
                              hipStream_t stream)
{
  const float* x      = (const float*)d_in[0];
  const int*   ei     = (const int*)d_in[1];
  const int*   src    = ei;
  const int*   dst    = ei + NE;
  const int*   batch  = (const int*)d_in[2];
  const float* c1_w1  = (const float*)d_in[3];
  const float* c1_b1  = (const float*)d_in[4];
  const float* c1_w2  = (const float*)d_in[5];
  const float* c1_b2  = (const float*)d_in[6];
  const float* c1_bng = (const float*)d_in[7];
  const float* c1_bnb = (const float*)d_in[8];
  const float* eps1   = (const float*)d_in[9];
  const float* bn1_g  = (const float*)d_in[10];
  const float* bn1_b  = (const float*)d_in[11];
  const float* cw1    = (const float*)d_in[12];
  const float* cb1    = (const float*)d_in[13];
  const float* cw2    = (const float*)d_in[14];
  const float* cb2    = (const float*)d_in[15];
  const float* cbn_g  = (const float*)d_in[16];
  const float* cbn_b  = (const float*)d_in[17];
  const float* ceps   = (const float*)d_in[18];
  const float* bns_g  = (const float*)d_in[19];
  const float* bns_b  = (const float*)d_in[20];
  const float* l1_w   = (const float*)d_in[21];
  const float* l1_b   = (const float*)d_in[22];
  const float* l2_w   = (const float*)d_in[23];
  const float* l2_b   = (const float*)d_in[24];
  float* out = (float*)d_out;

  const size_t NH = (size_t)NN*HD;
  unsigned short* buf0 = (unsigned short*)d_ws;   // fp16 NH
  unsigned short* buf1 = buf0 + NH;               // fp16 NH
  unsigned short* buf2 = buf1 + NH;               // fp16 NH
  float* h0   = (float*)(buf2 + NH);              // NN
  float* invs = h0 + NN;                          // NN
  float* z2   = invs + NN;                        // NN
  float* stG  = z2 + NN;                          // 1024
  float* stT  = stG + 1024;                       // 4 x 1024
  unsigned* mx = (unsigned*)(stT + 4*1024);       // 64
  unsigned* mn = mx + 64;                         // 64
  float* b1p  = (float*)(mn + 64);                // 64
  int* part = (int*)(b1p + 64);                   // 256 (scan partials)
  int* deg  = part + 256;                         // NN
  int* off  = deg + NN;                           // NN
  int* cur  = off + NN;                           // NN
  int* srcs = cur + NN;                           // NE
  int* m[5];
  m[0] = srcs + NE;
  for (int k=1;k<5;k++) m[k] = m[k-1] + NN;
  unsigned short* wt[7];
  wt[0] = (unsigned short*)(m[4] + NN);
  for (int k=1;k<7;k++) wt[k] = wt[k-1] + HD*HD;
  unsigned short* w1t = wt[6] + HD*HD;            // 64*512 fp16
  unsigned short* w1s = w1t + (size_t)HIDN*HD;    // 64*512 fp16 (affine-folded)

  const int TPB = 256;
  dim3 gN((NN+TPB-1)/TPB);
  dim3 gE((NE+TPB-1)/TPB);
  const int Mb = (NN+127)/128;          // 391
  const int QB = (Mb+7)/8;              // 49
  dim3 gmfma(8*4*QB);                   // 1568 swizzled 1D blocks
  dim3 ghead((NN+127)/128);
  dim3 gagg((NN+3)/4);

  // setup
  k_invs_mask0<<<gN, TPB, 0, stream>>>(batch, x, invs, m[0], deg);
  // CSR by dst (parallel 3-phase scan)
  k_deg<<<gE,TPB,0,stream>>>(dst, deg);
  k_scan1<<<NPART,256,0,stream>>>(deg, part);
  k_scan2<<<1,256,0,stream>>>(part);
  k_scan3<<<NPART,256,0,stream>>>(deg, part, off, cur);
  k_scatter<<<gE,TPB,0,stream>>>(src, dst, cur, srcs);
  // masks via CSR gather
  for (int k=1;k<5;k++)
    k_mask_gather<<<gN,TPB,0,stream>>>(m[k-1], m[k], off, deg, srcs);
  // weight prep: all 8 transposes in one launch
  W8 wp;
  wp.s[0] = c1_w2; wp.d[0] = wt[0]; wp.N[0] = HD;
  for (int i=0;i<3;i++){
    wp.s[1+i] = cw1 + (size_t)i*HD*HD; wp.d[1+i] = wt[1+i]; wp.N[1+i] = HD;
    wp.s[4+i] = cw2 + (size_t)i*HD*HD; wp.d[4+i] = wt[4+i]; wp.N[4+i] = HD;
  }
  wp.s[7] = l1_w; wp.d[7] = w1t; wp.N[7] = HIDN;
  k_w2ht8<<<dim3(HD/32, HD/32, 8),256,0,stream>>>(wp);

  // conv1: h0 (zeros stG,stT[0]), fused rank-1 GEMM(+stats)->buf2, apply<false>->buf0
  k_sagg_csr<<<gN,TPB,0,stream>>>(x, off, deg, srcs, eps1, h0, stG, stT);
  k_gemm_mfma<true,true><<<gmfma,256,0,stream>>>(nullptr, (const _Float16*)wt[0], c1_b2,
      (_Float16*)buf2, stG, nullptr, h0, c1_w1, c1_b1, NN);
  k_bn_apply_stats<false><<<512,256,0,stream>>>((const uint4*)buf2, c1_bng, c1_bnb, stG,
      nullptr, nullptr, nullptr, nullptr, m[1], invs, (uint4*)buf0, stT);

  // rotation state
  unsigned short *P = buf0, *Q = buf1, *R = buf2;
  const float* stPrev = stT;
  const float* gPrev = bn1_g;
  const float* bPrev = bn1_b;

  for (int i=0;i<3;i++){
    float* stCur = stT + (i+1)*1024;
    k_agg_csr<<<gagg,256,0,stream>>>((const _Float16*)P, off, deg, srcs, ceps+i,
                                  stPrev, gPrev, bPrev, (_Float16*)Q, stG);
    k_gemm_mfma<false,false><<<gmfma,256,0,stream>>>((const _Float16*)Q, (const _Float16*)wt[1+i],
        cb1 + (size_t)i*HD, (_Float16*)R, nullptr, stCur, nullptr, nullptr, nullptr, NN);
    k_gemm_mfma<true,false><<<gmfma,256,0,stream>>>((const _Float16*)R, (const _Float16*)wt[4+i],
        cb2 + (size_t)i*HD, (_Float16*)Q, stG, nullptr, nullptr, nullptr, nullptr, NN);
    k_bn_apply_stats<true><<<512,256,0,stream>>>((const uint4*)Q, cbn_g + (size_t)i*HD, cbn_b + (size_t)i*HD, stG,
        (const uint4*)P, stPrev, gPrev, bPrev, m[i+2], invs, (uint4*)R, stCur);
    unsigned short* tmp = P; P = R; R = tmp;
    stPrev = stCur;
    gPrev = bns_g + (size_t)i*HD;
    bPrev = bns_b + (size_t)i*HD;
  }

  // head: fold final BN affine into lin1 weights (also inits mx/mn), then fused head on raw P
  k_headprep<<<HIDN,256,0,stream>>>(w1t, l1_b, stPrev, gPrev, bPrev, w1s, b1p, mx, mn);
  k_head<<<ghead,256,0,stream>>>((const _Float16*)P, (const _Float16*)w1s, b1p, l2_w, l2_b,
                                 m[4], batch, z2, mx, mn, NN);
  k_final<<<gN,TPB,0,stream>>>(z2, batch, mx, mn, out);
}

// Round 17
// 924.446 us; speedup vs baseline: 2.0490x; 1.0104x over previous
//
#include <hip/hip_runtime.h>
#include <hip/hip_fp16.h>

#define NN 50000
#define NE 150000
#define HD 512
#define HIDN 64
#define BN_EPS 1e-5f
#define SLOPE 0.01f
#define NPART 196   // ceil(NN/256)

typedef _Float16 half8 __attribute__((ext_vector_type(8)));
typedef float floatx4 __attribute__((ext_vector_type(4)));

__device__ __forceinline__ float leaky(float v){ return v > 0.f ? v : SLOPE*v; }
__device__ __forceinline__ float h2fu(unsigned short u){ return __half2float(__ushort_as_half(u)); }
__device__ __forceinline__ unsigned short f2hu(float f){ return __half_as_ushort(__float2half(f)); }
__device__ __forceinline__ unsigned packh2(float a, float b){
  return (unsigned)f2hu(a) | ((unsigned)f2hu(b) << 16);
}

// ---------------- setup: invs (via inline binary-search counts) + mask0 + deg-zero ----------------
__global__ void k_invs_mask0(const int* __restrict__ batch, const float* __restrict__ x,
                             float* __restrict__ invs, int* __restrict__ m0, int* __restrict__ deg){
  int i = blockIdx.x*blockDim.x + threadIdx.x;
  if (i < NN){
    int g = batch[i];
    int lo = 0, hi = NN;
    while (lo < hi){ int mid = (lo+hi)>>1; if (batch[mid] <  g) lo = mid+1; else hi = mid; }
    int start = lo;
    lo = 0; hi = NN;
    while (lo < hi){ int mid = (lo+hi)>>1; if (batch[mid] <= g) lo = mid+1; else hi = mid; }
    invs[i] = rsqrtf((float)(lo - start));
    m0[i] = (fabsf(x[i]) > 0.f) ? 1 : 0;
    deg[i] = 0;
  }
}
__global__ void k_mask_gather(const int* __restrict__ mi, int* __restrict__ mo,
                              const int* __restrict__ off, const int* __restrict__ deg,
                              const int* __restrict__ srcs){
  int i = blockIdx.x*blockDim.x + threadIdx.x;
  if (i < NN){
    int v = mi[i];
    int o = off[i], d = deg[i];
    for (int j = 0; j < d; j++) v |= mi[srcs[o+j]];
    mo[i] = v ? 1 : 0;
  }
}

// ---------------- CSR build (by dst) ----------------
__global__ void k_deg(const int* __restrict__ dst, int* __restrict__ deg){
  int e = blockIdx.x*blockDim.x + threadIdx.x;
  if (e < NE) atomicAdd(&deg[dst[e]], 1);
}
__global__ void k_scan1(const int* __restrict__ deg, int* __restrict__ part){
  __shared__ int s[256];
  int t = threadIdx.x;
  int i = blockIdx.x*256 + t;
  s[t] = (i < NN) ? deg[i] : 0;
  __syncthreads();
  for (int d = 128; d > 0; d >>= 1){
    if (t < d) s[t] += s[t+d];
    __syncthreads();
  }
  if (t == 0) part[blockIdx.x] = s[0];
}
__global__ void k_scan2(int* __restrict__ part){
  __shared__ int s[256];
  int t = threadIdx.x;
  int own = (t < NPART) ? part[t] : 0;
  s[t] = own;
  __syncthreads();
  for (int d = 1; d < 256; d <<= 1){
    int v = (t >= d) ? s[t-d] : 0;
    __syncthreads();
    s[t] += v;
    __syncthreads();
  }
  if (t < NPART) part[t] = s[t] - own;   // exclusive
}
__global__ void k_scan3(const int* __restrict__ deg, const int* __restrict__ part,
                        int* __restrict__ off, int* __restrict__ cur){
  __shared__ int s[256];
  int t = threadIdx.x;
  int i = blockIdx.x*256 + t;
  int own = (i < NN) ? deg[i] : 0;
  s[t] = own;
  __syncthreads();
  for (int d = 1; d < 256; d <<= 1){
    int v = (t >= d) ? s[t-d] : 0;
    __syncthreads();
    s[t] += v;
    __syncthreads();
  }
  if (i < NN){
    int e = s[t] - own + part[blockIdx.x];
    off[i] = e; cur[i] = e;
  }
}
__global__ void k_scatter(const int* __restrict__ src, const int* __restrict__ dst,
                          int* __restrict__ cur, int* __restrict__ srcs){
  int e = blockIdx.x*blockDim.x + threadIdx.x;
  if (e < NE){
    int pos = atomicAdd(&cur[dst[e]], 1);
    srcs[pos] = src[e];
  }
}

// ---------------- weight prep: all 8 transposes in one launch (z-gridded) ----------------
struct W8 { const float* s[8]; unsigned short* d[8]; int N[8]; };
__global__ void k_w2ht8(W8 p){
  int z = blockIdx.z;
  const float* W = p.s[z]; unsigned short* Wt = p.d[z]; int N = p.N[z];
  int kb = blockIdx.x*32, nb = blockIdx.y*32;
  if (nb >= N) return;
  __shared__ float t[32][33];
  int tx = threadIdx.x & 31, ty = threadIdx.x >> 5;   // 32 x 8
  for (int r = 0; r < 32; r += 8)
    t[ty+r][tx] = W[(size_t)(kb+ty+r)*N + nb+tx];
  __syncthreads();
  for (int r = 0; r < 32; r += 8)
    Wt[(size_t)(nb+ty+r)*HD + kb+tx] = f2hu(t[tx][ty+r]);
}

// ---------------- conv1 front: h0 = (1+eps)x + agg ; also zeros stG/stT ----------------
__global__ void k_sagg_csr(const float* __restrict__ x, const int* __restrict__ off,
                           const int* __restrict__ deg, const int* __restrict__ srcs,
                           const float* __restrict__ epsp, float* __restrict__ h0,
                           float* __restrict__ z1, float* __restrict__ z2){
  int i = blockIdx.x*blockDim.x + threadIdx.x;
  if (i < 1024){ z1[i] = 0.f; z2[i] = 0.f; }
  if (i < NN){
    float s = (1.f + epsp[0]) * x[i];
    int o = off[i], d = deg[i];
    for (int j = 0; j < d; j++) s += x[srcs[o + j]];
    h0[i] = s;
  }
}

// ---------------- gather+combine with on-the-fly BN affine (also zeros stGz) ----------------
__global__ __launch_bounds__(256) void k_agg_csr(const _Float16* __restrict__ T,
                          const int* __restrict__ off,
                          const int* __restrict__ deg, const int* __restrict__ srcs,
                          const float* __restrict__ epsp,
                          const float* __restrict__ st, const float* __restrict__ g,
                          const float* __restrict__ bb, _Float16* __restrict__ G,
                          float* __restrict__ stGz){
  const int tid = threadIdx.x;
  const int wave = tid >> 6, t = tid & 63;
  if (blockIdx.x == 0){
    for (int c = tid; c < 1024; c += 256) stGz[c] = 0.f;
  }
  int i = blockIdx.x*4 + wave;
  if (i >= NN) return;
  int c0 = t << 3;
  const float inv_n = 1.f/(float)NN;
  float sc[8], sh[8];
  #pragma unroll
  for (int k = 0; k < 8; k++){
    int c = c0 + k;
    float mu = st[c]*inv_n;
    float var = st[HD+c]*inv_n - mu*mu;
    float s = g[c]*rsqrtf(var+BN_EPS);
    sc[k] = s; sh[k] = bb[c] - mu*s;
  }
  const half8* Tv = (const half8*)T;
  half8 p = Tv[(size_t)i*64 + t];
  float ep = 1.f + epsp[0];
  float acc[8];
  #pragma unroll
  for (int k = 0; k < 8; k++) acc[k] = (float)p[k] * ep;
  int o = off[i], d = deg[i];
  int j = 0;
  for (; j + 1 < d; j += 2){
    int s0 = srcs[o + j], s1 = srcs[o + j + 1];
    half8 q0 = Tv[(size_t)s0*64 + t];
    half8 q1 = Tv[(size_t)s1*64 + t];
    #pragma unroll
    for (int k = 0; k < 8; k++) acc[k] += (float)q0[k] + (float)q1[k];
  }
  if (j < d){
    half8 q = Tv[(size_t)srcs[o + j]*64 + t];
    #pragma unroll
    for (int k = 0; k < 8; k++) acc[k] += (float)q[k];
  }
  float cnt = ep + (float)d;
  half8 r;
  #pragma unroll
  for (int k = 0; k < 8; k++) r[k] = (_Float16)fmaf(sc[k], acc[k], cnt*sh[k]);
  ((half8*)G)[(size_t)i*64 + t] = r;
}

// ---------------- MFMA GEMM: BK=64 single-buffer, dist-2 reg ring, XCD swizzle ----------------
// 128x128 tile, 4 waves x 64x64. BK=64 established best across r12-r16 (86us vs 96 at BK=32:
// barrier count beats blocks/CU at this shape). LDS 36.9KB (+2KB conv1) -> 4 blocks/CU.
// CONV1 A-gen from fp16 LDS wbH (broadcast half8 reads). Single-pass LDS-bounce epilogue.
template<bool STATS, bool CONV1>
__global__ __launch_bounds__(256) void k_gemm_mfma(const _Float16* __restrict__ A,
    const _Float16* __restrict__ Wt, const float* __restrict__ bias,
    _Float16* __restrict__ C, float* __restrict__ st, float* __restrict__ zbuf,
    const float* __restrict__ h0, const float* __restrict__ w1f, const float* __restrict__ b1f,
    int M)
{
  constexpr int PK = 72;                  // padded K row (halves): 144B
  constexpr int HTILE = 128*PK;           // 9216 halves
  __shared__ __attribute__((aligned(16))) _Float16 pool[2*HTILE + (CONV1 ? 1024 : 0)];
  _Float16* As = pool;
  _Float16* Bs = pool + HTILE;
  _Float16* wbH = pool + 2*HTILE;         // CONV1: w1[512], b1[512] fp16
  const int tid = threadIdx.x;
  if (zbuf && blockIdx.x == 0){
    for (int c = tid; c < 1024; c += 256) zbuf[c] = 0.f;
  }
  // swizzled 1D grid: XCD = flat%8; the 4 N-tiles of an M-block share an XCD
  const int Mb = (M + 127) >> 7;
  const int QB = (Mb + 7) >> 3;
  const int F = blockIdx.x;
  const int S = F & 7, rr = F >> 3;
  const int bx = rr / QB, q = rr % QB;
  const int by = q*8 + S;
  if (by >= Mb) return;
  const int m0 = by * 128;
  const int n0 = bx * 128;
  const int w = tid >> 6, lane = tid & 63;
  const int wm = (w >> 1) << 6, wn = (w & 1) << 6;
  const int quad = lane >> 4, l16 = lane & 15;

  floatx4 acc[4][4] = {};

  const int srow = tid >> 1;                 // 0..127
  const int skoff = (tid & 1) << 5;          // 0 or 32 halves
  int arow = m0 + srow; if (arow > M-1) arow = M-1;
  const _Float16* Ag = A  + (CONV1 ? 0 : (size_t)arow*HD + skoff);
  const _Float16* Bg = Wt + (size_t)(n0 + srow)*HD + skoff;
  const int soff = srow*PK + skoff;
  float h0v = 0.f;
  if (CONV1){
    h0v = h0[arow];
    for (int i2 = tid; i2 < 512; i2 += 256){
      wbH[i2] = (_Float16)w1f[i2];
      wbH[512 + i2] = (_Float16)b1f[i2];
    }
  }

  half8 ra[3][4], rb[3][4];
  #pragma unroll
  for (int j = 0; j < 4; j++){
    rb[0][j] = *(const half8*)(Bg + j*8);
    rb[1][j] = *(const half8*)(Bg + 64 + j*8);
    if (!CONV1){
      ra[0][j] = *(const half8*)(Ag + j*8);
      ra[1][j] = *(const half8*)(Ag + 64 + j*8);
    }
  }

  #pragma unroll
  for (int it = 0; it < 8; it++){
    const int cur = it % 3, nxt = (it + 2) % 3;
    __syncthreads();                 // prior reads done (also covers wbH staging at it=0)
    if (CONV1){
      #pragma unroll
      for (int j = 0; j < 4; j++){
        half8 wv = *(const half8*)(wbH + it*64 + skoff + j*8);
        half8 bv = *(const half8*)(wbH + 512 + it*64 + skoff + j*8);
        half8 av;
        #pragma unroll
        for (int e = 0; e < 8; e++){
          float v = fmaf(h0v, (float)wv[e], (float)bv[e]);
          av[e] = (_Float16)(v > 0.f ? v : 0.f);
        }
        *(half8*)(As + soff + j*8) = av;
        *(half8*)(Bs + soff + j*8) = rb[cur][j];
      }
    } else {
      #pragma unroll
      for (int j = 0; j < 4; j++){
        *(half8*)(As + soff + j*8) = ra[cur][j];
        *(half8*)(Bs + soff + j*8) = rb[cur][j];
      }
    }
    if (it + 2 < 8){
      #pragma unroll
      for (int j = 0; j < 4; j++){
        rb[nxt][j] = *(const half8*)(Bg + (it+2)*64 + j*8);
        if (!CONV1) ra[nxt][j] = *(const half8*)(Ag + (it+2)*64 + j*8);
      }
    }
    __syncthreads();
    #pragma unroll
    for (int k0 = 0; k0 < 64; k0 += 32){
      half8 af[4], bf[4];
      #pragma unroll
      for (int t4 = 0; t4 < 4; t4++){
        af[t4] = *(const half8*)(As + (wm + t4*16 + l16)*PK + k0 + quad*8);
        bf[t4] = *(const half8*)(Bs + (wn + t4*16 + l16)*PK + k0 + quad*8);
      }
      #pragma unroll
      for (int mi = 0; mi < 4; mi++){
        #pragma unroll
        for (int ni = 0; ni < 4; ni++){
          acc[mi][ni] = __builtin_amdgcn_mfma_f32_16x16x32_f16(af[mi], bf[ni], acc[mi][ni], 0, 0, 0);
        }
      }
    }
  }

  // epilogue: bias+relu (+stats), bounce D through LDS (128x136 fits 36.9KB pool), half8 stores
  __syncthreads();
  constexpr int CP = 136;
  _Float16* Ds = pool;
  float sv[4] = {0,0,0,0}, qv[4] = {0,0,0,0};
  #pragma unroll
  for (int ni = 0; ni < 4; ni++){
    int ccol = wn + ni*16 + l16;
    float bs = bias[n0 + ccol];
    #pragma unroll
    for (int mi = 0; mi < 4; mi++){
      #pragma unroll
      for (int reg = 0; reg < 4; reg++){
        int row_l = wm + mi*16 + quad*4 + reg;
        float v = acc[mi][ni][reg] + bs;
        v = v > 0.f ? v : 0.f;
        Ds[row_l*CP + ccol] = (_Float16)v;
        if (STATS && (m0 + row_l < M)){ sv[ni] += v; qv[ni] += v*v; }
      }
    }
  }
  if (STATS){
    #pragma unroll
    for (int ni = 0; ni < 4; ni++){
      float s = sv[ni], qq = qv[ni];
      s += __shfl_xor(s, 16); s += __shfl_xor(s, 32);
      qq += __shfl_xor(qq, 16); qq += __shfl_xor(qq, 32);
      if (quad == 0){
        int ccol = n0 + wn + ni*16 + l16;
        unsafeAtomicAdd(&st[ccol], s);
        unsafeAtomicAdd(&st[HD+ccol], qq);
      }
    }
  }
  __syncthreads();
  #pragma unroll
  for (int s = 0; s < 8; s++){
    int chunk = tid + s*256;          // 0..2047
    int row_l = chunk >> 4;
    int colc  = (chunk & 15) << 3;
    int r = m0 + row_l;
    if (r < M)
      *(half8*)&C[(size_t)r*HD + n0 + colc] = *(const half8*)&Ds[row_l*CP + colc];
  }
}

// ---------------- head prep: fold last BN affine into lin1 weights; init mx/mn ----------------
__global__ void k_headprep(const unsigned short* __restrict__ w1t, const float* __restrict__ b1,
    const float* __restrict__ st, const float* __restrict__ g, const float* __restrict__ bb,
    unsigned short* __restrict__ w1s, float* __restrict__ b1p,
    unsigned* __restrict__ mx, unsigned* __restrict__ mn){
  int n = blockIdx.x; int t = threadIdx.x;
  if (n == 0 && t < 64){ mx[t] = 0u; }
  if (n == 1 && t < 64){ mn[t] = 0xFFFFFFFFu; }
  __shared__ float red[256];
  const float inv_n = 1.f/(float)NN;
  float acc = 0.f;
  #pragma unroll
  for (int kk = 0; kk < 2; kk++){
    int k = t + kk*256;
    float mu = st[k]*inv_n;
    float var = st[HD+k]*inv_n - mu*mu;
    float sc = g[k]*rsqrtf(var+BN_EPS);
    float sh = bb[k] - mu*sc;
    float wv = h2fu(w1t[(size_t)n*HD + k]);
    w1s[(size_t)n*HD + k] = f2hu(sc*wv);
    acc += sh*wv;
  }
  red[t] = acc; __syncthreads();
  for (int d = 128; d > 0; d >>= 1){ if (t < d) red[t] += red[t+d]; __syncthreads(); }
  if (t == 0) b1p[n] = b1[n] + red[0];
}

// ---------------- fused head (pipelined) with per-block LDS min/max reduction ----------------
__global__ __launch_bounds__(256) void k_head(const _Float16* __restrict__ Xh,
    const _Float16* __restrict__ W1t, const float* __restrict__ b1,
    const float* __restrict__ w2, const float* __restrict__ b2p,
    const int* __restrict__ mask, const int* __restrict__ batch,
    float* __restrict__ z2, unsigned* __restrict__ mx, unsigned* __restrict__ mn, int M)
{
  constexpr int PK = 72;
  __shared__ __attribute__((aligned(16))) _Float16 As[128*PK];
  __shared__ __attribute__((aligned(16))) _Float16 Bs[64*PK];
  __shared__ unsigned smx[64], smn[64];
  const int tid = threadIdx.x;
  const int m0 = blockIdx.x * 128;
  const int w = tid >> 6, lane = tid & 63;
  const int wm = w << 5;
  const int quad = lane >> 4, l16 = lane & 15;

  if (tid < 64){ smx[tid] = 0u; smn[tid] = 0xFFFFFFFFu; }

  floatx4 acc[2][4] = {};

  const int srow = tid >> 1;
  const int skoff = (tid & 1) << 5;
  int arow = m0 + srow; if (arow > M-1) arow = M-1;
  const _Float16* Ag = Xh + (size_t)arow*HD + skoff;
  _Float16* Asw = As + srow*PK + skoff;
  const int brow = tid >> 2;
  const int bkoff = (tid & 3) << 4;
  const _Float16* Bg = W1t + (size_t)brow*HD + bkoff;
  _Float16* Bsw = Bs + brow*PK + bkoff;

  half8 ca[4], cb[2], na[4], nb[2];
  #pragma unroll
  for (int j = 0; j < 4; j++) ca[j] = *(const half8*)(Ag + j*8);
  cb[0] = *(const half8*)(Bg); cb[1] = *(const half8*)(Bg + 8);

  #pragma unroll
  for (int kt = 0; kt < HD; kt += 64){
    __syncthreads();
    #pragma unroll
    for (int j = 0; j < 4; j++) *(half8*)(Asw + j*8) = ca[j];
    *(half8*)(Bsw) = cb[0]; *(half8*)(Bsw + 8) = cb[1];
    if (kt + 64 < HD){
      #pragma unroll
      for (int j = 0; j < 4; j++) na[j] = *(const half8*)(Ag + kt + 64 + j*8);
      nb[0] = *(const half8*)(Bg + kt + 64); nb[1] = *(const half8*)(Bg + kt + 72);
    }
    __syncthreads();
    #pragma unroll
    for (int k0 = 0; k0 < 64; k0 += 32){
      half8 af[2], bf[4];
      #pragma unroll
      for (int mi = 0; mi < 2; mi++) af[mi] = *(const half8*)&As[(wm + mi*16 + l16)*PK + k0 + quad*8];
      #pragma unroll
      for (int ni = 0; ni < 4; ni++) bf[ni] = *(const half8*)&Bs[(ni*16 + l16)*PK + k0 + quad*8];
      #pragma unroll
      for (int mi = 0; mi < 2; mi++){
        #pragma unroll
        for (int ni = 0; ni < 4; ni++){
          acc[mi][ni] = __builtin_amdgcn_mfma_f32_16x16x32_f16(af[mi], bf[ni], acc[mi][ni], 0, 0, 0);
        }
      }
    }
    #pragma unroll
    for (int j = 0; j < 4; j++) ca[j] = na[j];
    cb[0] = nb[0]; cb[1] = nb[1];
  }

  float b1v[4], w2v[4];
  #pragma unroll
  for (int ni = 0; ni < 4; ni++){ b1v[ni] = b1[ni*16 + l16]; w2v[ni] = w2[ni*16 + l16]; }
  const float b2 = b2p[0];
  #pragma unroll
  for (int mi = 0; mi < 2; mi++){
    #pragma unroll
    for (int reg = 0; reg < 4; reg++){
      int r = m0 + wm + mi*16 + quad*4 + reg;
      bool ok = r < M;
      float mk = (ok && mask[r]) ? 1.f : 0.f;
      float t = 0.f;
      #pragma unroll
      for (int ni = 0; ni < 4; ni++){
        float v = leaky(acc[mi][ni][reg] + b1v[ni]) * mk;
        t += v * w2v[ni];
      }
      t += __shfl_xor(t, 1); t += __shfl_xor(t, 2);
      t += __shfl_xor(t, 4); t += __shfl_xor(t, 8);
      if (l16 == 0 && ok){
        float zv = leaky(t + b2) * mk;
        z2[r] = zv;
        unsigned u = __float_as_uint(zv);
        unsigned key = (u & 0x80000000u) ? ~u : (u | 0x80000000u);
        int gg = batch[r];
        atomicMax(&smx[gg], key); atomicMin(&smn[gg], key);
      }
    }
  }
  __syncthreads();
  if (tid < 64){
    unsigned vx = smx[tid], vn = smn[tid];
    if (vx != 0u)          atomicMax(&mx[tid], vx);
    if (vn != 0xFFFFFFFFu) atomicMin(&mn[tid], vn);
  }
}

// ---------------- BN apply: wave-per-row uint4, LDS stats reduction ----------------
template<bool RESID>
__global__ __launch_bounds__(256) void k_bn_apply_stats(const uint4* __restrict__ Hu,
    const float* __restrict__ g, const float* __restrict__ bb, const float* __restrict__ st,
    const uint4* __restrict__ Pu, const float* __restrict__ stP,
    const float* __restrict__ gP, const float* __restrict__ bP,
    const int* __restrict__ mask, const float* __restrict__ invs,
    uint4* __restrict__ Tu, float* __restrict__ st2)
{
  __shared__ float ls[2048], lq[2048];
  const int tid = threadIdx.x;
  const int wave = tid >> 6, lane = tid & 63;
  const int c8 = lane << 3;
  const float inv_n = 1.f/(float)NN;
  float sc[8], sh[8], pc[8], ps[8];
  #pragma unroll
  for (int k = 0; k < 8; k++){
    int c = c8 + k;
    float mu = st[c]*inv_n;
    float var = st[HD+c]*inv_n - mu*mu;
    float s = g[c]*rsqrtf(var+BN_EPS);
    sc[k] = s; sh[k] = bb[c] - mu*s;
    if (RESID){
      float muP = stP[c]*inv_n;
      float varP = stP[HD+c]*inv_n - muP*muP;
      float sP = gP[c]*rsqrtf(varP+BN_EPS);
      pc[k] = sP; ps[k] = bP[c] - muP*sP;
    }
  }
  float s8[8] = {}, q8[8] = {};
  for (int r = blockIdx.x*4 + wave; r < NN; r += gridDim.x*4){
    uint4 u = Hu[(size_t)r*64 + lane];
    float hv[8];
    hv[0]=h2fu(u.x&0xFFFF); hv[1]=h2fu(u.x>>16);
    hv[2]=h2fu(u.y&0xFFFF); hv[3]=h2fu(u.y>>16);
    hv[4]=h2fu(u.z&0xFFFF); hv[5]=h2fu(u.z>>16);
    hv[6]=h2fu(u.w&0xFFFF); hv[7]=h2fu(u.w>>16);
    float v[8];
    #pragma unroll
    for (int k = 0; k < 8; k++) v[k] = leaky(fmaf(hv[k], sc[k], sh[k]));
    if (RESID){
      uint4 p = Pu[(size_t)r*64 + lane];
      float pv[8];
      pv[0]=h2fu(p.x&0xFFFF); pv[1]=h2fu(p.x>>16);
      pv[2]=h2fu(p.y&0xFFFF); pv[3]=h2fu(p.y>>16);
      pv[4]=h2fu(p.z&0xFFFF); pv[5]=h2fu(p.z>>16);
      pv[6]=h2fu(p.w&0xFFFF); pv[7]=h2fu(p.w>>16);
      #pragma unroll
      for (int k = 0; k < 8; k++) v[k] += fmaf(pv[k], pc[k], ps[k]);
    }
    float ww = mask[r] ? invs[r] : 0.f;
    uint4 o;
    o.x = packh2(v[0]*ww, v[1]*ww); o.y = packh2(v[2]*ww, v[3]*ww);
    o.z = packh2(v[4]*ww, v[5]*ww); o.w = packh2(v[6]*ww, v[7]*ww);
    Tu[(size_t)r*64 + lane] = o;
    #pragma unroll
    for (int k = 0; k < 8; k++){ float t = v[k]*ww; s8[k] += t; q8[k] += t*t; }
  }
  #pragma unroll
  for (int k = 0; k < 8; k++){
    ls[wave*512 + c8 + k] = s8[k];
    lq[wave*512 + c8 + k] = q8[k];
  }
  __syncthreads();
  for (int cc = tid; cc < 512; cc += 256){
    float S = ls[cc] + ls[512+cc] + ls[1024+cc] + ls[1536+cc];
    float Q = lq[cc] + lq[512+cc] + lq[1024+cc] + lq[1536+cc];
    unsafeAtomicAdd(&st2[cc], S);
    unsafeAtomicAdd(&st2[HD+cc], Q);
  }
}

// ---------------- final normalize ----------------
__device__ __forceinline__ float funkey(unsigned k){
  unsigned u = (k & 0x80000000u) ? (k & 0x7fffffffu) : ~k;
  return __uint_as_float(u);
}
__global__ void k_final(const float* __restrict__ z2, const int* __restrict__ batch,
                        const unsigned* __restrict__ mx, const unsigned* __restrict__ mn,
                        float* __restrict__ out){
  int i = blockIdx.x*blockDim.x + threadIdx.x;
  if (i < NN){
    int g = batch[i];
    float bmax = funkey(mx[g]), bmin = funkey(mn[g]);
    out[i] = (z2[i] - bmin) / ((bmax + 1e-6f) - bmin);
  }
}

extern "C" void kernel_launch(void* const* d_in, const int* in_sizes, int n_in,
                              void* d_out, int out_size, void* d_ws, size_t ws_size,
                              hipStream_t stream)
{
  const float* x      = (const float*)d_in[0];
  const int*   ei     = (const int*)d_in[1];
  const int*   src    = ei;
  const int*   dst    = ei + NE;
  const int*   batch  = (const int*)d_in[2];
  const float* c1_w1  = (const float*)d_in[3];
  const float* c1_b1  = (const float*)d_in[4];
  const float* c1_w2  = (const float*)d_in[5];
  const float* c1_b2  = (const float*)d_in[6];
  const float* c1_bng = (const float*)d_in[7];
  const float* c1_bnb = (const float*)d_in[8];
  const float* eps1   = (const float*)d_in[9];
  const float* bn1_g  = (const float*)d_in[10];
  const float* bn1_b  = (const float*)d_in[11];
  const float* cw1    = (const float*)d_in[12];
  const float* cb1    = (const float*)d_in[13];
  const float* cw2    = (const float*)d_in[14];
  const float* cb2    = (const float*)d_in[15];
  const float* cbn_g  = (const float*)d_in[16];
  const float* cbn_b  = (const float*)d_in[17];
  const float* ceps   = (const float*)d_in[18];
  const float* bns_g  = (const float*)d_in[19];
  const float* bns_b  = (const float*)d_in[20];
  const float* l1_w   = (const float*)d_in[21];
  const float* l1_b   = (const float*)d_in[22];
  const float* l2_w   = (const float*)d_in[23];
  const float* l2_b   = (const float*)d_in[24];
  float* out = (float*)d_out;

  const size_t NH = (size_t)NN*HD;
  unsigned short* buf0 = (unsigned short*)d_ws;   // fp16 NH
  unsigned short* buf1 = buf0 + NH;               // fp16 NH
  unsigned short* buf2 = buf1 + NH;               // fp16 NH
  float* h0   = (float*)(buf2 + NH);              // NN
  float* invs = h0 + NN;                          // NN
  float* z2   = invs + NN;                        // NN
  float* stG  = z2 + NN;                          // 1024
  float* stT  = stG + 1024;                       // 4 x 1024
  unsigned* mx = (unsigned*)(stT + 4*1024);       // 64
  unsigned* mn = mx + 64;                         // 64
  float* b1p  = (float*)(mn + 64);                // 64
  int* part = (int*)(b1p + 64);                   // 256 (scan partials)
  int* deg  = part + 256;                         // NN
  int* off  = deg + NN;                           // NN
  int* cur  = off + NN;                           // NN
  int* srcs = cur + NN;                           // NE
  int* m[5];
  m[0] = srcs + NE;
  for (int k=1;k<5;k++) m[k] = m[k-1] + NN;
  unsigned short* wt[7];
  wt[0] = (unsigned short*)(m[4] + NN);
  for (int k=1;k<7;k++) wt[k] = wt[k-1] + HD*HD;
  unsigned short* w1t = wt[6] + HD*HD;            // 64*512 fp16
  unsigned short* w1s = w1t + (size_t)HIDN*HD;    // 64*512 fp16 (affine-folded)

  const int TPB = 256;
  dim3 gN((NN+TPB-1)/TPB);
  dim3 gE((NE+TPB-1)/TPB);
  const int Mb = (NN+127)/128;          // 391
  const int QB = (Mb+7)/8;              // 49
  dim3 gmfma(8*4*QB);                   // 1568 swizzled 1D blocks
  dim3 ghead((NN+127)/128);
  dim3 gagg((NN+3)/4);

  // setup
  k_invs_mask0<<<gN, TPB, 0, stream>>>(batch, x, invs, m[0], deg);
  // CSR by dst (parallel 3-phase scan)
  k_deg<<<gE,TPB,0,stream>>>(dst, deg);
  k_scan1<<<NPART,256,0,stream>>>(deg, part);
  k_scan2<<<1,256,0,stream>>>(part);
  k_scan3<<<NPART,256,0,stream>>>(deg, part, off, cur);
  k_scatter<<<gE,TPB,0,stream>>>(src, dst, cur, srcs);
  // masks via CSR gather
  for (int k=1;k<5;k++)
    k_mask_gather<<<gN,TPB,0,stream>>>(m[k-1], m[k], off, deg, srcs);
  // weight prep: all 8 transposes in one launch
  W8 wp;
  wp.s[0] = c1_w2; wp.d[0] = wt[0]; wp.N[0] = HD;
  for (int i=0;i<3;i++){
    wp.s[1+i] = cw1 + (size_t)i*HD*HD; wp.d[1+i] = wt[1+i]; wp.N[1+i] = HD;
    wp.s[4+i] = cw2 + (size_t)i*HD*HD; wp.d[4+i] = wt[4+i]; wp.N[4+i] = HD;
  }
  wp.s[7] = l1_w; wp.d[7] = w1t; wp.N[7] = HIDN;
  k_w2ht8<<<dim3(HD/32, HD/32, 8),256,0,stream>>>(wp);

  // conv1: h0 (zeros stG,stT[0]), fused rank-1 GEMM(+stats)->buf2, apply<false>->buf0
  k_sagg_csr<<<gN,TPB,0,stream>>>(x, off, deg, srcs, eps1, h0, stG, stT);
  k_gemm_mfma<true,true><<<gmfma,256,0,stream>>>(nullptr, (const _Float16*)wt[0], c1_b2,
      (_Float16*)buf2, stG, nullptr, h0, c1_w1, c1_b1, NN);
  k_bn_apply_stats<false><<<512,256,0,stream>>>((const uint4*)buf2, c1_bng, c1_bnb, stG,
      nullptr, nullptr, nullptr, nullptr, m[1], invs, (uint4*)buf0, stT);

  // rotation state
  unsigned short *P = buf0, *Q = buf1, *R = buf2;
  const float* stPrev = stT;
  const float* gPrev = bn1_g;
  const float* bPrev = bn1_b;

  for (int i=0;i<3;i++){
    float* stCur = stT + (i+1)*1024;
    k_agg_csr<<<gagg,256,0,stream>>>((const _Float16*)P, off, deg, srcs, ceps+i,
                                  stPrev, gPrev, bPrev, (_Float16*)Q, stG);
    k_gemm_mfma<false,false><<<gmfma,256,0,stream>>>((const _Float16*)Q, (const _Float16*)wt[1+i],
        cb1 + (size_t)i*HD, (_Float16*)R, nullptr, stCur, nullptr, nullptr, nullptr, NN);
    k_gemm_mfma<true,false><<<gmfma,256,0,stream>>>((const _Float16*)R, (const _Float16*)wt[4+i],
        cb2 + (size_t)i*HD, (_Float16*)Q, stG, nullptr, nullptr, nullptr, nullptr, NN);
    k_bn_apply_stats<true><<<512,256,0,stream>>>((const uint4*)Q, cbn_g + (size_t)i*HD, cbn_b + (size_t)i*HD, stG,
        (const uint4*)P, stPrev, gPrev, bPrev, m[i+2], invs, (uint4*)R, stCur);
    unsigned short* tmp = P; P = R; R = tmp;
    stPrev = stCur;
    gPrev = bns_g + (size_t)i*HD;
    bPrev = bns_b + (size_t)i*HD;
  }

  // head: fold final BN affine into lin1 weights (also inits mx/mn), then fused head on raw P
  k_headprep<<<HIDN,256,0,stream>>>(w1t, l1_b, stPrev, gPrev, bPrev, w1s, b1p, mx, mn);
  k_head<<<ghead,256,0,stream>>>((const _Float16*)P, (const _Float16*)w1s, b1p, l2_w, l2_b,
                                 m[4], batch, z2, mx, mn, NN);
  k_final<<<gN,TPB,0,stream>>>(z2, batch, mx, mn, out);
}

// Round 18
// 781.170 us; speedup vs baseline: 2.4248x; 1.1834x over previous
//
#include <hip/hip_runtime.h>
#include <hip/hip_fp16.h>

#define NN 50000
#define NE 150000
#define HD 512
#define HIDN 64
#define BN_EPS 1e-5f
#define SLOPE 0.01f
#define NPART 196   // ceil(NN/256)

typedef _Float16 half8 __attribute__((ext_vector_type(8)));
typedef float floatx4 __attribute__((ext_vector_type(4)));

__device__ __forceinline__ float leaky(float v){ return v > 0.f ? v : SLOPE*v; }
__device__ __forceinline__ float h2fu(unsigned short u){ return __half2float(__ushort_as_half(u)); }
__device__ __forceinline__ unsigned short f2hu(float f){ return __half_as_ushort(__float2half(f)); }
__device__ __forceinline__ unsigned packh2(float a, float b){
  return (unsigned)f2hu(a) | ((unsigned)f2hu(b) << 16);
}

// ---------------- setup: invs (via inline binary-search counts) + mask0 + deg-zero ----------------
__global__ void k_invs_mask0(const int* __restrict__ batch, const float* __restrict__ x,
                             float* __restrict__ invs, int* __restrict__ m0, int* __restrict__ deg){
  int i = blockIdx.x*blockDim.x + threadIdx.x;
  if (i < NN){
    int g = batch[i];
    int lo = 0, hi = NN;
    while (lo < hi){ int mid = (lo+hi)>>1; if (batch[mid] <  g) lo = mid+1; else hi = mid; }
    int start = lo;
    lo = 0; hi = NN;
    while (lo < hi){ int mid = (lo+hi)>>1; if (batch[mid] <= g) lo = mid+1; else hi = mid; }
    invs[i] = rsqrtf((float)(lo - start));
    m0[i] = (fabsf(x[i]) > 0.f) ? 1 : 0;
    deg[i] = 0;
  }
}
__global__ void k_mask_gather(const int* __restrict__ mi, int* __restrict__ mo,
                              const int* __restrict__ off, const int* __restrict__ deg,
                              const int* __restrict__ srcs){
  int i = blockIdx.x*blockDim.x + threadIdx.x;
  if (i < NN){
    int v = mi[i];
    int o = off[i], d = deg[i];
    for (int j = 0; j < d; j++) v |= mi[srcs[o+j]];
    mo[i] = v ? 1 : 0;
  }
}

// ---------------- CSR build (by dst) ----------------
__global__ void k_deg(const int* __restrict__ dst, int* __restrict__ deg){
  int e = blockIdx.x*blockDim.x + threadIdx.x;
  if (e < NE) atomicAdd(&deg[dst[e]], 1);
}
__global__ void k_scan1(const int* __restrict__ deg, int* __restrict__ part){
  __shared__ int s[256];
  int t = threadIdx.x;
  int i = blockIdx.x*256 + t;
  s[t] = (i < NN) ? deg[i] : 0;
  __syncthreads();
  for (int d = 128; d > 0; d >>= 1){
    if (t < d) s[t] += s[t+d];
    __syncthreads();
  }
  if (t == 0) part[blockIdx.x] = s[0];
}
__global__ void k_scan2(int* __restrict__ part){
  __shared__ int s[256];
  int t = threadIdx.x;
  int own = (t < NPART) ? part[t] : 0;
  s[t] = own;
  __syncthreads();
  for (int d = 1; d < 256; d <<= 1){
    int v = (t >= d) ? s[t-d] : 0;
    __syncthreads();
    s[t] += v;
    __syncthreads();
  }
  if (t < NPART) part[t] = s[t] - own;   // exclusive
}
__global__ void k_scan3(const int* __restrict__ deg, const int* __restrict__ part,
                        int* __restrict__ off, int* __restrict__ cur){
  __shared__ int s[256];
  int t = threadIdx.x;
  int i = blockIdx.x*256 + t;
  int own = (i < NN) ? deg[i] : 0;
  s[t] = own;
  __syncthreads();
  for (int d = 1; d < 256; d <<= 1){
    int v = (t >= d) ? s[t-d] : 0;
    __syncthreads();
    s[t] += v;
    __syncthreads();
  }
  if (i < NN){
    int e = s[t] - own + part[blockIdx.x];
    off[i] = e; cur[i] = e;
  }
}
__global__ void k_scatter(const int* __restrict__ src, const int* __restrict__ dst,
                          int* __restrict__ cur, int* __restrict__ srcs){
  int e = blockIdx.x*blockDim.x + threadIdx.x;
  if (e < NE){
    int pos = atomicAdd(&cur[dst[e]], 1);
    srcs[pos] = src[e];
  }
}

// ---------------- weight prep: all 8 transposes in one launch (z-gridded) ----------------
struct W8 { const float* s[8]; unsigned short* d[8]; int N[8]; };
__global__ void k_w2ht8(W8 p){
  int z = blockIdx.z;
  const float* W = p.s[z]; unsigned short* Wt = p.d[z]; int N = p.N[z];
  int kb = blockIdx.x*32, nb = blockIdx.y*32;
  if (nb >= N) return;
  __shared__ float t[32][33];
  int tx = threadIdx.x & 31, ty = threadIdx.x >> 5;   // 32 x 8
  for (int r = 0; r < 32; r += 8)
    t[ty+r][tx] = W[(size_t)(kb+ty+r)*N + nb+tx];
  __syncthreads();
  for (int r = 0; r < 32; r += 8)
    Wt[(size_t)(nb+ty+r)*HD + kb+tx] = f2hu(t[tx][ty+r]);
}

// ---------------- conv1 front: h0 = (1+eps)x + agg ; also zeros stG/stT ----------------
__global__ void k_sagg_csr(const float* __restrict__ x, const int* __restrict__ off,
                           const int* __restrict__ deg, const int* __restrict__ srcs,
                           const float* __restrict__ epsp, float* __restrict__ h0,
                           float* __restrict__ z1, float* __restrict__ z2){
  int i = blockIdx.x*blockDim.x + threadIdx.x;
  if (i < 1024){ z1[i] = 0.f; z2[i] = 0.f; }
  if (i < NN){
    float s = (1.f + epsp[0]) * x[i];
    int o = off[i], d = deg[i];
    for (int j = 0; j < d; j++) s += x[srcs[o + j]];
    h0[i] = s;
  }
}

// ---------------- gather+combine with on-the-fly BN affine (also zeros stGz) ----------------
__global__ __launch_bounds__(256) void k_agg_csr(const _Float16* __restrict__ T,
                          const int* __restrict__ off,
                          const int* __restrict__ deg, const int* __restrict__ srcs,
                          const float* __restrict__ epsp,
                          const float* __restrict__ st, const float* __restrict__ g,
                          const float* __restrict__ bb, _Float16* __restrict__ G,
                          float* __restrict__ stGz){
  const int tid = threadIdx.x;
  const int wave = tid >> 6, t = tid & 63;
  if (blockIdx.x == 0){
    for (int c = tid; c < 1024; c += 256) stGz[c] = 0.f;
  }
  int i = blockIdx.x*4 + wave;
  if (i >= NN) return;
  int c0 = t << 3;
  const float inv_n = 1.f/(float)NN;
  float sc[8], sh[8];
  #pragma unroll
  for (int k = 0; k < 8; k++){
    int c = c0 + k;
    float mu = st[c]*inv_n;
    float var = st[HD+c]*inv_n - mu*mu;
    float s = g[c]*rsqrtf(var+BN_EPS);
    sc[k] = s; sh[k] = bb[c] - mu*s;
  }
  const half8* Tv = (const half8*)T;
  half8 p = Tv[(size_t)i*64 + t];
  float ep = 1.f + epsp[0];
  float acc[8];
  #pragma unroll
  for (int k = 0; k < 8; k++) acc[k] = (float)p[k] * ep;
  int o = off[i], d = deg[i];
  int j = 0;
  for (; j + 1 < d; j += 2){
    int s0 = srcs[o + j], s1 = srcs[o + j + 1];
    half8 q0 = Tv[(size_t)s0*64 + t];
    half8 q1 = Tv[(size_t)s1*64 + t];
    #pragma unroll
    for (int k = 0; k < 8; k++) acc[k] += (float)q0[k] + (float)q1[k];
  }
  if (j < d){
    half8 q = Tv[(size_t)srcs[o + j]*64 + t];
    #pragma unroll
    for (int k = 0; k < 8; k++) acc[k] += (float)q[k];
  }
  float cnt = ep + (float)d;
  half8 r;
  #pragma unroll
  for (int k = 0; k < 8; k++) r[k] = (_Float16)fmaf(sc[k], acc[k], cnt*sh[k]);
  ((half8*)G)[(size_t)i*64 + t] = r;
}

// ---------------- MFMA GEMM: BK=64 single-buffer, dist-2 reg ring, XCD swizzle ----------------
// 128x128 tile, 4 waves x 64x64. Grid decode: rr = q*4 + bx (bx FAST) so the 4 N-tiles of
// an M-block are 8 flat-indices apart -> co-resident on one XCD -> A-tile L2 reuse.
// (r17 had bx slow: siblings 392 apart -> 6.3MB streamed through 4MB L2 between reads ->
// FETCH = 1.84x A. This is the single variable changed this round.)
template<bool STATS, bool CONV1>
__global__ __launch_bounds__(256) void k_gemm_mfma(const _Float16* __restrict__ A,
    const _Float16* __restrict__ Wt, const float* __restrict__ bias,
    _Float16* __restrict__ C, float* __restrict__ st, float* __restrict__ zbuf,
    const float* __restrict__ h0, const float* __restrict__ w1f, const float* __restrict__ b1f,
    int M)
{
  constexpr int PK = 72;                  // padded K row (halves): 144B
  constexpr int HTILE = 128*PK;           // 9216 halves
  __shared__ __attribute__((aligned(16))) _Float16 pool[2*HTILE + (CONV1 ? 1024 : 0)];
  _Float16* As = pool;
  _Float16* Bs = pool + HTILE;
  _Float16* wbH = pool + 2*HTILE;         // CONV1: w1[512], b1[512] fp16
  const int tid = threadIdx.x;
  if (zbuf && blockIdx.x == 0){
    for (int c = tid; c < 1024; c += 256) zbuf[c] = 0.f;
  }
  const int Mb = (M + 127) >> 7;
  const int QB = (Mb + 7) >> 3;
  const int F = blockIdx.x;
  const int S = F & 7, rr = F >> 3;
  const int bx = rr & 3, q = rr >> 2;     // bx FAST: N-tile siblings adjacent
  const int by = q*8 + S;
  if (by >= Mb) return;
  const int m0 = by * 128;
  const int n0 = bx * 128;
  const int w = tid >> 6, lane = tid & 63;
  const int wm = (w >> 1) << 6, wn = (w & 1) << 6;
  const int quad = lane >> 4, l16 = lane & 15;

  floatx4 acc[4][4] = {};

  const int srow = tid >> 1;                 // 0..127
  const int skoff = (tid & 1) << 5;          // 0 or 32 halves
  int arow = m0 + srow; if (arow > M-1) arow = M-1;
  const _Float16* Ag = A  + (CONV1 ? 0 : (size_t)arow*HD + skoff);
  const _Float16* Bg = Wt + (size_t)(n0 + srow)*HD + skoff;
  const int soff = srow*PK + skoff;
  float h0v = 0.f;
  if (CONV1){
    h0v = h0[arow];
    for (int i2 = tid; i2 < 512; i2 += 256){
      wbH[i2] = (_Float16)w1f[i2];
      wbH[512 + i2] = (_Float16)b1f[i2];
    }
  }

  half8 ra[3][4], rb[3][4];
  #pragma unroll
  for (int j = 0; j < 4; j++){
    rb[0][j] = *(const half8*)(Bg + j*8);
    rb[1][j] = *(const half8*)(Bg + 64 + j*8);
    if (!CONV1){
      ra[0][j] = *(const half8*)(Ag + j*8);
      ra[1][j] = *(const half8*)(Ag + 64 + j*8);
    }
  }

  #pragma unroll
  for (int it = 0; it < 8; it++){
    const int cur = it % 3, nxt = (it + 2) % 3;
    __syncthreads();                 // prior reads done (also covers wbH staging at it=0)
    if (CONV1){
      #pragma unroll
      for (int j = 0; j < 4; j++){
        half8 wv = *(const half8*)(wbH + it*64 + skoff + j*8);
        half8 bv = *(const half8*)(wbH + 512 + it*64 + skoff + j*8);
        half8 av;
        #pragma unroll
        for (int e = 0; e < 8; e++){
          float v = fmaf(h0v, (float)wv[e], (float)bv[e]);
          av[e] = (_Float16)(v > 0.f ? v : 0.f);
        }
        *(half8*)(As + soff + j*8) = av;
        *(half8*)(Bs + soff + j*8) = rb[cur][j];
      }
    } else {
      #pragma unroll
      for (int j = 0; j < 4; j++){
        *(half8*)(As + soff + j*8) = ra[cur][j];
        *(half8*)(Bs + soff + j*8) = rb[cur][j];
      }
    }
    if (it + 2 < 8){
      #pragma unroll
      for (int j = 0; j < 4; j++){
        rb[nxt][j] = *(const half8*)(Bg + (it+2)*64 + j*8);
        if (!CONV1) ra[nxt][j] = *(const half8*)(Ag + (it+2)*64 + j*8);
      }
    }
    __syncthreads();
    #pragma unroll
    for (int k0 = 0; k0 < 64; k0 += 32){
      half8 af[4], bf[4];
      #pragma unroll
      for (int t4 = 0; t4 < 4; t4++){
        af[t4] = *(const half8*)(As + (wm + t4*16 + l16)*PK + k0 + quad*8);
        bf[t4] = *(const half8*)(Bs + (wn + t4*16 + l16)*PK + k0 + quad*8);
      }
      #pragma unroll
      for (int mi = 0; mi < 4; mi++){
        #pragma unroll
        for (int ni = 0; ni < 4; ni++){
          acc[mi][ni] = __builtin_amdgcn_mfma_f32_16x16x32_f16(af[mi], bf[ni], acc[mi][ni], 0, 0, 0);
        }
      }
    }
  }

  // epilogue: bias+relu (+stats), bounce D through LDS (128x136 fits pool), half8 stores
  __syncthreads();
  constexpr int CP = 136;
  _Float16* Ds = pool;
  float sv[4] = {0,0,0,0}, qv[4] = {0,0,0,0};
  #pragma unroll
  for (int ni = 0; ni < 4; ni++){
    int ccol = wn + ni*16 + l16;
    float bs = bias[n0 + ccol];
    #pragma unroll
    for (int mi = 0; mi < 4; mi++){
      #pragma unroll
      for (int reg = 0; reg < 4; reg++){
        int row_l = wm + mi*16 + quad*4 + reg;
        float v = acc[mi][ni][reg] + bs;
        v = v > 0.f ? v : 0.f;
        Ds[row_l*CP + ccol] = (_Float16)v;
        if (STATS && (m0 + row_l < M)){ sv[ni] += v; qv[ni] += v*v; }
      }
    }
  }
  if (STATS){
    #pragma unroll
    for (int ni = 0; ni < 4; ni++){
      float s = sv[ni], qq = qv[ni];
      s += __shfl_xor(s, 16); s += __shfl_xor(s, 32);
      qq += __shfl_xor(qq, 16); qq += __shfl_xor(qq, 32);
      if (quad == 0){
        int ccol = n0 + wn + ni*16 + l16;
        unsafeAtomicAdd(&st[ccol], s);
        unsafeAtomicAdd(&st[HD+ccol], qq);
      }
    }
  }
  __syncthreads();
  #pragma unroll
  for (int s = 0; s < 8; s++){
    int chunk = tid + s*256;          // 0..2047
    int row_l = chunk >> 4;
    int colc  = (chunk & 15) << 3;
    int r = m0 + row_l;
    if (r < M)
      *(half8*)&C[(size_t)r*HD + n0 + colc] = *(const half8*)&Ds[row_l*CP + colc];
  }
}

// ---------------- head prep: fold last BN affine into lin1 weights; init mx/mn ----------------
__global__ void k_headprep(const unsigned short* __restrict__ w1t, const float* __restrict__ b1,
    const float* __restrict__ st, const float* __restrict__ g, const float* __restrict__ bb,
    unsigned short* __restrict__ w1s, float* __restrict__ b1p,
    unsigned* __restrict__ mx, unsigned* __restrict__ mn){
  int n = blockIdx.x; int t = threadIdx.x;
  if (n == 0 && t < 64){ mx[t] = 0u; }
  if (n == 1 && t < 64){ mn[t] = 0xFFFFFFFFu; }
  __shared__ float red[256];
  const float inv_n = 1.f/(float)NN;
  float acc = 0.f;
  #pragma unroll
  for (int kk = 0; kk < 2; kk++){
    int k = t + kk*256;
    float mu = st[k]*inv_n;
    float var = st[HD+k]*inv_n - mu*mu;
    float sc = g[k]*rsqrtf(var+BN_EPS);
    float sh = bb[k] - mu*sc;
    float wv = h2fu(w1t[(size_t)n*HD + k]);
    w1s[(size_t)n*HD + k] = f2hu(sc*wv);
    acc += sh*wv;
  }
  red[t] = acc; __syncthreads();
  for (int d = 128; d > 0; d >>= 1){ if (t < d) red[t] += red[t+d]; __syncthreads(); }
  if (t == 0) b1p[n] = b1[n] + red[0];
}

// ---------------- fused head (pipelined) with per-block LDS min/max reduction ----------------
__global__ __launch_bounds__(256) void k_head(const _Float16* __restrict__ Xh,
    const _Float16* __restrict__ W1t, const float* __restrict__ b1,
    const float* __restrict__ w2, const float* __restrict__ b2p,
    const int* __restrict__ mask, const int* __restrict__ batch,
    float* __restrict__ z2, unsigned* __restrict__ mx, unsigned* __restrict__ mn, int M)
{
  constexpr int PK = 72;
  __shared__ __attribute__((aligned(16))) _Float16 As[128*PK];
  __shared__ __attribute__((aligned(16))) _Float16 Bs[64*PK];
  __shared__ unsigned smx[64], smn[64];
  const int tid = threadIdx.x;
  const int m0 = blockIdx.x * 128;
  const int w = tid >> 6, lane = tid & 63;
  const int wm = w << 5;
  const int quad = lane >> 4, l16 = lane & 15;

  if (tid < 64){ smx[tid] = 0u; smn[tid] = 0xFFFFFFFFu; }

  floatx4 acc[2][4] = {};

  const int srow = tid >> 1;
  const int skoff = (tid & 1) << 5;
  int arow = m0 + srow; if (arow > M-1) arow = M-1;
  const _Float16* Ag = Xh + (size_t)arow*HD + skoff;
  _Float16* Asw = As + srow*PK + skoff;
  const int brow = tid >> 2;
  const int bkoff = (tid & 3) << 4;
  const _Float16* Bg = W1t + (size_t)brow*HD + bkoff;
  _Float16* Bsw = Bs + brow*PK + bkoff;

  half8 ca[4], cb[2], na[4], nb[2];
  #pragma unroll
  for (int j = 0; j < 4; j++) ca[j] = *(const half8*)(Ag + j*8);
  cb[0] = *(const half8*)(Bg); cb[1] = *(const half8*)(Bg + 8);

  #pragma unroll
  for (int kt = 0; kt < HD; kt += 64){
    __syncthreads();
    #pragma unroll
    for (int j = 0; j < 4; j++) *(half8*)(Asw + j*8) = ca[j];
    *(half8*)(Bsw) = cb[0]; *(half8*)(Bsw + 8) = cb[1];
    if (kt + 64 < HD){
      #pragma unroll
      for (int j = 0; j < 4; j++) na[j] = *(const half8*)(Ag + kt + 64 + j*8);
      nb[0] = *(const half8*)(Bg + kt + 64); nb[1] = *(const half8*)(Bg + kt + 72);
    }
    __syncthreads();
    #pragma unroll
    for (int k0 = 0; k0 < 64; k0 += 32){
      half8 af[2], bf[4];
      #pragma unroll
      for (int mi = 0; mi < 2; mi++) af[mi] = *(const half8*)&As[(wm + mi*16 + l16)*PK + k0 + quad*8];
      #pragma unroll
      for (int ni = 0; ni < 4; ni++) bf[ni] = *(const half8*)&Bs[(ni*16 + l16)*PK + k0 + quad*8];
      #pragma unroll
      for (int mi = 0; mi < 2; mi++){
        #pragma unroll
        for (int ni = 0; ni < 4; ni++){
          acc[mi][ni] = __builtin_amdgcn_mfma_f32_16x16x32_f16(af[mi], bf[ni], acc[mi][ni], 0, 0, 0);
        }
      }
    }
    #pragma unroll
    for (int j = 0; j < 4; j++) ca[j] = na[j];
    cb[0] = nb[0]; cb[1] = nb[1];
  }

  float b1v[4], w2v[4];
  #pragma unroll
  for (int ni = 0; ni < 4; ni++){ b1v[ni] = b1[ni*16 + l16]; w2v[ni] = w2[ni*16 + l16]; }
  const float b2 = b2p[0];
  #pragma unroll
  for (int mi = 0; mi < 2; mi++){
    #pragma unroll
    for (int reg = 0; reg < 4; reg++){
      int r = m0 + wm + mi*16 + quad*4 + reg;
      bool ok = r < M;
      float mk = (ok && mask[r]) ? 1.f : 0.f;
      float t = 0.f;
      #pragma unroll
      for (int ni = 0; ni < 4; ni++){
        float v = leaky(acc[mi][ni][reg] + b1v[ni]) * mk;
        t += v * w2v[ni];
      }
      t += __shfl_xor(t, 1); t += __shfl_xor(t, 2);
      t += __shfl_xor(t, 4); t += __shfl_xor(t, 8);
      if (l16 == 0 && ok){
        float zv = leaky(t + b2) * mk;
        z2[r] = zv;
        unsigned u = __float_as_uint(zv);
        unsigned key = (u & 0x80000000u) ? ~u : (u | 0x80000000u);
        int gg = batch[r];
        atomicMax(&smx[gg], key); atomicMin(&smn[gg], key);
      }
    }
  }
  __syncthreads();
  if (tid < 64){
    unsigned vx = smx[tid], vn = smn[tid];
    if (vx != 0u)          atomicMax(&mx[tid], vx);
    if (vn != 0xFFFFFFFFu) atomicMin(&mn[tid], vn);
  }
}

// ---------------- BN apply: wave-per-row uint4, LDS stats reduction ----------------
template<bool RESID>
__global__ __launch_bounds__(256) void k_bn_apply_stats(const uint4* __restrict__ Hu,
    const float* __restrict__ g, const float* __restrict__ bb, const float* __restrict__ st,
    const uint4* __restrict__ Pu, const float* __restrict__ stP,
    const float* __restrict__ gP, const float* __restrict__ bP,
    const int* __restrict__ mask, const float* __restrict__ invs,
    uint4* __restrict__ Tu, float* __restrict__ st2)
{
  __shared__ float ls[2048], lq[2048];
  const int tid = threadIdx.x;
  const int wave = tid >> 6, lane = tid & 63;
  const int c8 = lane << 3;
  const float inv_n = 1.f/(float)NN;
  float sc[8], sh[8], pc[8], ps[8];
  #pragma unroll
  for (int k = 0; k < 8; k++){
    int c = c8 + k;
    float mu = st[c]*inv_n;
    float var = st[HD+c]*inv_n - mu*mu;
    float s = g[c]*rsqrtf(var+BN_EPS);
    sc[k] = s; sh[k] = bb[c] - mu*s;
    if (RESID){
      float muP = stP[c]*inv_n;
      float varP = stP[HD+c]*inv_n - muP*muP;
      float sP = gP[c]*rsqrtf(varP+BN_EPS);
      pc[k] = sP; ps[k] = bP[c] - muP*sP;
    }
  }
  float s8[8] = {}, q8[8] = {};
  for (int r = blockIdx.x*4 + wave; r < NN; r += gridDim.x*4){
    uint4 u = Hu[(size_t)r*64 + lane];
    float hv[8];
    hv[0]=h2fu(u.x&0xFFFF); hv[1]=h2fu(u.x>>16);
    hv[2]=h2fu(u.y&0xFFFF); hv[3]=h2fu(u.y>>16);
    hv[4]=h2fu(u.z&0xFFFF); hv[5]=h2fu(u.z>>16);
    hv[6]=h2fu(u.w&0xFFFF); hv[7]=h2fu(u.w>>16);
    float v[8];
    #pragma unroll
    for (int k = 0; k < 8; k++) v[k] = leaky(fmaf(hv[k], sc[k], sh[k]));
    if (RESID){
      uint4 p = Pu[(size_t)r*64 + lane];
      float pv[8];
      pv[0]=h2fu(p.x&0xFFFF); pv[1]=h2fu(p.x>>16);
      pv[2]=h2fu(p.y&0xFFFF); pv[3]=h2fu(p.y>>16);
      pv[4]=h2fu(p.z&0xFFFF); pv[5]=h2fu(p.z>>16);
      pv[6]=h2fu(p.w&0xFFFF); pv[7]=h2fu(p.w>>16);
      #pragma unroll
      for (int k = 0; k < 8; k++) v[k] += fmaf(pv[k], pc[k], ps[k]);
    }
    float ww = mask[r] ? invs[r] : 0.f;
    uint4 o;
    o.x = packh2(v[0]*ww, v[1]*ww); o.y = packh2(v[2]*ww, v[3]*ww);
    o.z = packh2(v[4]*ww, v[5]*ww); o.w = packh2(v[6]*ww, v[7]*ww);
    Tu[(size_t)r*64 + lane] = o;
    #pragma unroll
    for (int k = 0; k < 8; k++){ float t = v[k]*ww; s8[k] += t; q8[k] += t*t; }
  }
  #pragma unroll
  for (int k = 0; k < 8; k++){
    ls[wave*512 + c8 + k] = s8[k];
    lq[wave*512 + c8 + k] = q8[k];
  }
  __syncthreads();
  for (int cc = tid; cc < 512; cc += 256){
    float S = ls[cc] + ls[512+cc] + ls[1024+cc] + ls[1536+cc];
    float Q = lq[cc] + lq[512+cc] + lq[1024+cc] + lq[1536+cc];
    unsafeAtomicAdd(&st2[cc], S);
    unsafeAtomicAdd(&st2[HD+cc], Q);
  }
}

// ---------------- final normalize ----------------
__device__ __forceinline__ float funkey(unsigned k){
  unsigned u = (k & 0x80000000u) ? (k & 0x7fffffffu) : ~k;
  return __uint_as_float(u);
}
__global__ void k_final(const float* __restrict__ z2, const int* __restrict__ batch,
                        const unsigned* __restrict__ mx, const unsigned* __restrict__ mn,
                        float* __restrict__ out){
  int i = blockIdx.x*blockDim.x + threadIdx.x;
  if (i < NN){
    int g = batch[i];
    float bmax = funkey(mx[g]), bmin = funkey(mn[g]);
    out[i] = (z2[i] - bmin) / ((bmax + 1e-6f) - bmin);
  }
}

extern "C" void kernel_launch(void* const* d_in, const int* in_sizes, int n_in,
                              void* d_out, int out_size, void* d_ws, size_t ws_size,
                              hipStream_t stream)
{
  const float* x      = (const float*)d_in[0];
  const int*   ei     = (const int*)d_in[1];
  const int*   src    = ei;
  const int*   dst    = ei + NE;
  const int*   batch  = (const int*)d_in[2];
  const float* c1_w1  = (const float*)d_in[3];
  const float* c1_b1  = (const float*)d_in[4];
  const float* c1_w2  = (const float*)d_in[5];
  const float* c1_b2  = (const float*)d_in[6];
  const float* c1_bng = (const float*)d_in[7];
  const float* c1_bnb = (const float*)d_in[8];
  const float* eps1   = (const float*)d_in[9];
  const float* bn1_g  = (const float*)d_in[10];
  const float* bn1_b  = (const float*)d_in[11];
  const float* cw1    = (const float*)d_in[12];
  const float* cb1    = (const float*)d_in[13];
  const float* cw2    = (const float*)d_in[14];
  const float* cb2    = (const float*)d_in[15];
  const float* cbn_g  = (const float*)d_in[16];
  const float* cbn_b  = (const float*)d_in[17];
  const float* ceps   = (const float*)d_in[18];
  const float* bns_g  = (const float*)d_in[19];
  const float* bns_b  = (const float*)d_in[20];
  const float* l1_w   = (const float*)d_in[21];
  const float* l1_b   = (const float*)d_in[22];
  const float* l2_w   = (const float*)d_in[23];
  const float* l2_b   = (const float*)d_in[24];
  float* out = (float*)d_out;

  const size_t NH = (size_t)NN*HD;
  unsigned short* buf0 = (unsigned short*)d_ws;   // fp16 NH
  unsigned short* buf1 = buf0 + NH;               // fp16 NH
  unsigned short* buf2 = buf1 + NH;               // fp16 NH
  float* h0   = (float*)(buf2 + NH);              // NN
  float* invs = h0 + NN;                          // NN
  float* z2   = invs + NN;                        // NN
  float* stG  = z2 + NN;                          // 1024
  float* stT  = stG + 1024;                       // 4 x 1024
  unsigned* mx = (unsigned*)(stT + 4*1024);       // 64
  unsigned* mn = mx + 64;                         // 64
  float* b1p  = (float*)(mn + 64);                // 64
  int* part = (int*)(b1p + 64);                   // 256 (scan partials)
  int* deg  = part + 256;                         // NN
  int* off  = deg + NN;                           // NN
  int* cur  = off + NN;                           // NN
  int* srcs = cur + NN;                           // NE
  int* m[5];
  m[0] = srcs + NE;
  for (int k=1;k<5;k++) m[k] = m[k-1] + NN;
  unsigned short* wt[7];
  wt[0] = (unsigned short*)(m[4] + NN);
  for (int k=1;k<7;k++) wt[k] = wt[k-1] + HD*HD;
  unsigned short* w1t = wt[6] + HD*HD;            // 64*512 fp16
  unsigned short* w1s = w1t + (size_t)HIDN*HD;    // 64*512 fp16 (affine-folded)

  const int TPB = 256;
  dim3 gN((NN+TPB-1)/TPB);
  dim3 gE((NE+TPB-1)/TPB);
  const int Mb = (NN+127)/128;          // 391
  const int QB = (Mb+7)/8;              // 49
  dim3 gmfma(8*4*QB);                   // 1568 swizzled 1D blocks
  dim3 ghead((NN+127)/128);
  dim3 gagg((NN+3)/4);

  // setup
  k_invs_mask0<<<gN, TPB, 0, stream>>>(batch, x, invs, m[0], deg);
  // CSR by dst (parallel 3-phase scan)
  k_deg<<<gE,TPB,0,stream>>>(dst, deg);
  k_scan1<<<NPART,256,0,stream>>>(deg, part);
  k_scan2<<<1,256,0,stream>>>(part);
  k_scan3<<<NPART,256,0,stream>>>(deg, part, off, cur);
  k_scatter<<<gE,TPB,0,stream>>>(src, dst, cur, srcs);
  // masks via CSR gather
  for (int k=1;k<5;k++)
    k_mask_gather<<<gN,TPB,0,stream>>>(m[k-1], m[k], off, deg, srcs);
  // weight prep: all 8 transposes in one launch
  W8 wp;
  wp.s[0] = c1_w2; wp.d[0] = wt[0]; wp.N[0] = HD;
  for (int i=0;i<3;i++){
    wp.s[1+i] = cw1 + (size_t)i*HD*HD; wp.d[1+i] = wt[1+i]; wp.N[1+i] = HD;
    wp.s[4+i] = cw2 + (size_t)i*HD*HD; wp.d[4+i] = wt[4+i]; wp.N[4+i] = HD;
  }
  wp.s[7] = l1_w; wp.d[7] = w1t; wp.N[7] = HIDN;
  k_w2ht8<<<dim3(HD/32, HD/32, 8),256,0,stream>>>(wp);

  // conv1: h0 (zeros stG,stT[0]), fused rank-1 GEMM(+stats)->buf2, apply<false>->buf0
  k_sagg_csr<<<gN,TPB,0,stream>>>(x, off, deg, srcs, eps1, h0, stG, stT);
  k_gemm_mfma<true,true><<<gmfma,256,0,stream>>>(nullptr, (const _Float16*)wt[0], c1_b2,
      (_Float16*)buf2, stG, nullptr, h0, c1_w1, c1_b1, NN);
  k_bn_apply_stats<false><<<512,256,0,stream>>>((const uint4*)buf2, c1_bng, c1_bnb, stG,
      nullptr, nullptr, nullptr, nullptr, m[1], invs, (uint4*)buf0, stT);

  // rotation state
  unsigned short *P = buf0, *Q = buf1, *R = buf2;
  const float* stPrev = stT;
  const float* gPrev = bn1_g;
  const float* bPrev = bn1_b;

  for (int i=0;i<3;i++){
    float* stCur = stT + (i+1)*1024;
    k_agg_csr<<<gagg,256,0,stream>>>((const _Float16*)P, off, deg, srcs, ceps+i,
                                  stPrev, gPrev, bPrev, (_Float16*)Q, stG);
    k_gemm_mfma<false,false><<<gmfma,256,0,stream>>>((const _Float16*)Q, (const _Float16*)wt[1+i],
        cb1 + (size_t)i*HD, (_Float16*)R, nullptr, stCur, nullptr, nullptr, nullptr, NN);
    k_gemm_mfma<true,false><<<gmfma,256,0,stream>>>((const _Float16*)R, (const _Float16*)wt[4+i],
        cb2 + (size_t)i*HD, (_Float16*)Q, stG, nullptr, nullptr, nullptr, nullptr, NN);
    k_bn_apply_stats<true><<<512,256,0,stream>>>((const uint4*)Q, cbn_g + (size_t)i*HD, cbn_b + (size_t)i*HD, stG,
        (const uint4*)P, stPrev, gPrev, bPrev, m[i+2], invs, (uint4*)R, stCur);
    unsigned short* tmp = P; P = R; R = tmp;
    stPrev = stCur;
    gPrev = bns_g + (size_t)i*HD;
    bPrev = bns_b + (size_t)i*HD;
  }

  // head: fold final BN affine into lin1 weights (also inits mx/mn), then fused head on raw P
  k_headprep<<<HIDN,256,0,stream>>>(w1t, l1_b, stPrev, gPrev, bPrev, w1s, b1p, mx, mn);
  k_head<<<ghead,256,0,stream>>>((const _Float16*)P, (const _Float16*)w1s, b1p, l2_w, l2_b,
                                 m[4], batch, z2, mx, mn, NN);
  k_final<<<gN,TPB,0,stream>>>(z2, batch, mx, mn, out);
}